// Round 1
// baseline (526.978 us; speedup 1.0000x reference)
//
#include <hip/hip_runtime.h>

typedef unsigned short u16;
typedef __attribute__((ext_vector_type(8))) short short8;
typedef __attribute__((ext_vector_type(4))) float f32x4;

#define DIMV 1024
#define KD 512
#define HEADS 16
#define DK 32
#define DV 64
#define TT 4096
#define BB 2
#define MROWS 8192           // B*T
#define CHUNK 64
#define NCH 64               // T/CHUNK
#define NBH 32               // B*HEADS
#define SCALE 0.17677669529663687f  // 32^-0.5

__device__ __forceinline__ u16 f2bf(float f) {
    union { float f; unsigned int u; } x; x.f = f;
    unsigned int u = x.u;
    unsigned int r = (u + 0x7fffu + ((u >> 16) & 1u)) >> 16;
    return (u16)r;
}
__device__ __forceinline__ float bf2f(u16 s) {
    union { unsigned int u; float f; } x; x.u = ((unsigned int)s) << 16;
    return x.f;
}

// ---------------- x f32 -> bf16 ----------------
__global__ __launch_bounds__(256) void f32_to_bf16_vec(const float* __restrict__ src,
                                                       u16* __restrict__ dst, int n4) {
    int i = blockIdx.x * 256 + threadIdx.x;
    if (i < n4) {
        const float4 v = ((const float4*)src)[i];
        ushort4 o;
        o.x = f2bf(v.x); o.y = f2bf(v.y); o.z = f2bf(v.z); o.w = f2bf(v.w);
        ((ushort4*)dst)[i] = o;
    }
}

// ---------------- W (K x N) f32 -> Wt (N x K) bf16 ----------------
__global__ __launch_bounds__(256) void transpose_to_bf16(const float* __restrict__ src,
                                                         u16* __restrict__ dst, int K, int N) {
    __shared__ float tile[32][33];
    int n0 = blockIdx.x * 32, k0 = blockIdx.y * 32;
    int tx = threadIdx.x & 31, ty = threadIdx.x >> 5;
    for (int r = ty; r < 32; r += 8)
        tile[r][tx] = src[(size_t)(k0 + r) * N + n0 + tx];
    __syncthreads();
    for (int r = ty; r < 32; r += 8)
        dst[(size_t)(n0 + r) * K + k0 + tx] = f2bf(tile[tx][r]);
}

// ---------------- gate: gk = logsigmoid((x@W1)@W2 + b) / 16 ----------------
__global__ __launch_bounds__(256) void gate_kernel(const float* __restrict__ x,
                                                   const float* __restrict__ W1,
                                                   const float* __restrict__ W2,
                                                   const float* __restrict__ b2,
                                                   float* __restrict__ gk) {
    __shared__ float xrow[1024];
    __shared__ float part[16][17];
    __shared__ float xg1[16];
    int row = blockIdx.x;
    int tid = threadIdx.x;
    float4 xv = ((const float4*)(x + (size_t)row * 1024))[tid];
    *(float4*)&xrow[tid * 4] = xv;
    __syncthreads();
    int j = tid >> 4, l16 = tid & 15;
    float p = 0.f;
    #pragma unroll 8
    for (int m = 0; m < 64; ++m) {
        int d = l16 + m * 16;
        p += xrow[d] * W1[d * 16 + j];
    }
    part[j][l16] = p;
    __syncthreads();
    if (tid < 16) {
        float s = 0.f;
        #pragma unroll
        for (int u = 0; u < 16; ++u) s += part[tid][u];
        xg1[tid] = s;
    }
    __syncthreads();
    for (int c = tid; c < 512; c += 256) {
        float z = b2[c];
        #pragma unroll
        for (int u = 0; u < 16; ++u) z += xg1[u] * W2[u * 512 + c];
        float ls = fminf(z, 0.f) - log1pf(expf(-fabsf(z)));
        gk[(size_t)row * 512 + c] = ls * 0.0625f;
    }
}

// ---------------- bf16 MFMA GEMM: C(MxN) = A(MxK) @ Bt(NxK)^T ----------------
template<int OUTBF>
__global__ __launch_bounds__(256) void gemm_bt(const u16* __restrict__ A,
                                               const u16* __restrict__ Bt,
                                               void* __restrict__ C,
                                               int M, int N, int K) {
    __shared__ u16 As[64][40];
    __shared__ u16 Bs[64][40];
    int tid = threadIdx.x;
    int wave = tid >> 6, lane = tid & 63;
    int wr = wave >> 1, wc = wave & 1;
    int brow = blockIdx.y * 64, bcol = blockIdx.x * 64;
    int sr = tid >> 2, sk = (tid & 3) << 3;
    const u16* aS = A + (size_t)(brow + sr) * K + sk;
    const u16* bS = Bt + (size_t)(bcol + sr) * K + sk;
    short8 av = *(const short8*)aS;
    short8 bv = *(const short8*)bS;
    f32x4 acc[2][2];
    #pragma unroll
    for (int mi = 0; mi < 2; ++mi)
        #pragma unroll
        for (int ni = 0; ni < 2; ++ni)
            acc[mi][ni] = (f32x4){0.f, 0.f, 0.f, 0.f};
    int l15 = lane & 15, lk = (lane >> 4) << 3;
    for (int kt = 0; kt < K; kt += 32) {
        __syncthreads();
        *(short8*)&As[sr][sk] = av;
        *(short8*)&Bs[sr][sk] = bv;
        __syncthreads();
        if (kt + 32 < K) {
            av = *(const short8*)(aS + kt + 32);
            bv = *(const short8*)(bS + kt + 32);
        }
        short8 a0 = *(short8*)&As[wr * 32 + l15][lk];
        short8 a1 = *(short8*)&As[wr * 32 + 16 + l15][lk];
        short8 b0 = *(short8*)&Bs[wc * 32 + l15][lk];
        short8 b1 = *(short8*)&Bs[wc * 32 + 16 + l15][lk];
        acc[0][0] = __builtin_amdgcn_mfma_f32_16x16x32_bf16(a0, b0, acc[0][0], 0, 0, 0);
        acc[0][1] = __builtin_amdgcn_mfma_f32_16x16x32_bf16(a0, b1, acc[0][1], 0, 0, 0);
        acc[1][0] = __builtin_amdgcn_mfma_f32_16x16x32_bf16(a1, b0, acc[1][0], 0, 0, 0);
        acc[1][1] = __builtin_amdgcn_mfma_f32_16x16x32_bf16(a1, b1, acc[1][1], 0, 0, 0);
    }
    int r0 = brow + wr * 32 + ((lane >> 4) << 2);
    int c0 = bcol + wc * 32 + l15;
    #pragma unroll
    for (int mi = 0; mi < 2; ++mi)
        #pragma unroll
        for (int ni = 0; ni < 2; ++ni)
            #pragma unroll
            for (int rr = 0; rr < 4; ++rr) {
                size_t idx = (size_t)(r0 + mi * 16 + rr) * N + (c0 + ni * 16);
                float val = acc[mi][ni][rr];
                if (OUTBF) ((u16*)C)[idx] = f2bf(val);
                else       ((float*)C)[idx] = val;
            }
}

// ---------------- phase A: per-chunk cumsum S, decayed K^T V  ----------------
__global__ __launch_bounds__(256) void phaseA(const u16* __restrict__ qkvg,
                                              const float* __restrict__ gk,
                                              float* __restrict__ S_ws,
                                              float* __restrict__ M_ws,
                                              float* __restrict__ D_ws) {
    int bh = blockIdx.x >> 6, c = blockIdx.x & 63;
    int b = bh >> 4, h = bh & 15;
    int t0 = b * TT + c * CHUNK;
    __shared__ float gkS[64][36];
    __shared__ float k_l[64][36];
    __shared__ float kd[64][36];
    __shared__ float v_l[64][68];
    __shared__ float Z[32];
    int tid = threadIdx.x;
    int s = tid >> 2, i0 = (tid & 3) << 3;
    // gk chunk
    {
        const float* g = gk + (size_t)(t0 + s) * KD + h * DK + i0;
        float4 a = *(const float4*)g, bq = *(const float4*)(g + 4);
        *(float4*)&gkS[s][i0] = a;
        *(float4*)&gkS[s][i0 + 4] = bq;
    }
    // k chunk (bf16)
    {
        short8 kv = *(const short8*)(qkvg + (size_t)(t0 + s) * 3072 + 512 + h * DK + i0);
        #pragma unroll
        for (int jj = 0; jj < 8; ++jj) k_l[s][i0 + jj] = bf2f((u16)kv[jj]);
    }
    // v chunk (bf16): 16 per thread
    {
        int j0 = (tid & 3) << 4;
        short8 v0 = *(const short8*)(qkvg + (size_t)(t0 + s) * 3072 + 1024 + h * DV + j0);
        short8 v1 = *(const short8*)(qkvg + (size_t)(t0 + s) * 3072 + 1024 + h * DV + j0 + 8);
        #pragma unroll
        for (int jj = 0; jj < 8; ++jj) {
            v_l[s][j0 + jj] = bf2f((u16)v0[jj]);
            v_l[s][j0 + 8 + jj] = bf2f((u16)v1[jj]);
        }
    }
    __syncthreads();
    // inclusive cumsum along t for each i (threads 0..31)
    if (tid < 32) {
        float run = 0.f;
        for (int t = 0; t < 64; ++t) {
            run += gkS[t][tid];
            gkS[t][tid] = run;
        }
        Z[tid] = run;
    }
    __syncthreads();
    // store S, compute kd = exp(Z - S) * k
    {
        float* sp = S_ws + (size_t)(t0 + s) * KD + h * DK + i0;
        *(float4*)sp = *(float4*)&gkS[s][i0];
        *(float4*)(sp + 4) = *(float4*)&gkS[s][i0 + 4];
        #pragma unroll
        for (int jj = 0; jj < 8; ++jj)
            kd[s][i0 + jj] = expf(Z[i0 + jj] - gkS[s][i0 + jj]) * k_l[s][i0 + jj];
    }
    __syncthreads();
    // M[i][j] = sum_s kd[s][i] * v[s][j]
    {
        int i = tid >> 4, j4 = tid & 15;
        int i2 = i + 16;
        float a0 = 0, a1 = 0, a2 = 0, a3 = 0, b0 = 0, b1 = 0, b2v = 0, b3 = 0;
        for (int ss = 0; ss < 64; ++ss) {
            float kd1 = kd[ss][i], kd2 = kd[ss][i2];
            const float4 vv = *(const float4*)&v_l[ss][j4 * 4];
            a0 += kd1 * vv.x; a1 += kd1 * vv.y; a2 += kd1 * vv.z; a3 += kd1 * vv.w;
            b0 += kd2 * vv.x; b1 += kd2 * vv.y; b2v += kd2 * vv.z; b3 += kd2 * vv.w;
        }
        size_t base = ((size_t)(bh * NCH + c)) * 2048;
        float4 o1; o1.x = a0; o1.y = a1; o1.z = a2; o1.w = a3;
        float4 o2; o2.x = b0; o2.y = b1; o2.z = b2v; o2.w = b3;
        *(float4*)(M_ws + base + i * 64 + j4 * 4) = o1;
        *(float4*)(M_ws + base + i2 * 64 + j4 * 4) = o2;
    }
    if (tid < 32) D_ws[(size_t)(bh * NCH + c) * 32 + tid] = expf(Z[tid]);
}

// ---------------- phase B: sequential chunk-state recurrence ----------------
__global__ __launch_bounds__(256) void phaseB(const float* __restrict__ M_ws,
                                              const float* __restrict__ D_ws,
                                              float* __restrict__ H_ws) {
    int bh = blockIdx.x;
    int tid = threadIdx.x;
    int i = tid >> 3, j0 = (tid & 7) << 3;
    float h[8];
    #pragma unroll
    for (int u = 0; u < 8; ++u) h[u] = 0.f;
    for (int c = 0; c < NCH; ++c) {
        size_t base = ((size_t)(bh * NCH + c)) * 2048 + i * 64 + j0;
        float4 h0; h0.x = h[0]; h0.y = h[1]; h0.z = h[2]; h0.w = h[3];
        float4 h1; h1.x = h[4]; h1.y = h[5]; h1.z = h[6]; h1.w = h[7];
        *(float4*)(H_ws + base) = h0;
        *(float4*)(H_ws + base + 4) = h1;
        float d = D_ws[(size_t)(bh * NCH + c) * 32 + i];
        const float4 m0 = *(const float4*)(M_ws + base);
        const float4 m1 = *(const float4*)(M_ws + base + 4);
        h[0] = h[0] * d + m0.x; h[1] = h[1] * d + m0.y;
        h[2] = h[2] * d + m0.z; h[3] = h[3] * d + m0.w;
        h[4] = h[4] * d + m1.x; h[5] = h[5] * d + m1.y;
        h[6] = h[6] * d + m1.z; h[7] = h[7] * d + m1.w;
    }
}

// ---------------- phase C: intra-chunk attention + inter-chunk output ----------------
__global__ __launch_bounds__(256) void phaseC(const u16* __restrict__ qkvg,
                                              const float* __restrict__ S_ws,
                                              const float* __restrict__ H_ws,
                                              u16* __restrict__ o_ws) {
    int bh = blockIdx.x >> 6, c = blockIdx.x & 63;
    int b = bh >> 4, h = bh & 15;
    int t0 = b * TT + c * CHUNK;
    __shared__ float qh[64][36];
    __shared__ float kt[64][36];
    __shared__ float v_l[64][68];
    __shared__ float H_l[32][68];
    __shared__ float A_l[64][68];
    int tid = threadIdx.x;
    int s = tid >> 2, i0 = (tid & 3) << 3;
    // load S + q,k; build qh = q*exp(S)*scale, kt = k*exp(-S)
    {
        const float* sp = S_ws + (size_t)(t0 + s) * KD + h * DK + i0;
        float4 S0 = *(const float4*)sp, S1 = *(const float4*)(sp + 4);
        short8 qv = *(const short8*)(qkvg + (size_t)(t0 + s) * 3072 + h * DK + i0);
        short8 kv = *(const short8*)(qkvg + (size_t)(t0 + s) * 3072 + 512 + h * DK + i0);
        float Sv[8] = {S0.x, S0.y, S0.z, S0.w, S1.x, S1.y, S1.z, S1.w};
        #pragma unroll
        for (int jj = 0; jj < 8; ++jj) {
            qh[s][i0 + jj] = bf2f((u16)qv[jj]) * expf(Sv[jj]) * SCALE;
            kt[s][i0 + jj] = bf2f((u16)kv[jj]) * expf(fminf(-Sv[jj], 80.f));
        }
    }
    // v chunk
    {
        int j0 = (tid & 3) << 4;
        short8 v0 = *(const short8*)(qkvg + (size_t)(t0 + s) * 3072 + 1024 + h * DV + j0);
        short8 v1 = *(const short8*)(qkvg + (size_t)(t0 + s) * 3072 + 1024 + h * DV + j0 + 8);
        #pragma unroll
        for (int jj = 0; jj < 8; ++jj) {
            v_l[s][j0 + jj] = bf2f((u16)v0[jj]);
            v_l[s][j0 + 8 + jj] = bf2f((u16)v1[jj]);
        }
    }
    // H chunk-initial state
    {
        int i = tid >> 3, j0 = (tid & 7) << 3;
        size_t base = ((size_t)(bh * NCH + c)) * 2048 + i * 64 + j0;
        *(float4*)&H_l[i][j0] = *(const float4*)(H_ws + base);
        *(float4*)&H_l[i][j0 + 4] = *(const float4*)(H_ws + base + 4);
    }
    __syncthreads();
    // A[t][s] = sum_i qh[t][i]*kt[s][i]  (s<=t), else 0
    {
        int ta = tid >> 2, s0 = (tid & 3) << 4;
        for (int ss = s0; ss < s0 + 16; ++ss) {
            float a = 0.f;
            if (ss <= ta) {
                #pragma unroll 8
                for (int i = 0; i < 32; ++i) a += qh[ta][i] * kt[ss][i];
            }
            A_l[ta][ss] = a;
        }
    }
    __syncthreads();
    // o[t][j] = qh[t]·H[:,j] + sum_{s<=t} A[t][s] v[s][j]
    #pragma unroll
    for (int q4 = 0; q4 < 4; ++q4) {
        int slot = tid + q4 * 256;
        int t = slot >> 4, j4 = slot & 15;
        float a0 = 0, a1 = 0, a2 = 0, a3 = 0;
        #pragma unroll 8
        for (int i = 0; i < 32; ++i) {
            float qv = qh[t][i];
            const float4 hv = *(const float4*)&H_l[i][j4 * 4];
            a0 += qv * hv.x; a1 += qv * hv.y; a2 += qv * hv.z; a3 += qv * hv.w;
        }
        for (int ss = 0; ss <= t; ++ss) {
            float av = A_l[t][ss];
            const float4 vv = *(const float4*)&v_l[ss][j4 * 4];
            a0 += av * vv.x; a1 += av * vv.y; a2 += av * vv.z; a3 += av * vv.w;
        }
        ushort4 ov;
        ov.x = f2bf(a0); ov.y = f2bf(a1); ov.z = f2bf(a2); ov.w = f2bf(a3);
        *(ushort4*)(o_ws + (size_t)(t0 + t) * 1024 + h * DV + j4 * 4) = ov;
    }
}

// ---------------- RMSNorm + swish gate ----------------
__global__ __launch_bounds__(256) void norm_gate(const u16* __restrict__ o_ws,
                                                 const u16* __restrict__ qkvg,
                                                 const float* __restrict__ gnw,
                                                 u16* __restrict__ o_n) {
    int tid = threadIdx.x;
    int wave = tid >> 6, lane = tid & 63;
    int r = blockIdx.x * 4 + wave;
    int t = r >> 4, h = r & 15;
    float v = bf2f(o_ws[(size_t)t * 1024 + h * DV + lane]);
    float ss = v * v;
    #pragma unroll
    for (int off = 32; off; off >>= 1) ss += __shfl_xor(ss, off);
    float rms = rsqrtf(ss * (1.f / 64.f) + 1e-5f);
    float g = bf2f(qkvg[(size_t)t * 3072 + 2048 + h * DV + lane]);
    float sw = g / (1.f + expf(-g));
    o_n[(size_t)t * 1024 + h * DV + lane] = f2bf(v * rms * gnw[lane] * sw);
}

// ---------------- launch ----------------
extern "C" void kernel_launch(void* const* d_in, const int* in_sizes, int n_in,
                              void* d_out, int out_size, void* d_ws, size_t ws_size,
                              hipStream_t stream) {
    const float* x    = (const float*)d_in[0];
    const float* Wq   = (const float*)d_in[1];
    const float* Wk   = (const float*)d_in[2];
    const float* Wv   = (const float*)d_in[3];
    const float* Wgk1 = (const float*)d_in[4];
    const float* Wgk2 = (const float*)d_in[5];
    const float* bgk2 = (const float*)d_in[6];
    const float* Wg   = (const float*)d_in[7];
    const float* gnw  = (const float*)d_in[8];
    const float* Wo   = (const float*)d_in[9];

    char* ws = (char*)d_ws;
    size_t off = 0;
    u16* xb     = (u16*)(ws + off); off += (size_t)MROWS * 1024 * 2;          // 16.8 MB
    u16* WcatT  = (u16*)(ws + off); off += (size_t)3072 * 1024 * 2;           // 6.3 MB
    u16* WoT    = (u16*)(ws + off); off += (size_t)1024 * 1024 * 2;           // 2.1 MB
    u16* qkvg   = (u16*)(ws + off); off += (size_t)MROWS * 3072 * 2;          // 50.3 MB
    float* gkp  = (float*)(ws + off); off += (size_t)MROWS * KD * 4;          // 16.8 MB
    float* S_ws = (float*)(ws + off); off += (size_t)MROWS * KD * 4;          // 16.8 MB
    float* M_ws = (float*)(ws + off); off += (size_t)NBH * NCH * 2048 * 4;    // 16.8 MB
    float* D_ws = (float*)(ws + off); off += (size_t)NBH * NCH * 32 * 4;      // 0.26 MB
    float* H_ws = (float*)(ws + off); off += (size_t)NBH * NCH * 2048 * 4;    // 16.8 MB
    u16* o_scan = (u16*)(ws + off); off += (size_t)MROWS * 1024 * 2;          // 16.8 MB
    u16* o_n    = (u16*)(ws + off); off += (size_t)MROWS * 1024 * 2;          // 16.8 MB

    f32_to_bf16_vec<<<MROWS, 256, 0, stream>>>(x, xb, MROWS * 1024 / 4);
    transpose_to_bf16<<<dim3(16, 32), 256, 0, stream>>>(Wq, WcatT, 1024, 512);
    transpose_to_bf16<<<dim3(16, 32), 256, 0, stream>>>(Wk, WcatT + (size_t)512 * 1024, 1024, 512);
    transpose_to_bf16<<<dim3(32, 32), 256, 0, stream>>>(Wv, WcatT + (size_t)1024 * 1024, 1024, 1024);
    transpose_to_bf16<<<dim3(32, 32), 256, 0, stream>>>(Wg, WcatT + (size_t)2048 * 1024, 1024, 1024);
    transpose_to_bf16<<<dim3(32, 32), 256, 0, stream>>>(Wo, WoT, 1024, 1024);
    gate_kernel<<<MROWS, 256, 0, stream>>>(x, Wgk1, Wgk2, bgk2, gkp);
    gemm_bt<1><<<dim3(48, 128), 256, 0, stream>>>(xb, WcatT, qkvg, MROWS, 3072, 1024);
    phaseA<<<NBH * NCH, 256, 0, stream>>>(qkvg, gkp, S_ws, M_ws, D_ws);
    phaseB<<<NBH, 256, 0, stream>>>(M_ws, D_ws, H_ws);
    phaseC<<<NBH * NCH, 256, 0, stream>>>(qkvg, S_ws, H_ws, o_scan);
    norm_gate<<<MROWS * HEADS / 4, 256, 0, stream>>>(o_scan, qkvg, gnw, o_n);
    gemm_bt<0><<<dim3(16, 128), 256, 0, stream>>>(o_n, WoT, d_out, MROWS, 1024, 1024);
}

// Round 2
// 314.559 us; speedup vs baseline: 1.6753x; 1.6753x over previous
//
#include <hip/hip_runtime.h>

typedef unsigned short u16;
typedef __attribute__((ext_vector_type(8))) short short8;
typedef __attribute__((ext_vector_type(4))) float f32x4;

#define DIMV 1024
#define KD 512
#define HEADS 16
#define DK 32
#define DV 64
#define TT 4096
#define BB 2
#define MROWS 8192           // B*T
#define CHUNK 64
#define NCH 64               // T/CHUNK
#define NBH 32               // B*HEADS
#define SCALE 0.17677669529663687f  // 32^-0.5

__device__ __forceinline__ u16 f2bf(float f) {
    union { float f; unsigned int u; } x; x.f = f;
    unsigned int u = x.u;
    unsigned int r = (u + 0x7fffu + ((u >> 16) & 1u)) >> 16;
    return (u16)r;
}
__device__ __forceinline__ float bf2f(u16 s) {
    union { unsigned int u; float f; } x; x.u = ((unsigned int)s) << 16;
    return x.f;
}

// ---------------- W (K x N) f32 -> Wt (N x K) bf16 ----------------
__global__ __launch_bounds__(256) void transpose_to_bf16(const float* __restrict__ src,
                                                         u16* __restrict__ dst, int K, int N) {
    __shared__ float tile[32][33];
    int n0 = blockIdx.x * 32, k0 = blockIdx.y * 32;
    int tx = threadIdx.x & 31, ty = threadIdx.x >> 5;
    for (int r = ty; r < 32; r += 8)
        tile[r][tx] = src[(size_t)(k0 + r) * N + n0 + tx];
    __syncthreads();
    for (int r = ty; r < 32; r += 8)
        dst[(size_t)(n0 + r) * K + k0 + tx] = f2bf(tile[tx][r]);
}

// ---------------- fused: x->bf16 cast + gate gk = logsigmoid((x@W1)@W2+b)/16 ----------------
// 8 rows per block; thread (r=tid>>5, c=tid&31) owns x[row][c*32 .. c*32+32)
__global__ __launch_bounds__(256) void xcast_gate(const float* __restrict__ x,
                                                  u16* __restrict__ xb,
                                                  const float* __restrict__ W1,
                                                  const float* __restrict__ W2,
                                                  const float* __restrict__ b2,
                                                  float* __restrict__ gk) {
    __shared__ float xg1s[8][16];
    int tid = threadIdx.x;
    int r = tid >> 5, c = tid & 31;
    int gr = blockIdx.x * 8 + r;
    const float* xp = x + (size_t)gr * 1024 + c * 32;
    u16* xbp = xb + (size_t)gr * 1024 + c * 32;
    float p[16];
    #pragma unroll
    for (int j = 0; j < 16; ++j) p[j] = 0.f;
    #pragma unroll
    for (int q = 0; q < 8; ++q) {
        float4 xv = *(const float4*)(xp + q * 4);
        ushort4 ov;
        ov.x = f2bf(xv.x); ov.y = f2bf(xv.y); ov.z = f2bf(xv.z); ov.w = f2bf(xv.w);
        *(ushort4*)(xbp + q * 4) = ov;
        float xa[4] = {xv.x, xv.y, xv.z, xv.w};
        #pragma unroll
        for (int dd = 0; dd < 4; ++dd) {
            int d = c * 32 + q * 4 + dd;
            const float4* w = (const float4*)(W1 + (size_t)d * 16);
            float4 w0 = w[0], w1 = w[1], w2 = w[2], w3 = w[3];
            float xd = xa[dd];
            p[0] += xd * w0.x; p[1] += xd * w0.y; p[2] += xd * w0.z; p[3] += xd * w0.w;
            p[4] += xd * w1.x; p[5] += xd * w1.y; p[6] += xd * w1.z; p[7] += xd * w1.w;
            p[8] += xd * w2.x; p[9] += xd * w2.y; p[10] += xd * w2.z; p[11] += xd * w2.w;
            p[12] += xd * w3.x; p[13] += xd * w3.y; p[14] += xd * w3.z; p[15] += xd * w3.w;
        }
    }
    // reduce over the 32 lanes of this row (offsets <32 stay within the half-wave)
    #pragma unroll
    for (int off = 1; off < 32; off <<= 1)
        #pragma unroll
        for (int j = 0; j < 16; ++j) p[j] += __shfl_xor(p[j], off);
    if (c == 0) {
        #pragma unroll
        for (int j = 0; j < 16; ++j) xg1s[r][j] = p[j];
    }
    __syncthreads();
    // stage 2: z[cc..cc+16) = b2 + xg1 @ W2 ; gk = logsigmoid(z)/16
    int cc = c * 16;
    float xg[16];
    #pragma unroll
    for (int u = 0; u < 16; ++u) xg[u] = xg1s[r][u];
    float z[16];
    {
        const float4* bp = (const float4*)(b2 + cc);
        float4 z0 = bp[0], z1 = bp[1], z2 = bp[2], z3 = bp[3];
        z[0]=z0.x; z[1]=z0.y; z[2]=z0.z; z[3]=z0.w;
        z[4]=z1.x; z[5]=z1.y; z[6]=z1.z; z[7]=z1.w;
        z[8]=z2.x; z[9]=z2.y; z[10]=z2.z; z[11]=z2.w;
        z[12]=z3.x; z[13]=z3.y; z[14]=z3.z; z[15]=z3.w;
    }
    #pragma unroll
    for (int u = 0; u < 16; ++u) {
        const float4* w = (const float4*)(W2 + (size_t)u * 512 + cc);
        float4 w0 = w[0], w1 = w[1], w2 = w[2], w3 = w[3];
        float xu = xg[u];
        z[0] += xu * w0.x; z[1] += xu * w0.y; z[2] += xu * w0.z; z[3] += xu * w0.w;
        z[4] += xu * w1.x; z[5] += xu * w1.y; z[6] += xu * w1.z; z[7] += xu * w1.w;
        z[8] += xu * w2.x; z[9] += xu * w2.y; z[10] += xu * w2.z; z[11] += xu * w2.w;
        z[12] += xu * w3.x; z[13] += xu * w3.y; z[14] += xu * w3.z; z[15] += xu * w3.w;
    }
    float* gp = gk + (size_t)gr * 512 + cc;
    #pragma unroll
    for (int j = 0; j < 16; ++j) {
        float zz = z[j];
        float ls = fminf(zz, 0.f) - log1pf(expf(-fabsf(zz)));
        gp[j] = ls * 0.0625f;
    }
}

// ---------------- bf16 MFMA GEMM: C(MxN) = A(MxK) @ Bt(NxK)^T, 128x128 tile ----------------
template<int OUTBF>
__global__ __launch_bounds__(256) void gemm_bt(const u16* __restrict__ A,
                                               const u16* __restrict__ Bt,
                                               void* __restrict__ C,
                                               int M, int N, int K) {
    __shared__ u16 As[128][40];
    __shared__ u16 Bs[128][40];
    int tid = threadIdx.x;
    int wave = tid >> 6, lane = tid & 63;
    int wr = wave >> 1, wc = wave & 1;       // 2x2 waves, each owns 64x64
    int brow = blockIdx.y * 128, bcol = blockIdx.x * 128;
    int sr = tid >> 1, sk = (tid & 1) << 4;  // staging: row 0..127, k 0 or 16
    const u16* aS = A + (size_t)(brow + sr) * K + sk;
    const u16* bS = Bt + (size_t)(bcol + sr) * K + sk;
    short8 av0 = *(const short8*)aS;
    short8 av1 = *(const short8*)(aS + 8);
    short8 bv0 = *(const short8*)bS;
    short8 bv1 = *(const short8*)(bS + 8);
    f32x4 acc[4][4];
    #pragma unroll
    for (int mi = 0; mi < 4; ++mi)
        #pragma unroll
        for (int ni = 0; ni < 4; ++ni)
            acc[mi][ni] = (f32x4){0.f, 0.f, 0.f, 0.f};
    int l15 = lane & 15, lk = (lane >> 4) << 3;
    for (int kt = 0; kt < K; kt += 32) {
        __syncthreads();
        *(short8*)&As[sr][sk] = av0;
        *(short8*)&As[sr][sk + 8] = av1;
        *(short8*)&Bs[sr][sk] = bv0;
        *(short8*)&Bs[sr][sk + 8] = bv1;
        __syncthreads();
        if (kt + 32 < K) {
            av0 = *(const short8*)(aS + kt + 32);
            av1 = *(const short8*)(aS + kt + 40);
            bv0 = *(const short8*)(bS + kt + 32);
            bv1 = *(const short8*)(bS + kt + 40);
        }
        short8 af[4], bf[4];
        #pragma unroll
        for (int i = 0; i < 4; ++i) af[i] = *(short8*)&As[wr * 64 + i * 16 + l15][lk];
        #pragma unroll
        for (int i = 0; i < 4; ++i) bf[i] = *(short8*)&Bs[wc * 64 + i * 16 + l15][lk];
        #pragma unroll
        for (int mi = 0; mi < 4; ++mi)
            #pragma unroll
            for (int ni = 0; ni < 4; ++ni)
                acc[mi][ni] = __builtin_amdgcn_mfma_f32_16x16x32_bf16(af[mi], bf[ni], acc[mi][ni], 0, 0, 0);
    }
    int r0 = brow + wr * 64 + ((lane >> 4) << 2);
    int c0 = bcol + wc * 64 + l15;
    #pragma unroll
    for (int mi = 0; mi < 4; ++mi)
        #pragma unroll
        for (int ni = 0; ni < 4; ++ni)
            #pragma unroll
            for (int rr = 0; rr < 4; ++rr) {
                size_t idx = (size_t)(r0 + mi * 16 + rr) * N + (c0 + ni * 16);
                float val = acc[mi][ni][rr];
                if (OUTBF) ((u16*)C)[idx] = f2bf(val);
                else       ((float*)C)[idx] = val;
            }
}

// ---------------- phase A: per-chunk cumsum S, decayed K^T V  ----------------
__global__ __launch_bounds__(256) void phaseA(const u16* __restrict__ qkvg,
                                              const float* __restrict__ gk,
                                              float* __restrict__ S_ws,
                                              float* __restrict__ M_ws,
                                              float* __restrict__ D_ws) {
    int bh = blockIdx.x >> 6, c = blockIdx.x & 63;
    int b = bh >> 4, h = bh & 15;
    int t0 = b * TT + c * CHUNK;
    __shared__ float gkS[64][36];
    __shared__ float k_l[64][36];
    __shared__ float kd[64][36];
    __shared__ float v_l[64][68];
    __shared__ float Z[32];
    int tid = threadIdx.x;
    int s = tid >> 2, i0 = (tid & 3) << 3;
    {
        const float* g = gk + (size_t)(t0 + s) * KD + h * DK + i0;
        float4 a = *(const float4*)g, bq = *(const float4*)(g + 4);
        *(float4*)&gkS[s][i0] = a;
        *(float4*)&gkS[s][i0 + 4] = bq;
    }
    {
        short8 kv = *(const short8*)(qkvg + (size_t)(t0 + s) * 3072 + 512 + h * DK + i0);
        #pragma unroll
        for (int jj = 0; jj < 8; ++jj) k_l[s][i0 + jj] = bf2f((u16)kv[jj]);
    }
    {
        int j0 = (tid & 3) << 4;
        short8 v0 = *(const short8*)(qkvg + (size_t)(t0 + s) * 3072 + 1024 + h * DV + j0);
        short8 v1 = *(const short8*)(qkvg + (size_t)(t0 + s) * 3072 + 1024 + h * DV + j0 + 8);
        #pragma unroll
        for (int jj = 0; jj < 8; ++jj) {
            v_l[s][j0 + jj] = bf2f((u16)v0[jj]);
            v_l[s][j0 + 8 + jj] = bf2f((u16)v1[jj]);
        }
    }
    __syncthreads();
    if (tid < 32) {
        float run = 0.f;
        for (int t = 0; t < 64; ++t) {
            run += gkS[t][tid];
            gkS[t][tid] = run;
        }
        Z[tid] = run;
    }
    __syncthreads();
    {
        float* sp = S_ws + (size_t)(t0 + s) * KD + h * DK + i0;
        *(float4*)sp = *(float4*)&gkS[s][i0];
        *(float4*)(sp + 4) = *(float4*)&gkS[s][i0 + 4];
        #pragma unroll
        for (int jj = 0; jj < 8; ++jj)
            kd[s][i0 + jj] = expf(Z[i0 + jj] - gkS[s][i0 + jj]) * k_l[s][i0 + jj];
    }
    __syncthreads();
    {
        int i = tid >> 4, j4 = tid & 15;
        int i2 = i + 16;
        float a0 = 0, a1 = 0, a2 = 0, a3 = 0, b0 = 0, b1 = 0, b2v = 0, b3 = 0;
        for (int ss = 0; ss < 64; ++ss) {
            float kd1 = kd[ss][i], kd2 = kd[ss][i2];
            const float4 vv = *(const float4*)&v_l[ss][j4 * 4];
            a0 += kd1 * vv.x; a1 += kd1 * vv.y; a2 += kd1 * vv.z; a3 += kd1 * vv.w;
            b0 += kd2 * vv.x; b1 += kd2 * vv.y; b2v += kd2 * vv.z; b3 += kd2 * vv.w;
        }
        size_t base = ((size_t)(bh * NCH + c)) * 2048;
        float4 o1; o1.x = a0; o1.y = a1; o1.z = a2; o1.w = a3;
        float4 o2; o2.x = b0; o2.y = b1; o2.z = b2v; o2.w = b3;
        *(float4*)(M_ws + base + i * 64 + j4 * 4) = o1;
        *(float4*)(M_ws + base + i2 * 64 + j4 * 4) = o2;
    }
    if (tid < 32) D_ws[(size_t)(bh * NCH + c) * 32 + tid] = expf(Z[tid]);
}

// ---------------- phase B: sequential chunk-state recurrence ----------------
__global__ __launch_bounds__(256) void phaseB(const float* __restrict__ M_ws,
                                              const float* __restrict__ D_ws,
                                              float* __restrict__ H_ws) {
    int bh = blockIdx.x;
    int tid = threadIdx.x;
    int i = tid >> 3, j0 = (tid & 7) << 3;
    float h[8];
    #pragma unroll
    for (int u = 0; u < 8; ++u) h[u] = 0.f;
    for (int c = 0; c < NCH; ++c) {
        size_t base = ((size_t)(bh * NCH + c)) * 2048 + i * 64 + j0;
        float4 h0; h0.x = h[0]; h0.y = h[1]; h0.z = h[2]; h0.w = h[3];
        float4 h1; h1.x = h[4]; h1.y = h[5]; h1.z = h[6]; h1.w = h[7];
        *(float4*)(H_ws + base) = h0;
        *(float4*)(H_ws + base + 4) = h1;
        float d = D_ws[(size_t)(bh * NCH + c) * 32 + i];
        const float4 m0 = *(const float4*)(M_ws + base);
        const float4 m1 = *(const float4*)(M_ws + base + 4);
        h[0] = h[0] * d + m0.x; h[1] = h[1] * d + m0.y;
        h[2] = h[2] * d + m0.z; h[3] = h[3] * d + m0.w;
        h[4] = h[4] * d + m1.x; h[5] = h[5] * d + m1.y;
        h[6] = h[6] * d + m1.z; h[7] = h[7] * d + m1.w;
    }
}

// ---------------- phase C: intra-chunk attention + inter-chunk output ----------------
__global__ __launch_bounds__(256) void phaseC(const u16* __restrict__ qkvg,
                                              const float* __restrict__ S_ws,
                                              const float* __restrict__ H_ws,
                                              u16* __restrict__ o_ws) {
    int bh = blockIdx.x >> 6, c = blockIdx.x & 63;
    int b = bh >> 4, h = bh & 15;
    int t0 = b * TT + c * CHUNK;
    __shared__ float qh[64][36];
    __shared__ float kt[64][36];
    __shared__ float v_l[64][68];
    __shared__ float H_l[32][68];
    __shared__ float A_l[64][68];
    int tid = threadIdx.x;
    int s = tid >> 2, i0 = (tid & 3) << 3;
    {
        const float* sp = S_ws + (size_t)(t0 + s) * KD + h * DK + i0;
        float4 S0 = *(const float4*)sp, S1 = *(const float4*)(sp + 4);
        short8 qv = *(const short8*)(qkvg + (size_t)(t0 + s) * 3072 + h * DK + i0);
        short8 kv = *(const short8*)(qkvg + (size_t)(t0 + s) * 3072 + 512 + h * DK + i0);
        float Sv[8] = {S0.x, S0.y, S0.z, S0.w, S1.x, S1.y, S1.z, S1.w};
        #pragma unroll
        for (int jj = 0; jj < 8; ++jj) {
            qh[s][i0 + jj] = bf2f((u16)qv[jj]) * expf(Sv[jj]) * SCALE;
            kt[s][i0 + jj] = bf2f((u16)kv[jj]) * expf(fminf(-Sv[jj], 80.f));
        }
    }
    {
        int j0 = (tid & 3) << 4;
        short8 v0 = *(const short8*)(qkvg + (size_t)(t0 + s) * 3072 + 1024 + h * DV + j0);
        short8 v1 = *(const short8*)(qkvg + (size_t)(t0 + s) * 3072 + 1024 + h * DV + j0 + 8);
        #pragma unroll
        for (int jj = 0; jj < 8; ++jj) {
            v_l[s][j0 + jj] = bf2f((u16)v0[jj]);
            v_l[s][j0 + 8 + jj] = bf2f((u16)v1[jj]);
        }
    }
    {
        int i = tid >> 3, j0 = (tid & 7) << 3;
        size_t base = ((size_t)(bh * NCH + c)) * 2048 + i * 64 + j0;
        *(float4*)&H_l[i][j0] = *(const float4*)(H_ws + base);
        *(float4*)&H_l[i][j0 + 4] = *(const float4*)(H_ws + base + 4);
    }
    __syncthreads();
    {
        int ta = tid >> 2, s0 = (tid & 3) << 4;
        for (int ss = s0; ss < s0 + 16; ++ss) {
            float a = 0.f;
            if (ss <= ta) {
                #pragma unroll 8
                for (int i = 0; i < 32; ++i) a += qh[ta][i] * kt[ss][i];
            }
            A_l[ta][ss] = a;
        }
    }
    __syncthreads();
    #pragma unroll
    for (int q4 = 0; q4 < 4; ++q4) {
        int slot = tid + q4 * 256;
        int t = slot >> 4, j4 = slot & 15;
        float a0 = 0, a1 = 0, a2 = 0, a3 = 0;
        #pragma unroll 8
        for (int i = 0; i < 32; ++i) {
            float qv = qh[t][i];
            const float4 hv = *(const float4*)&H_l[i][j4 * 4];
            a0 += qv * hv.x; a1 += qv * hv.y; a2 += qv * hv.z; a3 += qv * hv.w;
        }
        for (int ss = 0; ss <= t; ++ss) {
            float av = A_l[t][ss];
            const float4 vv = *(const float4*)&v_l[ss][j4 * 4];
            a0 += av * vv.x; a1 += av * vv.y; a2 += av * vv.z; a3 += av * vv.w;
        }
        ushort4 ov;
        ov.x = f2bf(a0); ov.y = f2bf(a1); ov.z = f2bf(a2); ov.w = f2bf(a3);
        *(ushort4*)(o_ws + (size_t)(t0 + t) * 1024 + h * DV + j4 * 4) = ov;
    }
}

// ---------------- RMSNorm + swish gate ----------------
__global__ __launch_bounds__(256) void norm_gate(const u16* __restrict__ o_ws,
                                                 const u16* __restrict__ qkvg,
                                                 const float* __restrict__ gnw,
                                                 u16* __restrict__ o_n) {
    int tid = threadIdx.x;
    int wave = tid >> 6, lane = tid & 63;
    int r = blockIdx.x * 4 + wave;
    int t = r >> 4, h = r & 15;
    float v = bf2f(o_ws[(size_t)t * 1024 + h * DV + lane]);
    float ss = v * v;
    #pragma unroll
    for (int off = 32; off; off >>= 1) ss += __shfl_xor(ss, off);
    float rms = rsqrtf(ss * (1.f / 64.f) + 1e-5f);
    float g = bf2f(qkvg[(size_t)t * 3072 + 2048 + h * DV + lane]);
    float sw = g / (1.f + expf(-g));
    o_n[(size_t)t * 1024 + h * DV + lane] = f2bf(v * rms * gnw[lane] * sw);
}

// ---------------- launch ----------------
extern "C" void kernel_launch(void* const* d_in, const int* in_sizes, int n_in,
                              void* d_out, int out_size, void* d_ws, size_t ws_size,
                              hipStream_t stream) {
    const float* x    = (const float*)d_in[0];
    const float* Wq   = (const float*)d_in[1];
    const float* Wk   = (const float*)d_in[2];
    const float* Wv   = (const float*)d_in[3];
    const float* Wgk1 = (const float*)d_in[4];
    const float* Wgk2 = (const float*)d_in[5];
    const float* bgk2 = (const float*)d_in[6];
    const float* Wg   = (const float*)d_in[7];
    const float* gnw  = (const float*)d_in[8];
    const float* Wo   = (const float*)d_in[9];

    char* ws = (char*)d_ws;
    size_t off = 0;
    u16* xb     = (u16*)(ws + off); off += (size_t)MROWS * 1024 * 2;
    u16* WcatT  = (u16*)(ws + off); off += (size_t)3072 * 1024 * 2;
    u16* WoT    = (u16*)(ws + off); off += (size_t)1024 * 1024 * 2;
    u16* qkvg   = (u16*)(ws + off); off += (size_t)MROWS * 3072 * 2;
    float* gkp  = (float*)(ws + off); off += (size_t)MROWS * KD * 4;
    float* S_ws = (float*)(ws + off); off += (size_t)MROWS * KD * 4;
    float* M_ws = (float*)(ws + off); off += (size_t)NBH * NCH * 2048 * 4;
    float* D_ws = (float*)(ws + off); off += (size_t)NBH * NCH * 32 * 4;
    float* H_ws = (float*)(ws + off); off += (size_t)NBH * NCH * 2048 * 4;
    u16* o_scan = (u16*)(ws + off); off += (size_t)MROWS * 1024 * 2;
    u16* o_n    = (u16*)(ws + off); off += (size_t)MROWS * 1024 * 2;

    xcast_gate<<<MROWS / 8, 256, 0, stream>>>(x, xb, Wgk1, Wgk2, bgk2, gkp);
    transpose_to_bf16<<<dim3(16, 32), 256, 0, stream>>>(Wq, WcatT, 1024, 512);
    transpose_to_bf16<<<dim3(16, 32), 256, 0, stream>>>(Wk, WcatT + (size_t)512 * 1024, 1024, 512);
    transpose_to_bf16<<<dim3(32, 32), 256, 0, stream>>>(Wv, WcatT + (size_t)1024 * 1024, 1024, 1024);
    transpose_to_bf16<<<dim3(32, 32), 256, 0, stream>>>(Wg, WcatT + (size_t)2048 * 1024, 1024, 1024);
    transpose_to_bf16<<<dim3(32, 32), 256, 0, stream>>>(Wo, WoT, 1024, 1024);
    gemm_bt<1><<<dim3(24, 64), 256, 0, stream>>>(xb, WcatT, qkvg, MROWS, 3072, 1024);
    phaseA<<<NBH * NCH, 256, 0, stream>>>(qkvg, gkp, S_ws, M_ws, D_ws);
    phaseB<<<NBH, 256, 0, stream>>>(M_ws, D_ws, H_ws);
    phaseC<<<NBH * NCH, 256, 0, stream>>>(qkvg, S_ws, H_ws, o_scan);
    norm_gate<<<MROWS * HEADS / 4, 256, 0, stream>>>(o_scan, qkvg, gnw, o_n);
    gemm_bt<0><<<dim3(8, 64), 256, 0, stream>>>(o_n, WoT, d_out, MROWS, 1024, 1024);
}

// Round 3
// 279.251 us; speedup vs baseline: 1.8871x; 1.1264x over previous
//
#include <hip/hip_runtime.h>

typedef unsigned short u16;
typedef unsigned int u32;
typedef __attribute__((ext_vector_type(8))) short short8;
typedef __attribute__((ext_vector_type(4))) float f32x4;

#define KD 512
#define HEADS 16
#define DK 32
#define DV 64
#define TT 4096
#define MROWS 8192           // B*T
#define CHUNK 64
#define NCH 64               // T/CHUNK
#define NBH 32               // B*HEADS
#define QSTR 3200            // qkvg row stride (q 0 | k 512 | v 1024 | g 2048 | xg1 3072 | pad)
#define SCALE 0.17677669529663687f  // 32^-0.5

__device__ __forceinline__ u16 f2bf(float f) {
    union { float f; unsigned int u; } x; x.f = f;
    unsigned int u = x.u;
    unsigned int r = (u + 0x7fffu + ((u >> 16) & 1u)) >> 16;
    return (u16)r;
}
__device__ __forceinline__ float bf2f(u16 s) {
    union { unsigned int u; float f; } x; x.u = ((unsigned int)s) << 16;
    return x.f;
}
__device__ __forceinline__ void gload16(const u16* g, u16* l) {
    __builtin_amdgcn_global_load_lds((const __attribute__((address_space(1))) u32*)g,
                                     (__attribute__((address_space(3))) u32*)l, 16, 0, 0);
}

// ---------------- x f32 -> bf16 (coalesced) ----------------
__global__ __launch_bounds__(256) void f32_to_bf16_vec(const float* __restrict__ src,
                                                       u16* __restrict__ dst, int n4) {
    int i = blockIdx.x * 256 + threadIdx.x;
    if (i < n4) {
        const float4 v = ((const float4*)src)[i];
        ushort4 o;
        o.x = f2bf(v.x); o.y = f2bf(v.y); o.z = f2bf(v.z); o.w = f2bf(v.w);
        ((ushort4*)dst)[i] = o;
    }
}

// ---------------- W (K x N) f32 -> Wt (N x K) bf16 ----------------
__global__ __launch_bounds__(256) void transpose_to_bf16(const float* __restrict__ src,
                                                         u16* __restrict__ dst, int K, int N) {
    __shared__ float tile[32][33];
    int n0 = blockIdx.x * 32, k0 = blockIdx.y * 32;
    int tx = threadIdx.x & 31, ty = threadIdx.x >> 5;
    for (int r = ty; r < 32; r += 8)
        tile[r][tx] = src[(size_t)(k0 + r) * N + n0 + tx];
    __syncthreads();
    for (int r = ty; r < 32; r += 8)
        dst[(size_t)(n0 + r) * K + k0 + tx] = f2bf(tile[tx][r]);
}

// ---------------- W1 (1024x16) -> WcatT rows 3072..3087; rows 3088..3199 zero ----------------
__global__ __launch_bounds__(256) void w1_pad(const float* __restrict__ W1, u16* __restrict__ WcatT) {
    int n = 3072 + blockIdx.x;           // 3072..3199
    int k0 = threadIdx.x * 4;
    ushort4 o;
    if (n < 3088) {
        int j = n - 3072;
        o.x = f2bf(W1[(size_t)(k0 + 0) * 16 + j]);
        o.y = f2bf(W1[(size_t)(k0 + 1) * 16 + j]);
        o.z = f2bf(W1[(size_t)(k0 + 2) * 16 + j]);
        o.w = f2bf(W1[(size_t)(k0 + 3) * 16 + j]);
    } else {
        o.x = 0; o.y = 0; o.z = 0; o.w = 0;
    }
    *(ushort4*)(WcatT + (size_t)n * 1024 + k0) = o;
}

// ---------------- bf16 MFMA GEMM, m97 structure: global_load_lds + linear [128][32] LDS ----------------
template<int OUTBF>
__global__ __launch_bounds__(256) void gemm_lds(const u16* __restrict__ A,
                                                const u16* __restrict__ Bt,
                                                void* __restrict__ C,
                                                int M, int N, int K) {
    __shared__ u16 As[128 * 32];
    __shared__ u16 Bs[128 * 32];
    int tid = threadIdx.x;
    int wave = tid >> 6, lane = tid & 63;
    int wr = wave >> 1, wc = wave & 1;       // 2x2 waves, each owns 64x64
    int brow = blockIdx.y * 128, bcol = blockIdx.x * 128;
    // staging map: LDS elem tid*8 (+2048) <-> row tid/4 (+64), col (tid&3)*8
    int srow = tid >> 2, scol = (tid & 3) << 3;
    const u16* aS0 = A + (size_t)(brow + srow) * K + scol;
    const u16* aS1 = aS0 + (size_t)64 * K;
    const u16* bS0 = Bt + (size_t)(bcol + srow) * K + scol;
    const u16* bS1 = bS0 + (size_t)64 * K;
    u16* lA = As + tid * 8;
    u16* lB = Bs + tid * 8;
    f32x4 acc[4][4];
    #pragma unroll
    for (int mi = 0; mi < 4; ++mi)
        #pragma unroll
        for (int ni = 0; ni < 4; ++ni)
            acc[mi][ni] = (f32x4){0.f, 0.f, 0.f, 0.f};
    int l15 = lane & 15, lk = (lane >> 4) << 3;
    for (int kt = 0; kt < K; kt += 32) {
        __syncthreads();
        gload16(aS0 + kt, lA);
        gload16(aS1 + kt, lA + 2048);
        gload16(bS0 + kt, lB);
        gload16(bS1 + kt, lB + 2048);
        __syncthreads();   // drains vmcnt(0): LDS writes landed
        short8 af[4], bfr[4];
        #pragma unroll
        for (int i = 0; i < 4; ++i)
            af[i] = *(short8*)(As + (size_t)(wr * 64 + i * 16 + l15) * 32 + lk);
        #pragma unroll
        for (int i = 0; i < 4; ++i)
            bfr[i] = *(short8*)(Bs + (size_t)(wc * 64 + i * 16 + l15) * 32 + lk);
        #pragma unroll
        for (int mi = 0; mi < 4; ++mi)
            #pragma unroll
            for (int ni = 0; ni < 4; ++ni)
                acc[mi][ni] = __builtin_amdgcn_mfma_f32_16x16x32_bf16(af[mi], bfr[ni], acc[mi][ni], 0, 0, 0);
    }
    int r0 = brow + wr * 64 + ((lane >> 4) << 2);
    int c0 = bcol + wc * 64 + l15;
    #pragma unroll
    for (int mi = 0; mi < 4; ++mi)
        #pragma unroll
        for (int ni = 0; ni < 4; ++ni)
            #pragma unroll
            for (int rr = 0; rr < 4; ++rr) {
                size_t idx = (size_t)(r0 + mi * 16 + rr) * N + (c0 + ni * 16);
                float val = acc[mi][ni][rr];
                if (OUTBF) ((u16*)C)[idx] = f2bf(val);
                else       ((float*)C)[idx] = val;
            }
}

// ---------------- gate finish: gk = logsigmoid(xg1 @ W2 + b)/16 ----------------
__global__ __launch_bounds__(256) void gate_finish(const u16* __restrict__ qkvg,
                                                   const float* __restrict__ W2,
                                                   const float* __restrict__ b2,
                                                   float* __restrict__ gk) {
    int tid = threadIdx.x;
    int r = tid >> 5, c = tid & 31;
    int row = blockIdx.x * 8 + r;
    const u16* xg = qkvg + (size_t)row * QSTR + 3072;
    short8 x0 = *(const short8*)xg;
    short8 x1 = *(const short8*)(xg + 8);
    float xv[16];
    #pragma unroll
    for (int j = 0; j < 8; ++j) { xv[j] = bf2f((u16)x0[j]); xv[8 + j] = bf2f((u16)x1[j]); }
    int cc = c * 16;
    float z[16];
    {
        const float4* bp = (const float4*)(b2 + cc);
        float4 z0 = bp[0], z1 = bp[1], z2 = bp[2], z3 = bp[3];
        z[0]=z0.x; z[1]=z0.y; z[2]=z0.z; z[3]=z0.w;
        z[4]=z1.x; z[5]=z1.y; z[6]=z1.z; z[7]=z1.w;
        z[8]=z2.x; z[9]=z2.y; z[10]=z2.z; z[11]=z2.w;
        z[12]=z3.x; z[13]=z3.y; z[14]=z3.z; z[15]=z3.w;
    }
    #pragma unroll
    for (int u = 0; u < 16; ++u) {
        const float4* w = (const float4*)(W2 + (size_t)u * 512 + cc);
        float4 w0 = w[0], w1 = w[1], w2 = w[2], w3 = w[3];
        float xu = xv[u];
        z[0] += xu * w0.x; z[1] += xu * w0.y; z[2] += xu * w0.z; z[3] += xu * w0.w;
        z[4] += xu * w1.x; z[5] += xu * w1.y; z[6] += xu * w1.z; z[7] += xu * w1.w;
        z[8] += xu * w2.x; z[9] += xu * w2.y; z[10] += xu * w2.z; z[11] += xu * w2.w;
        z[12] += xu * w3.x; z[13] += xu * w3.y; z[14] += xu * w3.z; z[15] += xu * w3.w;
    }
    float* gp = gk + (size_t)row * 512 + cc;
    #pragma unroll
    for (int j = 0; j < 16; ++j) {
        float zz = z[j];
        float ls = fminf(zz, 0.f) - log1pf(expf(-fabsf(zz)));
        gp[j] = ls * 0.0625f;
    }
}

// ---------------- phase A: per-chunk cumsum S, decayed K^T V  ----------------
__global__ __launch_bounds__(256) void phaseA(const u16* __restrict__ qkvg,
                                              const float* __restrict__ gk,
                                              float* __restrict__ S_ws,
                                              float* __restrict__ M_ws,
                                              float* __restrict__ D_ws) {
    int bh = blockIdx.x >> 6, c = blockIdx.x & 63;
    int b = bh >> 4, h = bh & 15;
    int t0 = b * TT + c * CHUNK;
    __shared__ float gkS[64][36];
    __shared__ float k_l[64][36];
    __shared__ float kd[64][36];
    __shared__ float v_l[64][68];
    __shared__ float Z[32];
    int tid = threadIdx.x;
    int s = tid >> 2, i0 = (tid & 3) << 3;
    {
        const float* g = gk + (size_t)(t0 + s) * KD + h * DK + i0;
        float4 a = *(const float4*)g, bq = *(const float4*)(g + 4);
        *(float4*)&gkS[s][i0] = a;
        *(float4*)&gkS[s][i0 + 4] = bq;
    }
    {
        short8 kv = *(const short8*)(qkvg + (size_t)(t0 + s) * QSTR + 512 + h * DK + i0);
        #pragma unroll
        for (int jj = 0; jj < 8; ++jj) k_l[s][i0 + jj] = bf2f((u16)kv[jj]);
    }
    {
        int j0 = (tid & 3) << 4;
        short8 v0 = *(const short8*)(qkvg + (size_t)(t0 + s) * QSTR + 1024 + h * DV + j0);
        short8 v1 = *(const short8*)(qkvg + (size_t)(t0 + s) * QSTR + 1024 + h * DV + j0 + 8);
        #pragma unroll
        for (int jj = 0; jj < 8; ++jj) {
            v_l[s][j0 + jj] = bf2f((u16)v0[jj]);
            v_l[s][j0 + 8 + jj] = bf2f((u16)v1[jj]);
        }
    }
    __syncthreads();
    if (tid < 32) {
        float run = 0.f;
        for (int t = 0; t < 64; ++t) {
            run += gkS[t][tid];
            gkS[t][tid] = run;
        }
        Z[tid] = run;
    }
    __syncthreads();
    {
        float* sp = S_ws + (size_t)(t0 + s) * KD + h * DK + i0;
        *(float4*)sp = *(float4*)&gkS[s][i0];
        *(float4*)(sp + 4) = *(float4*)&gkS[s][i0 + 4];
        #pragma unroll
        for (int jj = 0; jj < 8; ++jj)
            kd[s][i0 + jj] = expf(Z[i0 + jj] - gkS[s][i0 + jj]) * k_l[s][i0 + jj];
    }
    __syncthreads();
    {
        int i = tid >> 4, j4 = tid & 15;
        int i2 = i + 16;
        float a0 = 0, a1 = 0, a2 = 0, a3 = 0, b0 = 0, b1 = 0, b2v = 0, b3 = 0;
        for (int ss = 0; ss < 64; ++ss) {
            float kd1 = kd[ss][i], kd2 = kd[ss][i2];
            const float4 vv = *(const float4*)&v_l[ss][j4 * 4];
            a0 += kd1 * vv.x; a1 += kd1 * vv.y; a2 += kd1 * vv.z; a3 += kd1 * vv.w;
            b0 += kd2 * vv.x; b1 += kd2 * vv.y; b2v += kd2 * vv.z; b3 += kd2 * vv.w;
        }
        size_t base = ((size_t)(bh * NCH + c)) * 2048;
        float4 o1; o1.x = a0; o1.y = a1; o1.z = a2; o1.w = a3;
        float4 o2; o2.x = b0; o2.y = b1; o2.z = b2v; o2.w = b3;
        *(float4*)(M_ws + base + i * 64 + j4 * 4) = o1;
        *(float4*)(M_ws + base + i2 * 64 + j4 * 4) = o2;
    }
    if (tid < 32) D_ws[(size_t)(bh * NCH + c) * 32 + tid] = expf(Z[tid]);
}

// ---------------- phase B: sequential chunk-state recurrence ----------------
__global__ __launch_bounds__(256) void phaseB(const float* __restrict__ M_ws,
                                              const float* __restrict__ D_ws,
                                              float* __restrict__ H_ws) {
    int bh = blockIdx.x;
    int tid = threadIdx.x;
    int i = tid >> 3, j0 = (tid & 7) << 3;
    float h[8];
    #pragma unroll
    for (int u = 0; u < 8; ++u) h[u] = 0.f;
    for (int c = 0; c < NCH; ++c) {
        size_t base = ((size_t)(bh * NCH + c)) * 2048 + i * 64 + j0;
        float4 h0; h0.x = h[0]; h0.y = h[1]; h0.z = h[2]; h0.w = h[3];
        float4 h1; h1.x = h[4]; h1.y = h[5]; h1.z = h[6]; h1.w = h[7];
        *(float4*)(H_ws + base) = h0;
        *(float4*)(H_ws + base + 4) = h1;
        float d = D_ws[(size_t)(bh * NCH + c) * 32 + i];
        const float4 m0 = *(const float4*)(M_ws + base);
        const float4 m1 = *(const float4*)(M_ws + base + 4);
        h[0] = h[0] * d + m0.x; h[1] = h[1] * d + m0.y;
        h[2] = h[2] * d + m0.z; h[3] = h[3] * d + m0.w;
        h[4] = h[4] * d + m1.x; h[5] = h[5] * d + m1.y;
        h[6] = h[6] * d + m1.z; h[7] = h[7] * d + m1.w;
    }
}

// ---------------- phase C: intra-chunk attn + inter-chunk output + fused RMSNorm/swish ----------------
__global__ __launch_bounds__(256) void phaseC(const u16* __restrict__ qkvg,
                                              const float* __restrict__ S_ws,
                                              const float* __restrict__ H_ws,
                                              const float* __restrict__ gnw,
                                              u16* __restrict__ o_n) {
    int bh = blockIdx.x >> 6, c = blockIdx.x & 63;
    int b = bh >> 4, h = bh & 15;
    int t0 = b * TT + c * CHUNK;
    __shared__ float qh[64][36];
    __shared__ float kt[64][36];
    __shared__ float v_l[64][68];
    __shared__ float H_l[32][68];
    __shared__ float A_l[64][68];
    int tid = threadIdx.x;
    int s = tid >> 2, i0 = (tid & 3) << 3;
    {
        const float* sp = S_ws + (size_t)(t0 + s) * KD + h * DK + i0;
        float4 S0 = *(const float4*)sp, S1 = *(const float4*)(sp + 4);
        short8 qv = *(const short8*)(qkvg + (size_t)(t0 + s) * QSTR + h * DK + i0);
        short8 kv = *(const short8*)(qkvg + (size_t)(t0 + s) * QSTR + 512 + h * DK + i0);
        float Sv[8] = {S0.x, S0.y, S0.z, S0.w, S1.x, S1.y, S1.z, S1.w};
        #pragma unroll
        for (int jj = 0; jj < 8; ++jj) {
            qh[s][i0 + jj] = bf2f((u16)qv[jj]) * expf(Sv[jj]) * SCALE;
            kt[s][i0 + jj] = bf2f((u16)kv[jj]) * expf(fminf(-Sv[jj], 80.f));
        }
    }
    {
        int j0 = (tid & 3) << 4;
        short8 v0 = *(const short8*)(qkvg + (size_t)(t0 + s) * QSTR + 1024 + h * DV + j0);
        short8 v1 = *(const short8*)(qkvg + (size_t)(t0 + s) * QSTR + 1024 + h * DV + j0 + 8);
        #pragma unroll
        for (int jj = 0; jj < 8; ++jj) {
            v_l[s][j0 + jj] = bf2f((u16)v0[jj]);
            v_l[s][j0 + 8 + jj] = bf2f((u16)v1[jj]);
        }
    }
    {
        int i = tid >> 3, j0 = (tid & 7) << 3;
        size_t base = ((size_t)(bh * NCH + c)) * 2048 + i * 64 + j0;
        *(float4*)&H_l[i][j0] = *(const float4*)(H_ws + base);
        *(float4*)&H_l[i][j0 + 4] = *(const float4*)(H_ws + base + 4);
    }
    __syncthreads();
    {
        int ta = tid >> 2, s0 = (tid & 3) << 4;
        for (int ss = s0; ss < s0 + 16; ++ss) {
            float a = 0.f;
            if (ss <= ta) {
                #pragma unroll 8
                for (int i = 0; i < 32; ++i) a += qh[ta][i] * kt[ss][i];
            }
            A_l[ta][ss] = a;
        }
    }
    __syncthreads();
    #pragma unroll
    for (int q4 = 0; q4 < 4; ++q4) {
        int slot = tid + q4 * 256;
        int t = slot >> 4, j4 = slot & 15;
        float a0 = 0, a1 = 0, a2 = 0, a3 = 0;
        #pragma unroll 8
        for (int i = 0; i < 32; ++i) {
            float qv = qh[t][i];
            const float4 hv = *(const float4*)&H_l[i][j4 * 4];
            a0 += qv * hv.x; a1 += qv * hv.y; a2 += qv * hv.z; a3 += qv * hv.w;
        }
        for (int ss = 0; ss <= t; ++ss) {
            float av = A_l[t][ss];
            const float4 vv = *(const float4*)&v_l[ss][j4 * 4];
            a0 += av * vv.x; a1 += av * vv.y; a2 += av * vv.z; a3 += av * vv.w;
        }
        // fused per-head RMSNorm + swish output gate (16-lane group = one (t,h) row)
        float ss2 = a0 * a0 + a1 * a1 + a2 * a2 + a3 * a3;
        ss2 += __shfl_xor(ss2, 1);
        ss2 += __shfl_xor(ss2, 2);
        ss2 += __shfl_xor(ss2, 4);
        ss2 += __shfl_xor(ss2, 8);
        float rms = rsqrtf(ss2 * (1.f / 64.f) + 1e-5f);
        const float4 gw = *(const float4*)(gnw + j4 * 4);
        ushort4 gv = *(const ushort4*)(qkvg + (size_t)(t0 + t) * QSTR + 2048 + h * DV + j4 * 4);
        float g0 = bf2f(gv.x), g1 = bf2f(gv.y), g2 = bf2f(gv.z), g3 = bf2f(gv.w);
        float o0 = a0 * rms * gw.x * (g0 / (1.f + expf(-g0)));
        float o1 = a1 * rms * gw.y * (g1 / (1.f + expf(-g1)));
        float o2 = a2 * rms * gw.z * (g2 / (1.f + expf(-g2)));
        float o3 = a3 * rms * gw.w * (g3 / (1.f + expf(-g3)));
        ushort4 ov;
        ov.x = f2bf(o0); ov.y = f2bf(o1); ov.z = f2bf(o2); ov.w = f2bf(o3);
        *(ushort4*)(o_n + (size_t)(t0 + t) * 1024 + h * DV + j4 * 4) = ov;
    }
}

// ---------------- launch ----------------
extern "C" void kernel_launch(void* const* d_in, const int* in_sizes, int n_in,
                              void* d_out, int out_size, void* d_ws, size_t ws_size,
                              hipStream_t stream) {
    const float* x    = (const float*)d_in[0];
    const float* Wq   = (const float*)d_in[1];
    const float* Wk   = (const float*)d_in[2];
    const float* Wv   = (const float*)d_in[3];
    const float* Wgk1 = (const float*)d_in[4];
    const float* Wgk2 = (const float*)d_in[5];
    const float* bgk2 = (const float*)d_in[6];
    const float* Wg   = (const float*)d_in[7];
    const float* gnw  = (const float*)d_in[8];
    const float* Wo   = (const float*)d_in[9];

    char* ws = (char*)d_ws;
    size_t off = 0;
    u16* xb     = (u16*)(ws + off); off += (size_t)MROWS * 1024 * 2;          // 16.8 MB
    u16* WcatT  = (u16*)(ws + off); off += (size_t)QSTR * 1024 * 2;           // 6.55 MB
    u16* WoT    = (u16*)(ws + off); off += (size_t)1024 * 1024 * 2;           // 2.1 MB
    u16* qkvg   = (u16*)(ws + off); off += (size_t)MROWS * QSTR * 2;          // 52.4 MB
    float* gkp  = (float*)(ws + off); off += (size_t)MROWS * KD * 4;          // 16.8 MB
    float* S_ws = (float*)(ws + off); off += (size_t)MROWS * KD * 4;          // 16.8 MB
    float* M_ws = (float*)(ws + off); off += (size_t)NBH * NCH * 2048 * 4;    // 16.8 MB
    float* D_ws = (float*)(ws + off); off += (size_t)NBH * NCH * 32 * 4;      // 0.26 MB
    float* H_ws = (float*)(ws + off); off += (size_t)NBH * NCH * 2048 * 4;    // 16.8 MB
    u16* o_n    = (u16*)(ws + off); off += (size_t)MROWS * 1024 * 2;          // 16.8 MB

    f32_to_bf16_vec<<<MROWS, 256, 0, stream>>>(x, xb, MROWS * 1024 / 4);
    transpose_to_bf16<<<dim3(16, 32), 256, 0, stream>>>(Wq, WcatT, 1024, 512);
    transpose_to_bf16<<<dim3(16, 32), 256, 0, stream>>>(Wk, WcatT + (size_t)512 * 1024, 1024, 512);
    transpose_to_bf16<<<dim3(32, 32), 256, 0, stream>>>(Wv, WcatT + (size_t)1024 * 1024, 1024, 1024);
    transpose_to_bf16<<<dim3(32, 32), 256, 0, stream>>>(Wg, WcatT + (size_t)2048 * 1024, 1024, 1024);
    transpose_to_bf16<<<dim3(32, 32), 256, 0, stream>>>(Wo, WoT, 1024, 1024);
    w1_pad<<<128, 256, 0, stream>>>(Wgk1, WcatT);
    gemm_lds<1><<<dim3(25, 64), 256, 0, stream>>>(xb, WcatT, qkvg, MROWS, QSTR, 1024);
    gate_finish<<<MROWS / 8, 256, 0, stream>>>(qkvg, Wgk2, bgk2, gkp);
    phaseA<<<NBH * NCH, 256, 0, stream>>>(qkvg, gkp, S_ws, M_ws, D_ws);
    phaseB<<<NBH, 256, 0, stream>>>(M_ws, D_ws, H_ws);
    phaseC<<<NBH * NCH, 256, 0, stream>>>(qkvg, S_ws, H_ws, gnw, o_n);
    gemm_lds<0><<<dim3(8, 64), 256, 0, stream>>>(o_n, WoT, d_out, MROWS, 1024, 1024);
}

// Round 4
// 267.222 us; speedup vs baseline: 1.9721x; 1.0450x over previous
//
#include <hip/hip_runtime.h>

typedef unsigned short u16;
typedef unsigned int u32;
typedef __attribute__((ext_vector_type(8))) short short8;
typedef __attribute__((ext_vector_type(4))) float f32x4;

#define KD 512
#define HEADS 16
#define DK 32
#define DV 64
#define TT 4096
#define MROWS 8192           // B*T
#define CHUNK 64
#define NCH 64               // T/CHUNK
#define NBH 32               // B*HEADS
#define QSTR 3200            // qkvg row stride (q 0 | k 512 | v 1024 | g 2048 | xg1 3072 | pad)
#define SCALE 0.17677669529663687f  // 32^-0.5

__device__ __forceinline__ u16 f2bf(float f) {
    union { float f; unsigned int u; } x; x.f = f;
    unsigned int u = x.u;
    unsigned int r = (u + 0x7fffu + ((u >> 16) & 1u)) >> 16;
    return (u16)r;
}
__device__ __forceinline__ float bf2f(u16 s) {
    union { unsigned int u; float f; } x; x.u = ((unsigned int)s) << 16;
    return x.f;
}
__device__ __forceinline__ void gload16(const u16* g, u16* l) {
    __builtin_amdgcn_global_load_lds((const __attribute__((address_space(1))) u32*)g,
                                     (__attribute__((address_space(3))) u32*)l, 16, 0, 0);
}

// ---------------- x f32 -> bf16 (coalesced) ----------------
__global__ __launch_bounds__(256) void f32_to_bf16_vec(const float* __restrict__ src,
                                                       u16* __restrict__ dst, int n4) {
    int i = blockIdx.x * 256 + threadIdx.x;
    if (i < n4) {
        const float4 v = ((const float4*)src)[i];
        ushort4 o;
        o.x = f2bf(v.x); o.y = f2bf(v.y); o.z = f2bf(v.z); o.w = f2bf(v.w);
        ((ushort4*)dst)[i] = o;
    }
}

// ---------------- W (K x N) f32 -> Wt (N x K) bf16 ----------------
__global__ __launch_bounds__(256) void transpose_to_bf16(const float* __restrict__ src,
                                                         u16* __restrict__ dst, int K, int N) {
    __shared__ float tile[32][33];
    int n0 = blockIdx.x * 32, k0 = blockIdx.y * 32;
    int tx = threadIdx.x & 31, ty = threadIdx.x >> 5;
    for (int r = ty; r < 32; r += 8)
        tile[r][tx] = src[(size_t)(k0 + r) * N + n0 + tx];
    __syncthreads();
    for (int r = ty; r < 32; r += 8)
        dst[(size_t)(n0 + r) * K + k0 + tx] = f2bf(tile[tx][r]);
}

// ---------------- W1 (1024x16) -> WcatT rows 3072..3087; rows 3088..3199 zero ----------------
__global__ __launch_bounds__(256) void w1_pad(const float* __restrict__ W1, u16* __restrict__ WcatT) {
    int n = 3072 + blockIdx.x;           // 3072..3199
    int k0 = threadIdx.x * 4;
    ushort4 o;
    if (n < 3088) {
        int j = n - 3072;
        o.x = f2bf(W1[(size_t)(k0 + 0) * 16 + j]);
        o.y = f2bf(W1[(size_t)(k0 + 1) * 16 + j]);
        o.z = f2bf(W1[(size_t)(k0 + 2) * 16 + j]);
        o.w = f2bf(W1[(size_t)(k0 + 3) * 16 + j]);
    } else {
        o.x = 0; o.y = 0; o.z = 0; o.w = 0;
    }
    *(ushort4*)(WcatT + (size_t)n * 1024 + k0) = o;
}

// ---------------- bf16 MFMA GEMM: 128x128 tile, BK=64, LDS dbuf, XOR-swizzled reads ----------------
// LDS layout (per buffer): [128 rows][64 u16], 128B rows. gload_lds dest is LINEAR
// (rule 21): the 16B granule at (r, g) holds global granule (r, g ^ (r&7)), achieved by
// pre-swizzling the GLOBAL source column; ds_read applies the same XOR -> 2-way banks (free).
template<int OUTBF>
__global__ __launch_bounds__(256) void gemm_db(const u16* __restrict__ A,
                                               const u16* __restrict__ Bt,
                                               void* __restrict__ C,
                                               int M, int N, int K) {
    __shared__ u16 As[2][128 * 64];
    __shared__ u16 Bs[2][128 * 64];
    int tid = threadIdx.x;
    int wave = tid >> 6, lane = tid & 63;
    int wr = wave >> 1, wc = wave & 1;       // 2x2 waves, each owns 64x64
    int brow = blockIdx.y * 128, bcol = blockIdx.x * 128;
    // staging: instruction i covers rows i*32 .. i*32+31; thread t -> row i*32 + (t>>3),
    // source granule = (t&7) ^ ((t>>3)&7)  (row&7 == (t>>3)&7 since i*32 % 8 == 0)
    int srow = tid >> 3;
    int sgrp = (tid & 7) ^ (srow & 7);
    const u16* aS = A + (size_t)(brow + srow) * K + sgrp * 8;
    const u16* bS = Bt + (size_t)(bcol + srow) * K + sgrp * 8;
    f32x4 acc[4][4];
    #pragma unroll
    for (int mi = 0; mi < 4; ++mi)
        #pragma unroll
        for (int ni = 0; ni < 4; ++ni)
            acc[mi][ni] = (f32x4){0.f, 0.f, 0.f, 0.f};
    int l15 = lane & 15, hi = lane >> 4;     // hi = k-granule 0..3
    int rxor = l15 & 7;                      // row&7 for fragment rows (i*16 keeps it)

    #define STAGE(B_, KOF_) do {                                   \
        u16* la_ = As[B_] + tid * 8;                               \
        u16* lb_ = Bs[B_] + tid * 8;                               \
        _Pragma("unroll")                                          \
        for (int i_ = 0; i_ < 4; ++i_) {                           \
            gload16(aS + (size_t)i_ * 32 * K + (KOF_), la_ + i_ * 2048); \
            gload16(bS + (size_t)i_ * 32 * K + (KOF_), lb_ + i_ * 2048); \
        }                                                          \
    } while (0)

    int cur = 0;
    STAGE(0, 0);
    __syncthreads();
    for (int kt = 0; kt < K; kt += 64) {
        if (kt + 64 < K) STAGE(cur ^ 1, kt + 64);   // loads fly under this tile's compute
        const u16* Ab = As[cur];
        const u16* Bb = Bs[cur];
        #pragma unroll
        for (int ks = 0; ks < 2; ++ks) {
            short8 af[4], bfr[4];
            int g = (ks * 4 + hi);
            #pragma unroll
            for (int i = 0; i < 4; ++i)
                af[i] = *(const short8*)(Ab + (size_t)(wr * 64 + i * 16 + l15) * 64 + ((g ^ rxor) << 3));
            #pragma unroll
            for (int i = 0; i < 4; ++i)
                bfr[i] = *(const short8*)(Bb + (size_t)(wc * 64 + i * 16 + l15) * 64 + ((g ^ rxor) << 3));
            #pragma unroll
            for (int mi = 0; mi < 4; ++mi)
                #pragma unroll
                for (int ni = 0; ni < 4; ++ni)
                    acc[mi][ni] = __builtin_amdgcn_mfma_f32_16x16x32_bf16(af[mi], bfr[ni], acc[mi][ni], 0, 0, 0);
        }
        __syncthreads();   // waves done reading cur; next tile's LDS writes landed
        cur ^= 1;
    }
    #undef STAGE

    int r0 = brow + wr * 64 + (hi << 2);
    int c0 = bcol + wc * 64 + l15;
    #pragma unroll
    for (int mi = 0; mi < 4; ++mi)
        #pragma unroll
        for (int ni = 0; ni < 4; ++ni)
            #pragma unroll
            for (int rr = 0; rr < 4; ++rr) {
                size_t idx = (size_t)(r0 + mi * 16 + rr) * N + (c0 + ni * 16);
                float val = acc[mi][ni][rr];
                if (OUTBF) ((u16*)C)[idx] = f2bf(val);
                else       ((float*)C)[idx] = val;
            }
}

// ---------------- gate finish: gk = logsigmoid(xg1 @ W2 + b)/16 ----------------
__global__ __launch_bounds__(256) void gate_finish(const u16* __restrict__ qkvg,
                                                   const float* __restrict__ W2,
                                                   const float* __restrict__ b2,
                                                   float* __restrict__ gk) {
    int tid = threadIdx.x;
    int r = tid >> 5, c = tid & 31;
    int row = blockIdx.x * 8 + r;
    const u16* xg = qkvg + (size_t)row * QSTR + 3072;
    short8 x0 = *(const short8*)xg;
    short8 x1 = *(const short8*)(xg + 8);
    float xv[16];
    #pragma unroll
    for (int j = 0; j < 8; ++j) { xv[j] = bf2f((u16)x0[j]); xv[8 + j] = bf2f((u16)x1[j]); }
    int cc = c * 16;
    float z[16];
    {
        const float4* bp = (const float4*)(b2 + cc);
        float4 z0 = bp[0], z1 = bp[1], z2 = bp[2], z3 = bp[3];
        z[0]=z0.x; z[1]=z0.y; z[2]=z0.z; z[3]=z0.w;
        z[4]=z1.x; z[5]=z1.y; z[6]=z1.z; z[7]=z1.w;
        z[8]=z2.x; z[9]=z2.y; z[10]=z2.z; z[11]=z2.w;
        z[12]=z3.x; z[13]=z3.y; z[14]=z3.z; z[15]=z3.w;
    }
    #pragma unroll
    for (int u = 0; u < 16; ++u) {
        const float4* w = (const float4*)(W2 + (size_t)u * 512 + cc);
        float4 w0 = w[0], w1 = w[1], w2 = w[2], w3 = w[3];
        float xu = xv[u];
        z[0] += xu * w0.x; z[1] += xu * w0.y; z[2] += xu * w0.z; z[3] += xu * w0.w;
        z[4] += xu * w1.x; z[5] += xu * w1.y; z[6] += xu * w1.z; z[7] += xu * w1.w;
        z[8] += xu * w2.x; z[9] += xu * w2.y; z[10] += xu * w2.z; z[11] += xu * w2.w;
        z[12] += xu * w3.x; z[13] += xu * w3.y; z[14] += xu * w3.z; z[15] += xu * w3.w;
    }
    float* gp = gk + (size_t)row * 512 + cc;
    #pragma unroll
    for (int j = 0; j < 16; ++j) {
        float zz = z[j];
        float ls = fminf(zz, 0.f) - log1pf(expf(-fabsf(zz)));
        gp[j] = ls * 0.0625f;
    }
}

// ---------------- phase A: per-chunk cumsum S, decayed K^T V  ----------------
__global__ __launch_bounds__(256) void phaseA(const u16* __restrict__ qkvg,
                                              const float* __restrict__ gk,
                                              float* __restrict__ S_ws,
                                              float* __restrict__ M_ws,
                                              float* __restrict__ D_ws) {
    int bh = blockIdx.x >> 6, c = blockIdx.x & 63;
    int b = bh >> 4, h = bh & 15;
    int t0 = b * TT + c * CHUNK;
    __shared__ float gkS[64][36];
    __shared__ float k_l[64][36];
    __shared__ float kd[64][36];
    __shared__ float v_l[64][68];
    __shared__ float Z[32];
    int tid = threadIdx.x;
    int s = tid >> 2, i0 = (tid & 3) << 3;
    {
        const float* g = gk + (size_t)(t0 + s) * KD + h * DK + i0;
        float4 a = *(const float4*)g, bq = *(const float4*)(g + 4);
        *(float4*)&gkS[s][i0] = a;
        *(float4*)&gkS[s][i0 + 4] = bq;
    }
    {
        short8 kv = *(const short8*)(qkvg + (size_t)(t0 + s) * QSTR + 512 + h * DK + i0);
        #pragma unroll
        for (int jj = 0; jj < 8; ++jj) k_l[s][i0 + jj] = bf2f((u16)kv[jj]);
    }
    {
        int j0 = (tid & 3) << 4;
        short8 v0 = *(const short8*)(qkvg + (size_t)(t0 + s) * QSTR + 1024 + h * DV + j0);
        short8 v1 = *(const short8*)(qkvg + (size_t)(t0 + s) * QSTR + 1024 + h * DV + j0 + 8);
        #pragma unroll
        for (int jj = 0; jj < 8; ++jj) {
            v_l[s][j0 + jj] = bf2f((u16)v0[jj]);
            v_l[s][j0 + 8 + jj] = bf2f((u16)v1[jj]);
        }
    }
    __syncthreads();
    if (tid < 32) {
        float run = 0.f;
        for (int t = 0; t < 64; ++t) {
            run += gkS[t][tid];
            gkS[t][tid] = run;
        }
        Z[tid] = run;
    }
    __syncthreads();
    {
        float* sp = S_ws + (size_t)(t0 + s) * KD + h * DK + i0;
        *(float4*)sp = *(float4*)&gkS[s][i0];
        *(float4*)(sp + 4) = *(float4*)&gkS[s][i0 + 4];
        #pragma unroll
        for (int jj = 0; jj < 8; ++jj)
            kd[s][i0 + jj] = expf(Z[i0 + jj] - gkS[s][i0 + jj]) * k_l[s][i0 + jj];
    }
    __syncthreads();
    {
        int i = tid >> 4, j4 = tid & 15;
        int i2 = i + 16;
        float a0 = 0, a1 = 0, a2 = 0, a3 = 0, b0 = 0, b1 = 0, b2v = 0, b3 = 0;
        for (int ss = 0; ss < 64; ++ss) {
            float kd1 = kd[ss][i], kd2 = kd[ss][i2];
            const float4 vv = *(const float4*)&v_l[ss][j4 * 4];
            a0 += kd1 * vv.x; a1 += kd1 * vv.y; a2 += kd1 * vv.z; a3 += kd1 * vv.w;
            b0 += kd2 * vv.x; b1 += kd2 * vv.y; b2v += kd2 * vv.z; b3 += kd2 * vv.w;
        }
        size_t base = ((size_t)(bh * NCH + c)) * 2048;
        float4 o1; o1.x = a0; o1.y = a1; o1.z = a2; o1.w = a3;
        float4 o2; o2.x = b0; o2.y = b1; o2.z = b2v; o2.w = b3;
        *(float4*)(M_ws + base + i * 64 + j4 * 4) = o1;
        *(float4*)(M_ws + base + i2 * 64 + j4 * 4) = o2;
    }
    if (tid < 32) D_ws[(size_t)(bh * NCH + c) * 32 + tid] = expf(Z[tid]);
}

// ---------------- phase B: sequential chunk-state recurrence ----------------
__global__ __launch_bounds__(256) void phaseB(const float* __restrict__ M_ws,
                                              const float* __restrict__ D_ws,
                                              float* __restrict__ H_ws) {
    int bh = blockIdx.x;
    int tid = threadIdx.x;
    int i = tid >> 3, j0 = (tid & 7) << 3;
    float h[8];
    #pragma unroll
    for (int u = 0; u < 8; ++u) h[u] = 0.f;
    for (int c = 0; c < NCH; ++c) {
        size_t base = ((size_t)(bh * NCH + c)) * 2048 + i * 64 + j0;
        float4 h0; h0.x = h[0]; h0.y = h[1]; h0.z = h[2]; h0.w = h[3];
        float4 h1; h1.x = h[4]; h1.y = h[5]; h1.z = h[6]; h1.w = h[7];
        *(float4*)(H_ws + base) = h0;
        *(float4*)(H_ws + base + 4) = h1;
        float d = D_ws[(size_t)(bh * NCH + c) * 32 + i];
        const float4 m0 = *(const float4*)(M_ws + base);
        const float4 m1 = *(const float4*)(M_ws + base + 4);
        h[0] = h[0] * d + m0.x; h[1] = h[1] * d + m0.y;
        h[2] = h[2] * d + m0.z; h[3] = h[3] * d + m0.w;
        h[4] = h[4] * d + m1.x; h[5] = h[5] * d + m1.y;
        h[6] = h[6] * d + m1.z; h[7] = h[7] * d + m1.w;
    }
}

// ---------------- phase C: intra-chunk attn + inter-chunk output + fused RMSNorm/swish ----------------
__global__ __launch_bounds__(256) void phaseC(const u16* __restrict__ qkvg,
                                              const float* __restrict__ S_ws,
                                              const float* __restrict__ H_ws,
                                              const float* __restrict__ gnw,
                                              u16* __restrict__ o_n) {
    int bh = blockIdx.x >> 6, c = blockIdx.x & 63;
    int b = bh >> 4, h = bh & 15;
    int t0 = b * TT + c * CHUNK;
    __shared__ float qh[64][36];
    __shared__ float kt[64][36];
    __shared__ float v_l[64][68];
    __shared__ float H_l[32][68];
    __shared__ float A_l[64][68];
    int tid = threadIdx.x;
    int s = tid >> 2, i0 = (tid & 3) << 3;
    {
        const float* sp = S_ws + (size_t)(t0 + s) * KD + h * DK + i0;
        float4 S0 = *(const float4*)sp, S1 = *(const float4*)(sp + 4);
        short8 qv = *(const short8*)(qkvg + (size_t)(t0 + s) * QSTR + h * DK + i0);
        short8 kv = *(const short8*)(qkvg + (size_t)(t0 + s) * QSTR + 512 + h * DK + i0);
        float Sv[8] = {S0.x, S0.y, S0.z, S0.w, S1.x, S1.y, S1.z, S1.w};
        #pragma unroll
        for (int jj = 0; jj < 8; ++jj) {
            qh[s][i0 + jj] = bf2f((u16)qv[jj]) * expf(Sv[jj]) * SCALE;
            kt[s][i0 + jj] = bf2f((u16)kv[jj]) * expf(fminf(-Sv[jj], 80.f));
        }
    }
    {
        int j0 = (tid & 3) << 4;
        short8 v0 = *(const short8*)(qkvg + (size_t)(t0 + s) * QSTR + 1024 + h * DV + j0);
        short8 v1 = *(const short8*)(qkvg + (size_t)(t0 + s) * QSTR + 1024 + h * DV + j0 + 8);
        #pragma unroll
        for (int jj = 0; jj < 8; ++jj) {
            v_l[s][j0 + jj] = bf2f((u16)v0[jj]);
            v_l[s][j0 + 8 + jj] = bf2f((u16)v1[jj]);
        }
    }
    {
        int i = tid >> 3, j0 = (tid & 7) << 3;
        size_t base = ((size_t)(bh * NCH + c)) * 2048 + i * 64 + j0;
        *(float4*)&H_l[i][j0] = *(const float4*)(H_ws + base);
        *(float4*)&H_l[i][j0 + 4] = *(const float4*)(H_ws + base + 4);
    }
    __syncthreads();
    {
        int ta = tid >> 2, s0 = (tid & 3) << 4;
        for (int ss = s0; ss < s0 + 16; ++ss) {
            float a = 0.f;
            if (ss <= ta) {
                #pragma unroll 8
                for (int i = 0; i < 32; ++i) a += qh[ta][i] * kt[ss][i];
            }
            A_l[ta][ss] = a;
        }
    }
    __syncthreads();
    #pragma unroll
    for (int q4 = 0; q4 < 4; ++q4) {
        int slot = tid + q4 * 256;
        int t = slot >> 4, j4 = slot & 15;
        float a0 = 0, a1 = 0, a2 = 0, a3 = 0;
        #pragma unroll 8
        for (int i = 0; i < 32; ++i) {
            float qv = qh[t][i];
            const float4 hv = *(const float4*)&H_l[i][j4 * 4];
            a0 += qv * hv.x; a1 += qv * hv.y; a2 += qv * hv.z; a3 += qv * hv.w;
        }
        for (int ss = 0; ss <= t; ++ss) {
            float av = A_l[t][ss];
            const float4 vv = *(const float4*)&v_l[ss][j4 * 4];
            a0 += av * vv.x; a1 += av * vv.y; a2 += av * vv.z; a3 += av * vv.w;
        }
        float ss2 = a0 * a0 + a1 * a1 + a2 * a2 + a3 * a3;
        ss2 += __shfl_xor(ss2, 1);
        ss2 += __shfl_xor(ss2, 2);
        ss2 += __shfl_xor(ss2, 4);
        ss2 += __shfl_xor(ss2, 8);
        float rms = rsqrtf(ss2 * (1.f / 64.f) + 1e-5f);
        const float4 gw = *(const float4*)(gnw + j4 * 4);
        ushort4 gv = *(const ushort4*)(qkvg + (size_t)(t0 + t) * QSTR + 2048 + h * DV + j4 * 4);
        float g0 = bf2f(gv.x), g1 = bf2f(gv.y), g2 = bf2f(gv.z), g3 = bf2f(gv.w);
        float o0 = a0 * rms * gw.x * (g0 / (1.f + expf(-g0)));
        float o1 = a1 * rms * gw.y * (g1 / (1.f + expf(-g1)));
        float o2 = a2 * rms * gw.z * (g2 / (1.f + expf(-g2)));
        float o3 = a3 * rms * gw.w * (g3 / (1.f + expf(-g3)));
        ushort4 ov;
        ov.x = f2bf(o0); ov.y = f2bf(o1); ov.z = f2bf(o2); ov.w = f2bf(o3);
        *(ushort4*)(o_n + (size_t)(t0 + t) * 1024 + h * DV + j4 * 4) = ov;
    }
}

// ---------------- launch ----------------
extern "C" void kernel_launch(void* const* d_in, const int* in_sizes, int n_in,
                              void* d_out, int out_size, void* d_ws, size_t ws_size,
                              hipStream_t stream) {
    const float* x    = (const float*)d_in[0];
    const float* Wq   = (const float*)d_in[1];
    const float* Wk   = (const float*)d_in[2];
    const float* Wv   = (const float*)d_in[3];
    const float* Wgk1 = (const float*)d_in[4];
    const float* Wgk2 = (const float*)d_in[5];
    const float* bgk2 = (const float*)d_in[6];
    const float* Wg   = (const float*)d_in[7];
    const float* gnw  = (const float*)d_in[8];
    const float* Wo   = (const float*)d_in[9];

    char* ws = (char*)d_ws;
    size_t off = 0;
    u16* xb     = (u16*)(ws + off); off += (size_t)MROWS * 1024 * 2;
    u16* WcatT  = (u16*)(ws + off); off += (size_t)QSTR * 1024 * 2;
    u16* WoT    = (u16*)(ws + off); off += (size_t)1024 * 1024 * 2;
    u16* qkvg   = (u16*)(ws + off); off += (size_t)MROWS * QSTR * 2;
    float* gkp  = (float*)(ws + off); off += (size_t)MROWS * KD * 4;
    float* S_ws = (float*)(ws + off); off += (size_t)MROWS * KD * 4;
    float* M_ws = (float*)(ws + off); off += (size_t)NBH * NCH * 2048 * 4;
    float* D_ws = (float*)(ws + off); off += (size_t)NBH * NCH * 32 * 4;
    float* H_ws = (float*)(ws + off); off += (size_t)NBH * NCH * 2048 * 4;
    u16* o_n    = (u16*)(ws + off); off += (size_t)MROWS * 1024 * 2;

    f32_to_bf16_vec<<<MROWS, 256, 0, stream>>>(x, xb, MROWS * 1024 / 4);
    transpose_to_bf16<<<dim3(16, 32), 256, 0, stream>>>(Wq, WcatT, 1024, 512);
    transpose_to_bf16<<<dim3(16, 32), 256, 0, stream>>>(Wk, WcatT + (size_t)512 * 1024, 1024, 512);
    transpose_to_bf16<<<dim3(32, 32), 256, 0, stream>>>(Wv, WcatT + (size_t)1024 * 1024, 1024, 1024);
    transpose_to_bf16<<<dim3(32, 32), 256, 0, stream>>>(Wg, WcatT + (size_t)2048 * 1024, 1024, 1024);
    transpose_to_bf16<<<dim3(32, 32), 256, 0, stream>>>(Wo, WoT, 1024, 1024);
    w1_pad<<<128, 256, 0, stream>>>(Wgk1, WcatT);
    gemm_db<1><<<dim3(25, 64), 256, 0, stream>>>(xb, WcatT, qkvg, MROWS, QSTR, 1024);
    gate_finish<<<MROWS / 8, 256, 0, stream>>>(qkvg, Wgk2, bgk2, gkp);
    phaseA<<<NBH * NCH, 256, 0, stream>>>(qkvg, gkp, S_ws, M_ws, D_ws);
    phaseB<<<NBH, 256, 0, stream>>>(M_ws, D_ws, H_ws);
    phaseC<<<NBH * NCH, 256, 0, stream>>>(qkvg, S_ws, H_ws, gnw, o_n);
    gemm_db<0><<<dim3(8, 64), 256, 0, stream>>>(o_n, WoT, d_out, MROWS, 1024, 1024);
}

// Round 5
// 237.319 us; speedup vs baseline: 2.2206x; 1.1260x over previous
//
#include <hip/hip_runtime.h>

typedef unsigned short u16;
typedef unsigned int u32;
typedef __attribute__((ext_vector_type(8))) short short8;
typedef __attribute__((ext_vector_type(4))) float f32x4;

#define KD 512
#define HEADS 16
#define DK 32
#define DV 64
#define TT 4096
#define MROWS 8192           // B*T
#define CHUNK 64
#define NCH 64               // T/CHUNK
#define NBH 32               // B*HEADS
#define QSTR 3200            // qkvg row stride (q 0 | k 512 | v 1024 | g 2048 | xg1 3072 | pad)
#define SCALE 0.17677669529663687f  // 32^-0.5

__device__ __forceinline__ u16 f2bf(float f) {
    union { float f; unsigned int u; } x; x.f = f;
    unsigned int u = x.u;
    unsigned int r = (u + 0x7fffu + ((u >> 16) & 1u)) >> 16;
    return (u16)r;
}
__device__ __forceinline__ float bf2f(u16 s) {
    union { unsigned int u; float f; } x; x.u = ((unsigned int)s) << 16;
    return x.f;
}
__device__ __forceinline__ void gload16(const u16* g, u16* l) {
    __builtin_amdgcn_global_load_lds((const __attribute__((address_space(1))) u32*)g,
                                     (__attribute__((address_space(3))) u32*)l, 16, 0, 0);
}

// ---------------- x f32 -> bf16 (coalesced) ----------------
__global__ __launch_bounds__(256) void f32_to_bf16_vec(const float* __restrict__ src,
                                                       u16* __restrict__ dst, int n4) {
    int i = blockIdx.x * 256 + threadIdx.x;
    if (i < n4) {
        const float4 v = ((const float4*)src)[i];
        ushort4 o;
        o.x = f2bf(v.x); o.y = f2bf(v.y); o.z = f2bf(v.z); o.w = f2bf(v.w);
        ((ushort4*)dst)[i] = o;
    }
}

// ---------------- all weights -> transposed bf16, one kernel ----------------
// dst rows: [0,512) WqT | [512,1024) WkT | [1024,2048) WvT | [2048,3072) WgT
//           [3072,3088) W1T | [3088,3200) zero | [3200,4224) WoT
__global__ __launch_bounds__(256) void weight_prep(const float* __restrict__ Wq,
                                                   const float* __restrict__ Wk,
                                                   const float* __restrict__ Wv,
                                                   const float* __restrict__ Wg,
                                                   const float* __restrict__ W1,
                                                   const float* __restrict__ Wo,
                                                   u16* __restrict__ dst) {
    __shared__ float tile[32][33];
    int n0 = blockIdx.x * 32, k0 = blockIdx.y * 32;
    int tx = threadIdx.x & 31, ty = threadIdx.x >> 5;
    int n = n0 + tx;
    const float* src; int sN, cc;
    if (n < 512)       { src = Wq; sN = 512;  cc = n; }
    else if (n < 1024) { src = Wk; sN = 512;  cc = n - 512; }
    else if (n < 2048) { src = Wv; sN = 1024; cc = n - 1024; }
    else if (n < 3072) { src = Wg; sN = 1024; cc = n - 2048; }
    else if (n < 3088) { src = W1; sN = 16;   cc = n - 3072; }
    else if (n < 3200) { src = nullptr; sN = 0; cc = 0; }
    else               { src = Wo; sN = 1024; cc = n - 3200; }
    for (int r = ty; r < 32; r += 8)
        tile[r][tx] = src ? src[(size_t)(k0 + r) * sN + cc] : 0.f;
    __syncthreads();
    for (int r = ty; r < 32; r += 8)
        dst[(size_t)(n0 + r) * 1024 + k0 + tx] = f2bf(tile[tx][r]);
}

// ---------------- bf16 MFMA GEMM: 128x128, BK=64, single-buffer, XOR swizzle, XCD swizzle ----
// LDS [128 rows][64 u16]: granule (r,g) holds global granule (g ^ (r&7)) via pre-swizzled
// source (rule 21); ds_read applies the same XOR -> conflict-free. nwg must be %8==0.
template<int OUTBF>
__global__ __launch_bounds__(256) void gemm_sb(const u16* __restrict__ A,
                                               const u16* __restrict__ Bt,
                                               void* __restrict__ C,
                                               int M, int N, int K, int nbx) {
    __shared__ u16 As[128 * 64];
    __shared__ u16 Bs[128 * 64];
    int nwg = gridDim.x;
    int bid = blockIdx.x;
    int cpx = nwg >> 3;
    int wg = (bid & 7) * cpx + (bid >> 3);   // XCD-chunked, bijective (nwg%8==0)
    int bx = wg % nbx, by = wg / nbx;
    int tid = threadIdx.x;
    int wave = tid >> 6, lane = tid & 63;
    int wr = wave >> 1, wc = wave & 1;       // 2x2 waves, each owns 64x64
    int brow = by * 128, bcol = bx * 128;
    int srow = tid >> 3;
    int sgrp = (tid & 7) ^ (srow & 7);
    const u16* aS = A + (size_t)(brow + srow) * K + sgrp * 8;
    const u16* bS = Bt + (size_t)(bcol + srow) * K + sgrp * 8;
    f32x4 acc[4][4];
    #pragma unroll
    for (int mi = 0; mi < 4; ++mi)
        #pragma unroll
        for (int ni = 0; ni < 4; ++ni)
            acc[mi][ni] = (f32x4){0.f, 0.f, 0.f, 0.f};
    int l15 = lane & 15, hi = lane >> 4;
    int rxor = l15 & 7;
    for (int kt = 0; kt < K; kt += 64) {
        __syncthreads();                      // prev-iter LDS reads done
        #pragma unroll
        for (int i_ = 0; i_ < 4; ++i_) {
            gload16(aS + (size_t)i_ * 32 * K + kt, As + tid * 8 + i_ * 2048);
            gload16(bS + (size_t)i_ * 32 * K + kt, Bs + tid * 8 + i_ * 2048);
        }
        __syncthreads();                      // vmcnt(0) drain: LDS writes landed
        #pragma unroll
        for (int ks = 0; ks < 2; ++ks) {
            short8 af[4], bfr[4];
            int g = ks * 4 + hi;
            #pragma unroll
            for (int i = 0; i < 4; ++i)
                af[i] = *(const short8*)(As + (size_t)(wr * 64 + i * 16 + l15) * 64 + ((g ^ rxor) << 3));
            #pragma unroll
            for (int i = 0; i < 4; ++i)
                bfr[i] = *(const short8*)(Bs + (size_t)(wc * 64 + i * 16 + l15) * 64 + ((g ^ rxor) << 3));
            #pragma unroll
            for (int mi = 0; mi < 4; ++mi)
                #pragma unroll
                for (int ni = 0; ni < 4; ++ni)
                    acc[mi][ni] = __builtin_amdgcn_mfma_f32_16x16x32_bf16(af[mi], bfr[ni], acc[mi][ni], 0, 0, 0);
        }
    }
    int r0 = brow + wr * 64 + (hi << 2);
    int c0 = bcol + wc * 64 + l15;
    #pragma unroll
    for (int mi = 0; mi < 4; ++mi)
        #pragma unroll
        for (int ni = 0; ni < 4; ++ni)
            #pragma unroll
            for (int rr = 0; rr < 4; ++rr) {
                size_t idx = (size_t)(r0 + mi * 16 + rr) * N + (c0 + ni * 16);
                float val = acc[mi][ni][rr];
                if (OUTBF) ((u16*)C)[idx] = f2bf(val);
                else       ((float*)C)[idx] = val;
            }
}

// ---------------- gate slice: ls[j] = logsigmoid(xg1·W2[:,cc+j] + b2)/16, j=0..7 ----------------
__device__ __forceinline__ void gate_z8(const u16* __restrict__ xg,
                                        const float* __restrict__ W2,
                                        const float* __restrict__ b2,
                                        int cc, float* out8) {
    short8 x0 = *(const short8*)xg;
    short8 x1 = *(const short8*)(xg + 8);
    float z[8];
    float4 z0 = *(const float4*)(b2 + cc);
    float4 z1 = *(const float4*)(b2 + cc + 4);
    z[0]=z0.x; z[1]=z0.y; z[2]=z0.z; z[3]=z0.w;
    z[4]=z1.x; z[5]=z1.y; z[6]=z1.z; z[7]=z1.w;
    #pragma unroll
    for (int u = 0; u < 16; ++u) {
        float xu = bf2f((u16)(u < 8 ? x0[u] : x1[u - 8]));
        const float4 w0 = *(const float4*)(W2 + (size_t)u * 512 + cc);
        const float4 w1 = *(const float4*)(W2 + (size_t)u * 512 + cc + 4);
        z[0] += xu * w0.x; z[1] += xu * w0.y; z[2] += xu * w0.z; z[3] += xu * w0.w;
        z[4] += xu * w1.x; z[5] += xu * w1.y; z[6] += xu * w1.z; z[7] += xu * w1.w;
    }
    #pragma unroll
    for (int j = 0; j < 8; ++j) {
        float zz = z[j];
        out8[j] = (fminf(zz, 0.f) - log1pf(expf(-fabsf(zz)))) * 0.0625f;
    }
}

// ---------------- phase A: gate + cumsum + decayed K^T V -> M, D ----------------
__global__ __launch_bounds__(256) void phaseA(const u16* __restrict__ qkvg,
                                              const float* __restrict__ W2,
                                              const float* __restrict__ b2,
                                              float* __restrict__ M_ws,
                                              float* __restrict__ D_ws) {
    int bh = blockIdx.x >> 6, c = blockIdx.x & 63;
    int b = bh >> 4, h = bh & 15;
    int t0 = b * TT + c * CHUNK;
    __shared__ float gkS[64][36];
    __shared__ float k_l[64][36];
    __shared__ float kd[64][36];
    __shared__ float v_l[64][68];
    __shared__ float Z[32];
    int tid = threadIdx.x;
    int s = tid >> 2, i0 = (tid & 3) << 3;
    {
        float ls[8];
        gate_z8(qkvg + (size_t)(t0 + s) * QSTR + 3072, W2, b2, h * DK + i0, ls);
        #pragma unroll
        for (int jj = 0; jj < 8; ++jj) gkS[s][i0 + jj] = ls[jj];
    }
    {
        short8 kv = *(const short8*)(qkvg + (size_t)(t0 + s) * QSTR + 512 + h * DK + i0);
        #pragma unroll
        for (int jj = 0; jj < 8; ++jj) k_l[s][i0 + jj] = bf2f((u16)kv[jj]);
    }
    {
        int j0 = (tid & 3) << 4;
        short8 v0 = *(const short8*)(qkvg + (size_t)(t0 + s) * QSTR + 1024 + h * DV + j0);
        short8 v1 = *(const short8*)(qkvg + (size_t)(t0 + s) * QSTR + 1024 + h * DV + j0 + 8);
        #pragma unroll
        for (int jj = 0; jj < 8; ++jj) {
            v_l[s][j0 + jj] = bf2f((u16)v0[jj]);
            v_l[s][j0 + 8 + jj] = bf2f((u16)v1[jj]);
        }
    }
    __syncthreads();
    if (tid < 32) {
        float run = 0.f;
        for (int t = 0; t < 64; ++t) {
            run += gkS[t][tid];
            gkS[t][tid] = run;
        }
        Z[tid] = run;
    }
    __syncthreads();
    #pragma unroll
    for (int jj = 0; jj < 8; ++jj)
        kd[s][i0 + jj] = expf(Z[i0 + jj] - gkS[s][i0 + jj]) * k_l[s][i0 + jj];
    __syncthreads();
    {
        int i = tid >> 4, j4 = tid & 15;
        int i2 = i + 16;
        float a0 = 0, a1 = 0, a2 = 0, a3 = 0, b0 = 0, b1 = 0, b2v = 0, b3 = 0;
        for (int ss = 0; ss < 64; ++ss) {
            float kd1 = kd[ss][i], kd2 = kd[ss][i2];
            const float4 vv = *(const float4*)&v_l[ss][j4 * 4];
            a0 += kd1 * vv.x; a1 += kd1 * vv.y; a2 += kd1 * vv.z; a3 += kd1 * vv.w;
            b0 += kd2 * vv.x; b1 += kd2 * vv.y; b2v += kd2 * vv.z; b3 += kd2 * vv.w;
        }
        size_t base = ((size_t)(bh * NCH + c)) * 2048;
        float4 o1; o1.x = a0; o1.y = a1; o1.z = a2; o1.w = a3;
        float4 o2; o2.x = b0; o2.y = b1; o2.z = b2v; o2.w = b3;
        *(float4*)(M_ws + base + i * 64 + j4 * 4) = o1;
        *(float4*)(M_ws + base + i2 * 64 + j4 * 4) = o2;
    }
    if (tid < 32) D_ws[(size_t)(bh * NCH + c) * 32 + tid] = expf(Z[tid]);
}

// ---------------- phase B: chunk-state recurrence, one thread per (bh,i,j) ----------------
__global__ __launch_bounds__(256) void phaseB(const float* __restrict__ M_ws,
                                              const float* __restrict__ D_ws,
                                              float* __restrict__ H_ws) {
    int idx = blockIdx.x * 256 + threadIdx.x;   // 65536 = 32 bh * 2048 (i*64+j)
    int bh = idx >> 11;
    int ij = idx & 2047;
    int i = ij >> 6;
    float h = 0.f;
    size_t base = (size_t)bh * NCH * 2048 + ij;
    const float* dp = D_ws + (size_t)bh * NCH * 32 + i;
    for (int c = 0; c < NCH; ++c) {
        H_ws[base + (size_t)c * 2048] = h;
        h = h * dp[c * 32] + M_ws[base + (size_t)c * 2048];
    }
}

// ---------------- phase C: gate + cumsum + intra-chunk attn + H + RMSNorm/swish ----------------
__global__ __launch_bounds__(256) void phaseC(const u16* __restrict__ qkvg,
                                              const float* __restrict__ W2,
                                              const float* __restrict__ b2,
                                              const float* __restrict__ H_ws,
                                              const float* __restrict__ gnw,
                                              u16* __restrict__ o_n) {
    int bh = blockIdx.x >> 6, c = blockIdx.x & 63;
    int b = bh >> 4, h = bh & 15;
    int t0 = b * TT + c * CHUNK;
    __shared__ float qh[64][36];
    __shared__ float kt[64][36];
    __shared__ float v_l[64][68];
    __shared__ float H_l[32][68];
    __shared__ float A_l[64][68];
    int tid = threadIdx.x;
    int s = tid >> 2, i0 = (tid & 3) << 3;
    short8 qv = *(const short8*)(qkvg + (size_t)(t0 + s) * QSTR + h * DK + i0);
    short8 kv = *(const short8*)(qkvg + (size_t)(t0 + s) * QSTR + 512 + h * DK + i0);
    {
        float ls[8];
        gate_z8(qkvg + (size_t)(t0 + s) * QSTR + 3072, W2, b2, h * DK + i0, ls);
        #pragma unroll
        for (int jj = 0; jj < 8; ++jj) kt[s][i0 + jj] = ls[jj];
    }
    {
        int j0 = (tid & 3) << 4;
        short8 v0 = *(const short8*)(qkvg + (size_t)(t0 + s) * QSTR + 1024 + h * DV + j0);
        short8 v1 = *(const short8*)(qkvg + (size_t)(t0 + s) * QSTR + 1024 + h * DV + j0 + 8);
        #pragma unroll
        for (int jj = 0; jj < 8; ++jj) {
            v_l[s][j0 + jj] = bf2f((u16)v0[jj]);
            v_l[s][j0 + 8 + jj] = bf2f((u16)v1[jj]);
        }
    }
    {
        int i = tid >> 3, j0 = (tid & 7) << 3;
        size_t base = ((size_t)(bh * NCH + c)) * 2048 + i * 64 + j0;
        *(float4*)&H_l[i][j0] = *(const float4*)(H_ws + base);
        *(float4*)&H_l[i][j0 + 4] = *(const float4*)(H_ws + base + 4);
    }
    __syncthreads();
    if (tid < 32) {                 // inclusive cumsum of log-decay over t
        float run = 0.f;
        for (int t = 0; t < 64; ++t) {
            run += kt[t][tid];
            kt[t][tid] = run;
        }
    }
    __syncthreads();
    #pragma unroll
    for (int jj = 0; jj < 8; ++jj) {
        float Sv = kt[s][i0 + jj];
        qh[s][i0 + jj] = bf2f((u16)qv[jj]) * expf(Sv) * SCALE;
        kt[s][i0 + jj] = bf2f((u16)kv[jj]) * expf(fminf(-Sv, 80.f));
    }
    __syncthreads();
    {
        int ta = tid >> 2, s0 = (tid & 3) << 4;
        for (int ss = s0; ss < s0 + 16; ++ss) {
            float a = 0.f;
            if (ss <= ta) {
                #pragma unroll 8
                for (int i = 0; i < 32; ++i) a += qh[ta][i] * kt[ss][i];
            }
            A_l[ta][ss] = a;
        }
    }
    __syncthreads();
    #pragma unroll
    for (int q4 = 0; q4 < 4; ++q4) {
        int slot = tid + q4 * 256;
        int t = slot >> 4, j4 = slot & 15;
        float a0 = 0, a1 = 0, a2 = 0, a3 = 0;
        #pragma unroll 8
        for (int i = 0; i < 32; ++i) {
            float qvf = qh[t][i];
            const float4 hv = *(const float4*)&H_l[i][j4 * 4];
            a0 += qvf * hv.x; a1 += qvf * hv.y; a2 += qvf * hv.z; a3 += qvf * hv.w;
        }
        for (int ss = 0; ss <= t; ++ss) {
            float av = A_l[t][ss];
            const float4 vv = *(const float4*)&v_l[ss][j4 * 4];
            a0 += av * vv.x; a1 += av * vv.y; a2 += av * vv.z; a3 += av * vv.w;
        }
        float ss2 = a0 * a0 + a1 * a1 + a2 * a2 + a3 * a3;
        ss2 += __shfl_xor(ss2, 1);
        ss2 += __shfl_xor(ss2, 2);
        ss2 += __shfl_xor(ss2, 4);
        ss2 += __shfl_xor(ss2, 8);
        float rms = rsqrtf(ss2 * (1.f / 64.f) + 1e-5f);
        const float4 gw = *(const float4*)(gnw + j4 * 4);
        ushort4 gv = *(const ushort4*)(qkvg + (size_t)(t0 + t) * QSTR + 2048 + h * DV + j4 * 4);
        float g0 = bf2f(gv.x), g1 = bf2f(gv.y), g2 = bf2f(gv.z), g3 = bf2f(gv.w);
        float o0 = a0 * rms * gw.x * (g0 / (1.f + expf(-g0)));
        float o1 = a1 * rms * gw.y * (g1 / (1.f + expf(-g1)));
        float o2 = a2 * rms * gw.z * (g2 / (1.f + expf(-g2)));
        float o3 = a3 * rms * gw.w * (g3 / (1.f + expf(-g3)));
        ushort4 ov;
        ov.x = f2bf(o0); ov.y = f2bf(o1); ov.z = f2bf(o2); ov.w = f2bf(o3);
        *(ushort4*)(o_n + (size_t)(t0 + t) * 1024 + h * DV + j4 * 4) = ov;
    }
}

// ---------------- launch ----------------
extern "C" void kernel_launch(void* const* d_in, const int* in_sizes, int n_in,
                              void* d_out, int out_size, void* d_ws, size_t ws_size,
                              hipStream_t stream) {
    const float* x    = (const float*)d_in[0];
    const float* Wq   = (const float*)d_in[1];
    const float* Wk   = (const float*)d_in[2];
    const float* Wv   = (const float*)d_in[3];
    const float* Wgk1 = (const float*)d_in[4];
    const float* Wgk2 = (const float*)d_in[5];
    const float* bgk2 = (const float*)d_in[6];
    const float* Wg   = (const float*)d_in[7];
    const float* gnw  = (const float*)d_in[8];
    const float* Wo   = (const float*)d_in[9];

    char* ws = (char*)d_ws;
    size_t off = 0;
    u16* xb     = (u16*)(ws + off); off += (size_t)MROWS * 1024 * 2;          // 16.8 MB
    u16* Wall   = (u16*)(ws + off); off += (size_t)4224 * 1024 * 2;           // 8.65 MB (WcatT | WoT)
    u16* qkvg   = (u16*)(ws + off); off += (size_t)MROWS * QSTR * 2;          // 52.4 MB
    float* M_ws = (float*)(ws + off); off += (size_t)NBH * NCH * 2048 * 4;    // 16.8 MB
    float* D_ws = (float*)(ws + off); off += (size_t)NBH * NCH * 32 * 4;      // 0.26 MB
    float* H_ws = (float*)(ws + off); off += (size_t)NBH * NCH * 2048 * 4;    // 16.8 MB
    u16* o_n    = (u16*)(ws + off); off += (size_t)MROWS * 1024 * 2;          // 16.8 MB
    u16* WcatT  = Wall;
    u16* WoT    = Wall + (size_t)3200 * 1024;

    f32_to_bf16_vec<<<MROWS, 256, 0, stream>>>(x, xb, MROWS * 1024 / 4);
    weight_prep<<<dim3(132, 32), 256, 0, stream>>>(Wq, Wk, Wv, Wg, Wgk1, Wo, Wall);
    gemm_sb<1><<<25 * 64, 256, 0, stream>>>(xb, WcatT, qkvg, MROWS, QSTR, 1024, 25);
    phaseA<<<NBH * NCH, 256, 0, stream>>>(qkvg, Wgk2, bgk2, M_ws, D_ws);
    phaseB<<<256, 256, 0, stream>>>(M_ws, D_ws, H_ws);
    phaseC<<<NBH * NCH, 256, 0, stream>>>(qkvg, Wgk2, bgk2, H_ws, gnw, o_n);
    gemm_sb<0><<<8 * 64, 256, 0, stream>>>(o_n, WoT, d_out, MROWS, 1024, 1024, 8);
}

// Round 6
// 181.154 us; speedup vs baseline: 2.9090x; 1.3100x over previous
//
#include <hip/hip_runtime.h>

typedef unsigned short u16;
typedef unsigned int u32;
typedef __attribute__((ext_vector_type(8))) short short8;
typedef __attribute__((ext_vector_type(4))) float f32x4;

#define KD 512
#define HEADS 16
#define DK 32
#define DV 64
#define TT 4096
#define MROWS 8192           // B*T
#define CHUNK 64
#define NCH 64               // T/CHUNK
#define NBH 32               // B*HEADS
#define QSTR 3200            // qkvg row stride (q 0 | k 512 | v 1024 | g 2048 | xg1 3072 | pad)
#define SCALE 0.17677669529663687f  // 32^-0.5

__device__ __forceinline__ u16 f2bf(float f) {
    union { float f; unsigned int u; } x; x.f = f;
    unsigned int u = x.u;
    unsigned int r = (u + 0x7fffu + ((u >> 16) & 1u)) >> 16;
    return (u16)r;
}
__device__ __forceinline__ float bf2f(u16 s) {
    union { unsigned int u; float f; } x; x.u = ((unsigned int)s) << 16;
    return x.f;
}
__device__ __forceinline__ void gload16(const u16* g, u16* l) {
    __builtin_amdgcn_global_load_lds((const __attribute__((address_space(1))) u32*)g,
                                     (__attribute__((address_space(3))) u32*)l, 16, 0, 0);
}

// ---------------- x f32 -> bf16 (coalesced) ----------------
__global__ __launch_bounds__(256) void f32_to_bf16_vec(const float* __restrict__ src,
                                                       u16* __restrict__ dst, int n4) {
    int i = blockIdx.x * 256 + threadIdx.x;
    if (i < n4) {
        const float4 v = ((const float4*)src)[i];
        ushort4 o;
        o.x = f2bf(v.x); o.y = f2bf(v.y); o.z = f2bf(v.z); o.w = f2bf(v.w);
        ((ushort4*)dst)[i] = o;
    }
}

// ---------------- all weights -> transposed bf16, one kernel ----------------
__global__ __launch_bounds__(256) void weight_prep(const float* __restrict__ Wq,
                                                   const float* __restrict__ Wk,
                                                   const float* __restrict__ Wv,
                                                   const float* __restrict__ Wg,
                                                   const float* __restrict__ W1,
                                                   const float* __restrict__ Wo,
                                                   u16* __restrict__ dst) {
    __shared__ float tile[32][33];
    int n0 = blockIdx.x * 32, k0 = blockIdx.y * 32;
    int tx = threadIdx.x & 31, ty = threadIdx.x >> 5;
    int n = n0 + tx;
    const float* src; int sN, cc;
    if (n < 512)       { src = Wq; sN = 512;  cc = n; }
    else if (n < 1024) { src = Wk; sN = 512;  cc = n - 512; }
    else if (n < 2048) { src = Wv; sN = 1024; cc = n - 1024; }
    else if (n < 3072) { src = Wg; sN = 1024; cc = n - 2048; }
    else if (n < 3088) { src = W1; sN = 16;   cc = n - 3072; }
    else if (n < 3200) { src = nullptr; sN = 0; cc = 0; }
    else               { src = Wo; sN = 1024; cc = n - 3200; }
    for (int r = ty; r < 32; r += 8)
        tile[r][tx] = src ? src[(size_t)(k0 + r) * sN + cc] : 0.f;
    __syncthreads();
    for (int r = ty; r < 32; r += 8)
        dst[(size_t)(n0 + r) * 1024 + k0 + tx] = f2bf(tile[tx][r]);
}

// ---------------- bf16 MFMA GEMM: 128x128, BK=64, single-buffer, XOR swizzle, XCD swizzle ----
template<int OUTBF>
__global__ __launch_bounds__(256) void gemm_sb(const u16* __restrict__ A,
                                               const u16* __restrict__ Bt,
                                               void* __restrict__ C,
                                               int M, int N, int K, int nbx) {
    __shared__ u16 As[128 * 64];
    __shared__ u16 Bs[128 * 64];
    int nwg = gridDim.x;
    int bid = blockIdx.x;
    int cpx = nwg >> 3;
    int wg = (bid & 7) * cpx + (bid >> 3);
    int bx = wg % nbx, by = wg / nbx;
    int tid = threadIdx.x;
    int wave = tid >> 6, lane = tid & 63;
    int wr = wave >> 1, wc = wave & 1;
    int brow = by * 128, bcol = bx * 128;
    int srow = tid >> 3;
    int sgrp = (tid & 7) ^ (srow & 7);
    const u16* aS = A + (size_t)(brow + srow) * K + sgrp * 8;
    const u16* bS = Bt + (size_t)(bcol + srow) * K + sgrp * 8;
    f32x4 acc[4][4];
    #pragma unroll
    for (int mi = 0; mi < 4; ++mi)
        #pragma unroll
        for (int ni = 0; ni < 4; ++ni)
            acc[mi][ni] = (f32x4){0.f, 0.f, 0.f, 0.f};
    int l15 = lane & 15, hi = lane >> 4;
    int rxor = l15 & 7;
    for (int kt = 0; kt < K; kt += 64) {
        __syncthreads();
        #pragma unroll
        for (int i_ = 0; i_ < 4; ++i_) {
            gload16(aS + (size_t)i_ * 32 * K + kt, As + tid * 8 + i_ * 2048);
            gload16(bS + (size_t)i_ * 32 * K + kt, Bs + tid * 8 + i_ * 2048);
        }
        __syncthreads();
        #pragma unroll
        for (int ks = 0; ks < 2; ++ks) {
            short8 af[4], bfr[4];
            int g = ks * 4 + hi;
            #pragma unroll
            for (int i = 0; i < 4; ++i)
                af[i] = *(const short8*)(As + (size_t)(wr * 64 + i * 16 + l15) * 64 + ((g ^ rxor) << 3));
            #pragma unroll
            for (int i = 0; i < 4; ++i)
                bfr[i] = *(const short8*)(Bs + (size_t)(wc * 64 + i * 16 + l15) * 64 + ((g ^ rxor) << 3));
            #pragma unroll
            for (int mi = 0; mi < 4; ++mi)
                #pragma unroll
                for (int ni = 0; ni < 4; ++ni)
                    acc[mi][ni] = __builtin_amdgcn_mfma_f32_16x16x32_bf16(af[mi], bfr[ni], acc[mi][ni], 0, 0, 0);
        }
    }
    int r0 = brow + wr * 64 + (hi << 2);
    int c0 = bcol + wc * 64 + l15;
    #pragma unroll
    for (int mi = 0; mi < 4; ++mi)
        #pragma unroll
        for (int ni = 0; ni < 4; ++ni)
            #pragma unroll
            for (int rr = 0; rr < 4; ++rr) {
                size_t idx = (size_t)(r0 + mi * 16 + rr) * N + (c0 + ni * 16);
                float val = acc[mi][ni][rr];
                if (OUTBF) ((u16*)C)[idx] = f2bf(val);
                else       ((float*)C)[idx] = val;
            }
}

// ---------------- gate slice: ls[j] = logsigmoid(xg1·W2[:,cc+j] + b2)/16, j=0..7 ----------------
__device__ __forceinline__ void gate_z8(const u16* __restrict__ xg,
                                        const float* __restrict__ W2,
                                        const float* __restrict__ b2,
                                        int cc, float* out8) {
    short8 x0 = *(const short8*)xg;
    short8 x1 = *(const short8*)(xg + 8);
    float z[8];
    float4 z0 = *(const float4*)(b2 + cc);
    float4 z1 = *(const float4*)(b2 + cc + 4);
    z[0]=z0.x; z[1]=z0.y; z[2]=z0.z; z[3]=z0.w;
    z[4]=z1.x; z[5]=z1.y; z[6]=z1.z; z[7]=z1.w;
    #pragma unroll
    for (int u = 0; u < 16; ++u) {
        float xu = bf2f((u16)(u < 8 ? x0[u] : x1[u - 8]));
        const float4 w0 = *(const float4*)(W2 + (size_t)u * 512 + cc);
        const float4 w1 = *(const float4*)(W2 + (size_t)u * 512 + cc + 4);
        z[0] += xu * w0.x; z[1] += xu * w0.y; z[2] += xu * w0.z; z[3] += xu * w0.w;
        z[4] += xu * w1.x; z[5] += xu * w1.y; z[6] += xu * w1.z; z[7] += xu * w1.w;
    }
    #pragma unroll
    for (int j = 0; j < 8; ++j) {
        float zz = z[j];
        out8[j] = (fminf(zz, 0.f) - log1pf(expf(-fabsf(zz)))) * 0.0625f;
    }
}

// ---------------- phase A (MFMA): gate+cumsum; M^T = (kd^T @ v)^T via mfma -> MT, D ----------------
__global__ __launch_bounds__(256) void phaseA(const u16* __restrict__ qkvg,
                                              const float* __restrict__ W2,
                                              const float* __restrict__ b2,
                                              float* __restrict__ MT_ws,
                                              float* __restrict__ D_ws) {
    int bh = blockIdx.x >> 6, c = blockIdx.x & 63;
    int b = bh >> 4, h = bh & 15;
    int t0 = b * TT + c * CHUNK;
    __shared__ float gkS[64][36];
    __shared__ u16 kdT_bf[32 * 72];
    __shared__ u16 VT_bf[64 * 72];
    __shared__ float Z[32];
    int tid = threadIdx.x;
    int s = tid >> 2, i0 = (tid & 3) << 3;
    // gate -> gkS
    {
        float ls[8];
        gate_z8(qkvg + (size_t)(t0 + s) * QSTR + 3072, W2, b2, h * DK + i0, ls);
        #pragma unroll
        for (int jj = 0; jj < 8; ++jj) gkS[s][i0 + jj] = ls[jj];
    }
    short8 kv = *(const short8*)(qkvg + (size_t)(t0 + s) * QSTR + 512 + h * DK + i0);
    // v (already bf16) -> VT (transposed raw copy)
    {
        int j0 = (tid & 3) << 4;
        short8 v0 = *(const short8*)(qkvg + (size_t)(t0 + s) * QSTR + 1024 + h * DV + j0);
        short8 v1 = *(const short8*)(qkvg + (size_t)(t0 + s) * QSTR + 1024 + h * DV + j0 + 8);
        #pragma unroll
        for (int jj = 0; jj < 8; ++jj) {
            VT_bf[(j0 + jj) * 72 + s] = (u16)v0[jj];
            VT_bf[(j0 + 8 + jj) * 72 + s] = (u16)v1[jj];
        }
    }
    __syncthreads();
    if (tid < 32) {
        float run = 0.f;
        for (int t = 0; t < 64; ++t) { run += gkS[t][tid]; gkS[t][tid] = run; }
        Z[tid] = run;
    }
    __syncthreads();
    #pragma unroll
    for (int jj = 0; jj < 8; ++jj)
        kdT_bf[(i0 + jj) * 72 + s] = f2bf(expf(Z[i0 + jj] - gkS[s][i0 + jj]) * bf2f((u16)kv[jj]));
    __syncthreads();
    // MFMA: M[i][j], tiles (it,jt): wave -> it = w&1, jt in {2*(w>>1), 2*(w>>1)+1}
    int wave = tid >> 6, lane = tid & 63, l15 = lane & 15, hi = lane >> 4;
    int it = wave & 1, jp = wave >> 1;
    size_t base = ((size_t)(bh * NCH + c)) * 2048;
    #pragma unroll
    for (int jj2 = 0; jj2 < 2; ++jj2) {
        int jt = jp * 2 + jj2;
        f32x4 mc = (f32x4){0.f, 0.f, 0.f, 0.f};
        #pragma unroll
        for (int kc = 0; kc < 2; ++kc) {
            short8 ak = *(const short8*)&kdT_bf[(it * 16 + l15) * 72 + kc * 32 + hi * 8];
            short8 bv = *(const short8*)&VT_bf[(jt * 16 + l15) * 72 + kc * 32 + hi * 8];
            mc = __builtin_amdgcn_mfma_f32_16x16x32_bf16(ak, bv, mc, 0, 0, 0);
        }
        #pragma unroll
        for (int rr = 0; rr < 4; ++rr)
            MT_ws[base + (size_t)(jt * 16 + l15) * 32 + it * 16 + hi * 4 + rr] = mc[rr];
    }
    if (tid < 32) D_ws[(size_t)(bh * NCH + c) * 32 + tid] = expf(Z[tid]);
}

// ---------------- phase B: chunk-state recurrence on transposed layout [j*32+i] ----------------
__global__ __launch_bounds__(256) void phaseB(const float* __restrict__ MT_ws,
                                              const float* __restrict__ D_ws,
                                              float* __restrict__ HT_ws) {
    int idx = blockIdx.x * 256 + threadIdx.x;   // 65536 = 32 bh * 2048 (j*32+i)
    int bh = idx >> 11;
    int ji = idx & 2047;
    int i = ji & 31;
    float h = 0.f;
    size_t base = (size_t)bh * NCH * 2048 + ji;
    const float* dp = D_ws + (size_t)bh * NCH * 32 + i;
    for (int c = 0; c < NCH; ++c) {
        HT_ws[base + (size_t)c * 2048] = h;
        h = h * dp[c * 32] + MT_ws[base + (size_t)c * 2048];
    }
}

// ---------------- phase C (MFMA): score->mask->P, O = P@V + qh@H, fused RMS/swish ----------------
__global__ __launch_bounds__(256) void phaseC(const u16* __restrict__ qkvg,
                                              const float* __restrict__ W2,
                                              const float* __restrict__ b2,
                                              const float* __restrict__ HT_ws,
                                              const float* __restrict__ gnw,
                                              u16* __restrict__ o_n) {
    int bh = blockIdx.x >> 6, c = blockIdx.x & 63;
    int b = bh >> 4, h = bh & 15;
    int t0 = b * TT + c * CHUNK;
    __shared__ float gkS[64][36];                // cumsum buffer; later aliased as P_bf[64][72] u16
    __shared__ u16 qh_bf[64 * 40];
    __shared__ u16 kt_bf[64 * 40];
    __shared__ u16 VT_bf[64 * 72];
    __shared__ u16 Ht_bf[64 * 40];
    u16* P_bf = (u16*)&gkS[0][0];
    int tid = threadIdx.x;
    int s = tid >> 2, i0 = (tid & 3) << 3;
    // gate -> gkS
    {
        float ls[8];
        gate_z8(qkvg + (size_t)(t0 + s) * QSTR + 3072, W2, b2, h * DK + i0, ls);
        #pragma unroll
        for (int jj = 0; jj < 8; ++jj) gkS[s][i0 + jj] = ls[jj];
    }
    short8 qv = *(const short8*)(qkvg + (size_t)(t0 + s) * QSTR + h * DK + i0);
    short8 kv = *(const short8*)(qkvg + (size_t)(t0 + s) * QSTR + 512 + h * DK + i0);
    // v -> VT (raw bf16 copy, transposed)
    {
        int j0 = (tid & 3) << 4;
        short8 v0 = *(const short8*)(qkvg + (size_t)(t0 + s) * QSTR + 1024 + h * DV + j0);
        short8 v1 = *(const short8*)(qkvg + (size_t)(t0 + s) * QSTR + 1024 + h * DV + j0 + 8);
        #pragma unroll
        for (int jj = 0; jj < 8; ++jj) {
            VT_bf[(j0 + jj) * 72 + s] = (u16)v0[jj];
            VT_bf[(j0 + 8 + jj) * 72 + s] = (u16)v1[jj];
        }
    }
    // H^T (chunk-initial state) -> Ht_bf rows j
    {
        const float* hp = HT_ws + ((size_t)(bh * NCH + c)) * 2048 + tid * 8;
        float4 h0 = *(const float4*)hp;
        float4 h1 = *(const float4*)(hp + 4);
        int j = tid >> 2, ii0 = (tid & 3) << 3;
        ushort4 o0, o1;
        o0.x = f2bf(h0.x); o0.y = f2bf(h0.y); o0.z = f2bf(h0.z); o0.w = f2bf(h0.w);
        o1.x = f2bf(h1.x); o1.y = f2bf(h1.y); o1.z = f2bf(h1.z); o1.w = f2bf(h1.w);
        *(ushort4*)&Ht_bf[j * 40 + ii0] = o0;
        *(ushort4*)&Ht_bf[j * 40 + ii0 + 4] = o1;
    }
    __syncthreads();
    if (tid < 32) {                 // inclusive cumsum of log-decay over t
        float run = 0.f;
        for (int t = 0; t < 64; ++t) { run += gkS[t][tid]; gkS[t][tid] = run; }
    }
    __syncthreads();
    // qh = q*exp(S)*scale, kt = k*exp(-S)  (bf16)
    #pragma unroll
    for (int jj = 0; jj < 8; ++jj) {
        float Sv = gkS[s][i0 + jj];
        qh_bf[s * 40 + i0 + jj] = f2bf(bf2f((u16)qv[jj]) * expf(Sv) * SCALE);
        kt_bf[s * 40 + i0 + jj] = f2bf(bf2f((u16)kv[jj]) * expf(fminf(-Sv, 80.f)));
    }
    __syncthreads();
    // per-wave: wave w owns t-rows [w*16, w*16+16)
    int wave = tid >> 6, lane = tid & 63, l15 = lane & 15, hi = lane >> 4;
    int w = wave;
    short8 aq = *(const short8*)&qh_bf[(w * 16 + l15) * 40 + hi * 8];
    // score tiles (sn <= w), mask diagonal, write P (aliases gkS; gkS dead after barrier above)
    #pragma unroll
    for (int sn = 0; sn < 4; ++sn) {
        f32x4 sc = (f32x4){0.f, 0.f, 0.f, 0.f};
        if (sn <= w) {
            short8 bk = *(const short8*)&kt_bf[(sn * 16 + l15) * 40 + hi * 8];
            sc = __builtin_amdgcn_mfma_f32_16x16x32_bf16(aq, bk, sc, 0, 0, 0);
        }
        #pragma unroll
        for (int rr = 0; rr < 4; ++rr) {
            float val = sc[rr];
            if (sn > w || (sn == w && l15 > hi * 4 + rr)) val = 0.f;
            P_bf[(w * 16 + hi * 4 + rr) * 72 + sn * 16 + l15] = f2bf(val);
        }
    }
    __syncthreads();
    // O = qh@H + P@V
    f32x4 acc[4];
    #pragma unroll
    for (int jn = 0; jn < 4; ++jn) {
        f32x4 a = (f32x4){0.f, 0.f, 0.f, 0.f};
        short8 bhf = *(const short8*)&Ht_bf[(jn * 16 + l15) * 40 + hi * 8];
        acc[jn] = __builtin_amdgcn_mfma_f32_16x16x32_bf16(aq, bhf, a, 0, 0, 0);
    }
    int nkc = (w < 2) ? 1 : 2;
    for (int kc = 0; kc < nkc; ++kc) {
        short8 ap = *(const short8*)&P_bf[(w * 16 + l15) * 72 + kc * 32 + hi * 8];
        #pragma unroll
        for (int jn = 0; jn < 4; ++jn) {
            short8 bv = *(const short8*)&VT_bf[(jn * 16 + l15) * 72 + kc * 32 + hi * 8];
            acc[jn] = __builtin_amdgcn_mfma_f32_16x16x32_bf16(ap, bv, acc[jn], 0, 0, 0);
        }
    }
    // fused RMSNorm + swish gate; lane holds O[t = w*16+hi*4+rr][j = jn*16+l15]
    #pragma unroll
    for (int rr = 0; rr < 4; ++rr) {
        float sum2 = 0.f;
        #pragma unroll
        for (int jn = 0; jn < 4; ++jn) sum2 += acc[jn][rr] * acc[jn][rr];
        sum2 += __shfl_xor(sum2, 1);
        sum2 += __shfl_xor(sum2, 2);
        sum2 += __shfl_xor(sum2, 4);
        sum2 += __shfl_xor(sum2, 8);
        float rms = rsqrtf(sum2 * (1.f / 64.f) + 1e-5f);
        int t = w * 16 + hi * 4 + rr;
        #pragma unroll
        for (int jn = 0; jn < 4; ++jn) {
            int j = jn * 16 + l15;
            float g = bf2f(qkvg[(size_t)(t0 + t) * QSTR + 2048 + h * DV + j]);
            float sw = g / (1.f + expf(-g));
            float o = acc[jn][rr] * rms * gnw[j] * sw;
            o_n[(size_t)(t0 + t) * 1024 + h * DV + j] = f2bf(o);
        }
    }
}

// ---------------- launch ----------------
extern "C" void kernel_launch(void* const* d_in, const int* in_sizes, int n_in,
                              void* d_out, int out_size, void* d_ws, size_t ws_size,
                              hipStream_t stream) {
    const float* x    = (const float*)d_in[0];
    const float* Wq   = (const float*)d_in[1];
    const float* Wk   = (const float*)d_in[2];
    const float* Wv   = (const float*)d_in[3];
    const float* Wgk1 = (const float*)d_in[4];
    const float* Wgk2 = (const float*)d_in[5];
    const float* bgk2 = (const float*)d_in[6];
    const float* Wg   = (const float*)d_in[7];
    const float* gnw  = (const float*)d_in[8];
    const float* Wo   = (const float*)d_in[9];

    char* ws = (char*)d_ws;
    size_t off = 0;
    u16* xb      = (u16*)(ws + off); off += (size_t)MROWS * 1024 * 2;
    u16* Wall    = (u16*)(ws + off); off += (size_t)4224 * 1024 * 2;
    u16* qkvg    = (u16*)(ws + off); off += (size_t)MROWS * QSTR * 2;
    float* MT_ws = (float*)(ws + off); off += (size_t)NBH * NCH * 2048 * 4;
    float* D_ws  = (float*)(ws + off); off += (size_t)NBH * NCH * 32 * 4;
    float* HT_ws = (float*)(ws + off); off += (size_t)NBH * NCH * 2048 * 4;
    u16* o_n     = (u16*)(ws + off); off += (size_t)MROWS * 1024 * 2;
    u16* WcatT   = Wall;
    u16* WoT     = Wall + (size_t)3200 * 1024;

    f32_to_bf16_vec<<<MROWS, 256, 0, stream>>>(x, xb, MROWS * 1024 / 4);
    weight_prep<<<dim3(132, 32), 256, 0, stream>>>(Wq, Wk, Wv, Wg, Wgk1, Wo, Wall);
    gemm_sb<1><<<25 * 64, 256, 0, stream>>>(xb, WcatT, qkvg, MROWS, QSTR, 1024, 25);
    phaseA<<<NBH * NCH, 256, 0, stream>>>(qkvg, Wgk2, bgk2, MT_ws, D_ws);
    phaseB<<<256, 256, 0, stream>>>(MT_ws, D_ws, HT_ws);
    phaseC<<<NBH * NCH, 256, 0, stream>>>(qkvg, Wgk2, bgk2, HT_ws, gnw, o_n);
    gemm_sb<0><<<8 * 64, 256, 0, stream>>>(o_n, WoT, d_out, MROWS, 1024, 1024, 8);
}

// Round 7
// 180.952 us; speedup vs baseline: 2.9123x; 1.0011x over previous
//
#include <hip/hip_runtime.h>

typedef unsigned short u16;
typedef unsigned int u32;
typedef __attribute__((ext_vector_type(8))) short short8;
typedef __attribute__((ext_vector_type(4))) float f32x4;

#define KD 512
#define HEADS 16
#define DK 32
#define DV 64
#define TT 4096
#define MROWS 8192           // B*T
#define CHUNK 64
#define NCH 64               // T/CHUNK
#define NBH 32               // B*HEADS
#define QSTR 3328            // qkvg row stride (q 0 | k 512 | v 1024 | g 2048 | xg1 3072 | pad to 13*256)
#define SCALE 0.17677669529663687f  // 32^-0.5

__device__ __forceinline__ u16 f2bf(float f) {
    union { float f; unsigned int u; } x; x.f = f;
    unsigned int u = x.u;
    unsigned int r = (u + 0x7fffu + ((u >> 16) & 1u)) >> 16;
    return (u16)r;
}
__device__ __forceinline__ float bf2f(u16 s) {
    union { unsigned int u; float f; } x; x.u = ((unsigned int)s) << 16;
    return x.f;
}
__device__ __forceinline__ void gload16(const u16* g, u16* l) {
    __builtin_amdgcn_global_load_lds((const __attribute__((address_space(1))) u32*)g,
                                     (__attribute__((address_space(3))) u32*)l, 16, 0, 0);
}

// ---------------- x f32 -> bf16 (coalesced) ----------------
__global__ __launch_bounds__(256) void f32_to_bf16_vec(const float* __restrict__ src,
                                                       u16* __restrict__ dst, int n4) {
    int i = blockIdx.x * 256 + threadIdx.x;
    if (i < n4) {
        const float4 v = ((const float4*)src)[i];
        ushort4 o;
        o.x = f2bf(v.x); o.y = f2bf(v.y); o.z = f2bf(v.z); o.w = f2bf(v.w);
        ((ushort4*)dst)[i] = o;
    }
}

// ---------------- all weights -> transposed bf16, one kernel ----------------
// dst rows: [0,512) WqT | [512,1024) WkT | [1024,2048) WvT | [2048,3072) WgT
//           [3072,3088) W1T | [3088,3328) zero | [3328,4352) WoT
__global__ __launch_bounds__(256) void weight_prep(const float* __restrict__ Wq,
                                                   const float* __restrict__ Wk,
                                                   const float* __restrict__ Wv,
                                                   const float* __restrict__ Wg,
                                                   const float* __restrict__ W1,
                                                   const float* __restrict__ Wo,
                                                   u16* __restrict__ dst) {
    __shared__ float tile[32][33];
    int n0 = blockIdx.x * 32, k0 = blockIdx.y * 32;
    int tx = threadIdx.x & 31, ty = threadIdx.x >> 5;
    int n = n0 + tx;
    const float* src; int sN, cc;
    if (n < 512)       { src = Wq; sN = 512;  cc = n; }
    else if (n < 1024) { src = Wk; sN = 512;  cc = n - 512; }
    else if (n < 2048) { src = Wv; sN = 1024; cc = n - 1024; }
    else if (n < 3072) { src = Wg; sN = 1024; cc = n - 2048; }
    else if (n < 3088) { src = W1; sN = 16;   cc = n - 3072; }
    else if (n < 3328) { src = nullptr; sN = 0; cc = 0; }
    else               { src = Wo; sN = 1024; cc = n - 3328; }
    for (int r = ty; r < 32; r += 8)
        tile[r][tx] = src ? src[(size_t)(k0 + r) * sN + cc] : 0.f;
    __syncthreads();
    for (int r = ty; r < 32; r += 8)
        dst[(size_t)(n0 + r) * 1024 + k0 + tx] = f2bf(tile[tx][r]);
}

// ======================= 8-phase 256x256 GEMM (T2+T3+T4+T5) =======================
// 512 thr / 8 waves (2M x 4N), BK=64, LDS 128KB dbuf. Regions: A-lo/A-hi (mh half,
// 128 perm-rows) and B-lo/B-hi (nh half) per buffer. Perm layout: A lds_row =
// mh*128 + wm*64 + (m&63); B lds_row = nh*128 + wn*32 + (n&31). XOR granule swizzle
// (rule 21: linear LDS dest, pre-swizzled global source, same XOR on ds_read).
// Counted vmcnt: 8 @P4, 10 @P6, 6 @P8 (stage slots give >=6-phase landing leads).
#define BARM() do { asm volatile("" ::: "memory"); __builtin_amdgcn_s_barrier(); asm volatile("" ::: "memory"); } while (0)
#define VMW(n) asm volatile("s_waitcnt vmcnt(" #n ")" ::: "memory")

template<int OUTBF>
__global__ __launch_bounds__(512, 2) void gemm8(const u16* __restrict__ A,
                                                const u16* __restrict__ Bt,
                                                void* __restrict__ C,
                                                int M, int N, int K, int nbx) {
    __shared__ u16 SA[2][16384];
    __shared__ u16 SB[2][16384];
    int nwg = gridDim.x, bid = blockIdx.x, cpx = nwg >> 3;
    int wg = (bid & 7) * cpx + (bid >> 3);       // XCD-chunked, bijective (nwg%8==0)
    int bx = wg % nbx, by = wg / nbx;
    int brow = by << 8, bcol = bx << 8;
    int tid = threadIdx.x;
    int wv = tid >> 6, lane = tid & 63;
    int wm = wv >> 2, wn = wv & 3;               // wave -> 128x64 C block
    int l15 = lane & 15, hi = lane >> 4;
    int rxor = l15 & 7;

    // staging source addresses (pre-swizzled granule)
    int srw = tid >> 3;                          // 0..63 perm-row within instr
    int sg8 = ((tid & 7) ^ (srw & 7)) << 3;      // swizzled source granule (u16 units)
    const u16* aBase = A + (size_t)(brow + srw) * K + sg8;                      // m = j*128 + h*64 + srw
    const u16* bBase = Bt + (size_t)(bcol + ((tid >> 8) << 6) + (srw & 31)) * K + sg8; // n = (j*2+(tid>>8))*64 + h*32 + (srw&31)

#define STAGE_A(b, h, tt) do { \
        const u16* s_ = aBase + (size_t)(tt) * 64 + (size_t)(h) * 64 * K; \
        gload16(s_,                    &SA[b][(h) * 8192 + tid * 8]); \
        gload16(s_ + (size_t)128 * K,  &SA[b][(h) * 8192 + 4096 + tid * 8]); \
    } while (0)
#define STAGE_B(b, h, tt) do { \
        const u16* s_ = bBase + (size_t)(tt) * 64 + (size_t)(h) * 32 * K; \
        gload16(s_,                    &SB[b][(h) * 8192 + tid * 8]); \
        gload16(s_ + (size_t)128 * K,  &SB[b][(h) * 8192 + 4096 + tid * 8]); \
    } while (0)

    int aRow = (wm * 64 + l15) * 64;
    int bRow = (wn * 32 + l15) * 64;
    int cg0 = (hi ^ rxor) << 3;
    int cg1 = ((4 + hi) ^ rxor) << 3;

#define READ_A(dst, mh, b) do { \
        _Pragma("unroll") \
        for (int mil_ = 0; mil_ < 4; ++mil_) { \
            dst[mil_ * 2 + 0] = *(const short8*)&SA[b][(mh) * 8192 + mil_ * 1024 + aRow + cg0]; \
            dst[mil_ * 2 + 1] = *(const short8*)&SA[b][(mh) * 8192 + mil_ * 1024 + aRow + cg1]; \
        } } while (0)
#define READ_B(dst, nh, b) do { \
        _Pragma("unroll") \
        for (int nil_ = 0; nil_ < 2; ++nil_) { \
            dst[nil_ * 2 + 0] = *(const short8*)&SB[b][(nh) * 8192 + nil_ * 1024 + bRow + cg0]; \
            dst[nil_ * 2 + 1] = *(const short8*)&SB[b][(nh) * 8192 + nil_ * 1024 + bRow + cg1]; \
        } } while (0)

    f32x4 acc[8][4];
    #pragma unroll
    for (int mi = 0; mi < 8; ++mi)
        #pragma unroll
        for (int ni = 0; ni < 4; ++ni)
            acc[mi][ni] = (f32x4){0.f, 0.f, 0.f, 0.f};

#define MM(mb, nb, AF, BF) do { \
        __builtin_amdgcn_s_setprio(1); \
        _Pragma("unroll") \
        for (int ks_ = 0; ks_ < 2; ++ks_) \
        _Pragma("unroll") \
        for (int mil_ = 0; mil_ < 4; ++mil_) \
        _Pragma("unroll") \
        for (int nil_ = 0; nil_ < 2; ++nil_) \
            acc[(mb) + mil_][(nb) + nil_] = __builtin_amdgcn_mfma_f32_16x16x32_bf16( \
                AF[mil_ * 2 + ks_], BF[nil_ * 2 + ks_], acc[(mb) + mil_][(nb) + nil_], 0, 0, 0); \
        __builtin_amdgcn_s_setprio(0); \
    } while (0)

    int NK = K >> 6, NI = NK >> 1;
    // prologue: buf0 <- t0 (all 4 regions), buf1 <- t1 (3 of 4; B1-hi comes at iter0 P1)
    STAGE_B(0, 0, 0); STAGE_A(0, 0, 0); STAGE_A(0, 1, 0); STAGE_B(0, 1, 0);
    STAGE_B(1, 0, 1); STAGE_A(1, 0, 1); STAGE_A(1, 1, 1);
    VMW(6);            // t0's 4 regions landed
    BARM();

    short8 alo[8], ahi[8], bb[4];
    for (int i = 0; i < NI; ++i) {
        int ta = 2 * i + 1; if (ta >= NK) ta = NK - 1;
        int tb = 2 * i + 2; if (tb >= NK) tb = NK - 1;
        int tc = 2 * i + 3; if (tc >= NK) tc = NK - 1;
        // ---- half 0: tile 2i from buf0 ----
        STAGE_B(1, 1, ta);                 // P1: B1-hi <- 2i+1 (read at P7)
        READ_A(alo, 0, 0); READ_B(bb, 0, 0);
        BARM(); MM(0, 0, alo, bb); BARM();
        STAGE_B(0, 0, tb);                 // P2: B0-lo <- 2i+2
        READ_A(ahi, 1, 0);
        BARM(); MM(4, 0, ahi, bb); BARM();
        STAGE_A(0, 0, tb);                 // P3: A0-lo <- 2i+2
        READ_B(bb, 1, 0);
        BARM(); MM(4, 2, ahi, bb); BARM();
        STAGE_A(0, 1, tb);                 // P4: A0-hi <- 2i+2
        BARM(); MM(0, 2, alo, bb);
        VMW(8);                            // all prev-iter stages landed -> buf1 ready
        BARM();
        // ---- half 1: tile 2i+1 from buf1 ----
        STAGE_B(0, 1, tb);                 // P5: B0-hi <- 2i+2
        READ_A(alo, 0, 1); READ_B(bb, 0, 1);
        BARM(); MM(0, 0, alo, bb); BARM();
        STAGE_B(1, 0, tc);                 // P6: B1-lo <- 2i+3
        READ_A(ahi, 1, 1);
        BARM(); MM(4, 0, ahi, bb);
        VMW(10);                           // P1's B1-hi landed -> P7 ready
        BARM();
        STAGE_A(1, 0, tc);                 // P7: A1-lo <- 2i+3
        READ_B(bb, 1, 1);
        BARM(); MM(4, 2, ahi, bb); BARM();
        STAGE_A(1, 1, tc);                 // P8: A1-hi <- 2i+3
        BARM(); MM(0, 2, alo, bb);
        VMW(6);                            // tb's 4 regions (P2..P5) landed -> next-iter buf0 ready
        BARM();
    }

    int r0 = brow + wm * 128 + (hi << 2);
    int c0 = bcol + wn * 64 + l15;
    #pragma unroll
    for (int mi = 0; mi < 8; ++mi)
        #pragma unroll
        for (int ni = 0; ni < 4; ++ni)
            #pragma unroll
            for (int rr = 0; rr < 4; ++rr) {
                size_t idx = (size_t)(r0 + mi * 16 + rr) * N + (c0 + ni * 16);
                float val = acc[mi][ni][rr];
                if (OUTBF) ((u16*)C)[idx] = f2bf(val);
                else       ((float*)C)[idx] = val;
            }
#undef STAGE_A
#undef STAGE_B
#undef READ_A
#undef READ_B
#undef MM
}

// ---------------- gate slice: ls[j] = logsigmoid(xg1·W2[:,cc+j] + b2)/16, j=0..7 ----------------
__device__ __forceinline__ void gate_z8(const u16* __restrict__ xg,
                                        const float* __restrict__ W2,
                                        const float* __restrict__ b2,
                                        int cc, float* out8) {
    short8 x0 = *(const short8*)xg;
    short8 x1 = *(const short8*)(xg + 8);
    float z[8];
    float4 z0 = *(const float4*)(b2 + cc);
    float4 z1 = *(const float4*)(b2 + cc + 4);
    z[0]=z0.x; z[1]=z0.y; z[2]=z0.z; z[3]=z0.w;
    z[4]=z1.x; z[5]=z1.y; z[6]=z1.z; z[7]=z1.w;
    #pragma unroll
    for (int u = 0; u < 16; ++u) {
        float xu = bf2f((u16)(u < 8 ? x0[u] : x1[u - 8]));
        const float4 w0 = *(const float4*)(W2 + (size_t)u * 512 + cc);
        const float4 w1 = *(const float4*)(W2 + (size_t)u * 512 + cc + 4);
        z[0] += xu * w0.x; z[1] += xu * w0.y; z[2] += xu * w0.z; z[3] += xu * w0.w;
        z[4] += xu * w1.x; z[5] += xu * w1.y; z[6] += xu * w1.z; z[7] += xu * w1.w;
    }
    #pragma unroll
    for (int j = 0; j < 8; ++j) {
        float zz = z[j];
        out8[j] = (fminf(zz, 0.f) - log1pf(expf(-fabsf(zz)))) * 0.0625f;
    }
}

// ---------------- phase A (MFMA): gate+cumsum; M^T via mfma -> MT, D ----------------
__global__ __launch_bounds__(256) void phaseA(const u16* __restrict__ qkvg,
                                              const float* __restrict__ W2,
                                              const float* __restrict__ b2,
                                              float* __restrict__ MT_ws,
                                              float* __restrict__ D_ws) {
    int bh = blockIdx.x >> 6, c = blockIdx.x & 63;
    int b = bh >> 4, h = bh & 15;
    int t0 = b * TT + c * CHUNK;
    __shared__ float gkS[64][36];
    __shared__ u16 kdT_bf[32 * 72];
    __shared__ u16 VT_bf[64 * 72];
    __shared__ float Z[32];
    int tid = threadIdx.x;
    int s = tid >> 2, i0 = (tid & 3) << 3;
    {
        float ls[8];
        gate_z8(qkvg + (size_t)(t0 + s) * QSTR + 3072, W2, b2, h * DK + i0, ls);
        #pragma unroll
        for (int jj = 0; jj < 8; ++jj) gkS[s][i0 + jj] = ls[jj];
    }
    short8 kv = *(const short8*)(qkvg + (size_t)(t0 + s) * QSTR + 512 + h * DK + i0);
    {
        int j0 = (tid & 3) << 4;
        short8 v0 = *(const short8*)(qkvg + (size_t)(t0 + s) * QSTR + 1024 + h * DV + j0);
        short8 v1 = *(const short8*)(qkvg + (size_t)(t0 + s) * QSTR + 1024 + h * DV + j0 + 8);
        #pragma unroll
        for (int jj = 0; jj < 8; ++jj) {
            VT_bf[(j0 + jj) * 72 + s] = (u16)v0[jj];
            VT_bf[(j0 + 8 + jj) * 72 + s] = (u16)v1[jj];
        }
    }
    __syncthreads();
    if (tid < 32) {
        float run = 0.f;
        for (int t = 0; t < 64; ++t) { run += gkS[t][tid]; gkS[t][tid] = run; }
        Z[tid] = run;
    }
    __syncthreads();
    #pragma unroll
    for (int jj = 0; jj < 8; ++jj)
        kdT_bf[(i0 + jj) * 72 + s] = f2bf(expf(Z[i0 + jj] - gkS[s][i0 + jj]) * bf2f((u16)kv[jj]));
    __syncthreads();
    int wave = tid >> 6, lane = tid & 63, l15 = lane & 15, hi = lane >> 4;
    int it = wave & 1, jp = wave >> 1;
    size_t base = ((size_t)(bh * NCH + c)) * 2048;
    #pragma unroll
    for (int jj2 = 0; jj2 < 2; ++jj2) {
        int jt = jp * 2 + jj2;
        f32x4 mc = (f32x4){0.f, 0.f, 0.f, 0.f};
        #pragma unroll
        for (int kc = 0; kc < 2; ++kc) {
            short8 ak = *(const short8*)&kdT_bf[(it * 16 + l15) * 72 + kc * 32 + hi * 8];
            short8 bv = *(const short8*)&VT_bf[(jt * 16 + l15) * 72 + kc * 32 + hi * 8];
            mc = __builtin_amdgcn_mfma_f32_16x16x32_bf16(ak, bv, mc, 0, 0, 0);
        }
        #pragma unroll
        for (int rr = 0; rr < 4; ++rr)
            MT_ws[base + (size_t)(jt * 16 + l15) * 32 + it * 16 + hi * 4 + rr] = mc[rr];
    }
    if (tid < 32) D_ws[(size_t)(bh * NCH + c) * 32 + tid] = expf(Z[tid]);
}

// ---------------- phase B: chunk-state recurrence on transposed layout [j*32+i] ----------------
__global__ __launch_bounds__(256) void phaseB(const float* __restrict__ MT_ws,
                                              const float* __restrict__ D_ws,
                                              float* __restrict__ HT_ws) {
    int idx = blockIdx.x * 256 + threadIdx.x;
    int bh = idx >> 11;
    int ji = idx & 2047;
    int i = ji & 31;
    float h = 0.f;
    size_t base = (size_t)bh * NCH * 2048 + ji;
    const float* dp = D_ws + (size_t)bh * NCH * 32 + i;
    for (int c = 0; c < NCH; ++c) {
        HT_ws[base + (size_t)c * 2048] = h;
        h = h * dp[c * 32] + MT_ws[base + (size_t)c * 2048];
    }
}

// ---------------- phase C (MFMA): score->mask->P, O = P@V + qh@H, fused RMS/swish ----------------
__global__ __launch_bounds__(256) void phaseC(const u16* __restrict__ qkvg,
                                              const float* __restrict__ W2,
                                              const float* __restrict__ b2,
                                              const float* __restrict__ HT_ws,
                                              const float* __restrict__ gnw,
                                              u16* __restrict__ o_n) {
    int bh = blockIdx.x >> 6, c = blockIdx.x & 63;
    int b = bh >> 4, h = bh & 15;
    int t0 = b * TT + c * CHUNK;
    __shared__ float gkS[64][36];
    __shared__ u16 qh_bf[64 * 40];
    __shared__ u16 kt_bf[64 * 40];
    __shared__ u16 VT_bf[64 * 72];
    __shared__ u16 Ht_bf[64 * 40];
    u16* P_bf = (u16*)&gkS[0][0];
    int tid = threadIdx.x;
    int s = tid >> 2, i0 = (tid & 3) << 3;
    {
        float ls[8];
        gate_z8(qkvg + (size_t)(t0 + s) * QSTR + 3072, W2, b2, h * DK + i0, ls);
        #pragma unroll
        for (int jj = 0; jj < 8; ++jj) gkS[s][i0 + jj] = ls[jj];
    }
    short8 qv = *(const short8*)(qkvg + (size_t)(t0 + s) * QSTR + h * DK + i0);
    short8 kv = *(const short8*)(qkvg + (size_t)(t0 + s) * QSTR + 512 + h * DK + i0);
    {
        int j0 = (tid & 3) << 4;
        short8 v0 = *(const short8*)(qkvg + (size_t)(t0 + s) * QSTR + 1024 + h * DV + j0);
        short8 v1 = *(const short8*)(qkvg + (size_t)(t0 + s) * QSTR + 1024 + h * DV + j0 + 8);
        #pragma unroll
        for (int jj = 0; jj < 8; ++jj) {
            VT_bf[(j0 + jj) * 72 + s] = (u16)v0[jj];
            VT_bf[(j0 + 8 + jj) * 72 + s] = (u16)v1[jj];
        }
    }
    {
        const float* hp = HT_ws + ((size_t)(bh * NCH + c)) * 2048 + tid * 8;
        float4 h0 = *(const float4*)hp;
        float4 h1 = *(const float4*)(hp + 4);
        int j = tid >> 2, ii0 = (tid & 3) << 3;
        ushort4 o0, o1;
        o0.x = f2bf(h0.x); o0.y = f2bf(h0.y); o0.z = f2bf(h0.z); o0.w = f2bf(h0.w);
        o1.x = f2bf(h1.x); o1.y = f2bf(h1.y); o1.z = f2bf(h1.z); o1.w = f2bf(h1.w);
        *(ushort4*)&Ht_bf[j * 40 + ii0] = o0;
        *(ushort4*)&Ht_bf[j * 40 + ii0 + 4] = o1;
    }
    __syncthreads();
    if (tid < 32) {
        float run = 0.f;
        for (int t = 0; t < 64; ++t) { run += gkS[t][tid]; gkS[t][tid] = run; }
    }
    __syncthreads();
    #pragma unroll
    for (int jj = 0; jj < 8; ++jj) {
        float Sv = gkS[s][i0 + jj];
        qh_bf[s * 40 + i0 + jj] = f2bf(bf2f((u16)qv[jj]) * expf(Sv) * SCALE);
        kt_bf[s * 40 + i0 + jj] = f2bf(bf2f((u16)kv[jj]) * expf(fminf(-Sv, 80.f)));
    }
    __syncthreads();
    int wave = tid >> 6, lane = tid & 63, l15 = lane & 15, hi = lane >> 4;
    int w = wave;
    short8 aq = *(const short8*)&qh_bf[(w * 16 + l15) * 40 + hi * 8];
    #pragma unroll
    for (int sn = 0; sn < 4; ++sn) {
        f32x4 sc = (f32x4){0.f, 0.f, 0.f, 0.f};
        if (sn <= w) {
            short8 bk = *(const short8*)&kt_bf[(sn * 16 + l15) * 40 + hi * 8];
            sc = __builtin_amdgcn_mfma_f32_16x16x32_bf16(aq, bk, sc, 0, 0, 0);
        }
        #pragma unroll
        for (int rr = 0; rr < 4; ++rr) {
            float val = sc[rr];
            if (sn > w || (sn == w && l15 > hi * 4 + rr)) val = 0.f;
            P_bf[(w * 16 + hi * 4 + rr) * 72 + sn * 16 + l15] = f2bf(val);
        }
    }
    __syncthreads();
    f32x4 acc[4];
    #pragma unroll
    for (int jn = 0; jn < 4; ++jn) {
        f32x4 a = (f32x4){0.f, 0.f, 0.f, 0.f};
        short8 bhf = *(const short8*)&Ht_bf[(jn * 16 + l15) * 40 + hi * 8];
        acc[jn] = __builtin_amdgcn_mfma_f32_16x16x32_bf16(aq, bhf, a, 0, 0, 0);
    }
    int nkc = (w < 2) ? 1 : 2;
    for (int kc = 0; kc < nkc; ++kc) {
        short8 ap = *(const short8*)&P_bf[(w * 16 + l15) * 72 + kc * 32 + hi * 8];
        #pragma unroll
        for (int jn = 0; jn < 4; ++jn) {
            short8 bv = *(const short8*)&VT_bf[(jn * 16 + l15) * 72 + kc * 32 + hi * 8];
            acc[jn] = __builtin_amdgcn_mfma_f32_16x16x32_bf16(ap, bv, acc[jn], 0, 0, 0);
        }
    }
    #pragma unroll
    for (int rr = 0; rr < 4; ++rr) {
        float sum2 = 0.f;
        #pragma unroll
        for (int jn = 0; jn < 4; ++jn) sum2 += acc[jn][rr] * acc[jn][rr];
        sum2 += __shfl_xor(sum2, 1);
        sum2 += __shfl_xor(sum2, 2);
        sum2 += __shfl_xor(sum2, 4);
        sum2 += __shfl_xor(sum2, 8);
        float rms = rsqrtf(sum2 * (1.f / 64.f) + 1e-5f);
        int t = w * 16 + hi * 4 + rr;
        #pragma unroll
        for (int jn = 0; jn < 4; ++jn) {
            int j = jn * 16 + l15;
            float g = bf2f(qkvg[(size_t)(t0 + t) * QSTR + 2048 + h * DV + j]);
            float sw = g / (1.f + expf(-g));
            float o = acc[jn][rr] * rms * gnw[j] * sw;
            o_n[(size_t)(t0 + t) * 1024 + h * DV + j] = f2bf(o);
        }
    }
}

// ---------------- launch ----------------
extern "C" void kernel_launch(void* const* d_in, const int* in_sizes, int n_in,
                              void* d_out, int out_size, void* d_ws, size_t ws_size,
                              hipStream_t stream) {
    const float* x    = (const float*)d_in[0];
    const float* Wq   = (const float*)d_in[1];
    const float* Wk   = (const float*)d_in[2];
    const float* Wv   = (const float*)d_in[3];
    const float* Wgk1 = (const float*)d_in[4];
    const float* Wgk2 = (const float*)d_in[5];
    const float* bgk2 = (const float*)d_in[6];
    const float* Wg   = (const float*)d_in[7];
    const float* gnw  = (const float*)d_in[8];
    const float* Wo   = (const float*)d_in[9];

    char* ws = (char*)d_ws;
    size_t off = 0;
    u16* xb      = (u16*)(ws + off); off += (size_t)MROWS * 1024 * 2;          // 16.8 MB
    u16* Wall    = (u16*)(ws + off); off += (size_t)4352 * 1024 * 2;           // 8.9 MB (WcatT | WoT)
    u16* qkvg    = (u16*)(ws + off); off += (size_t)MROWS * QSTR * 2;          // 54.5 MB
    float* MT_ws = (float*)(ws + off); off += (size_t)NBH * NCH * 2048 * 4;    // 16.8 MB
    float* D_ws  = (float*)(ws + off); off += (size_t)NBH * NCH * 32 * 4;      // 0.26 MB
    float* HT_ws = (float*)(ws + off); off += (size_t)NBH * NCH * 2048 * 4;    // 16.8 MB
    u16* o_n     = (u16*)(ws + off); off += (size_t)MROWS * 1024 * 2;          // 16.8 MB
    u16* WcatT   = Wall;
    u16* WoT     = Wall + (size_t)3328 * 1024;

    f32_to_bf16_vec<<<MROWS, 256, 0, stream>>>(x, xb, MROWS * 1024 / 4);
    weight_prep<<<dim3(136, 32), 256, 0, stream>>>(Wq, Wk, Wv, Wg, Wgk1, Wo, Wall);
    gemm8<1><<<416, 512, 0, stream>>>(xb, WcatT, qkvg, MROWS, QSTR, 1024, 13);
    phaseA<<<NBH * NCH, 256, 0, stream>>>(qkvg, Wgk2, bgk2, MT_ws, D_ws);
    phaseB<<<256, 256, 0, stream>>>(MT_ws, D_ws, HT_ws);
    phaseC<<<NBH * NCH, 256, 0, stream>>>(qkvg, Wgk2, bgk2, HT_ws, gnw, o_n);
    gemm8<0><<<128, 512, 0, stream>>>(o_n, WoT, d_out, MROWS, 1024, 1024, 4);
}

// Round 8
// 174.002 us; speedup vs baseline: 3.0286x; 1.0399x over previous
//
#include <hip/hip_runtime.h>

typedef unsigned short u16;
typedef unsigned int u32;
typedef __attribute__((ext_vector_type(8))) short short8;
typedef __attribute__((ext_vector_type(4))) float f32x4;

#define KD 512
#define HEADS 16
#define DK 32
#define DV 64
#define TT 4096
#define MROWS 8192           // B*T
#define CHUNK 64
#define NCH 64               // T/CHUNK
#define NBH 32               // B*HEADS
#define QSTR 3328            // qkvg row stride (q 0 | k 512 | v 1024 | g 2048 | xg1 3072 | pad to 13*256)
#define SCALE 0.17677669529663687f  // 32^-0.5

__device__ __forceinline__ u16 f2bf(float f) {
    union { float f; unsigned int u; } x; x.f = f;
    unsigned int u = x.u;
    unsigned int r = (u + 0x7fffu + ((u >> 16) & 1u)) >> 16;
    return (u16)r;
}
__device__ __forceinline__ float bf2f(u16 s) {
    union { unsigned int u; float f; } x; x.u = ((unsigned int)s) << 16;
    return x.f;
}
__device__ __forceinline__ void gload16(const u16* g, u16* l) {
    __builtin_amdgcn_global_load_lds((const __attribute__((address_space(1))) u32*)g,
                                     (__attribute__((address_space(3))) u32*)l, 16, 0, 0);
}

// ---------------- x f32 -> bf16 (coalesced) ----------------
__global__ __launch_bounds__(256) void f32_to_bf16_vec(const float* __restrict__ src,
                                                       u16* __restrict__ dst, int n4) {
    int i = blockIdx.x * 256 + threadIdx.x;
    if (i < n4) {
        const float4 v = ((const float4*)src)[i];
        ushort4 o;
        o.x = f2bf(v.x); o.y = f2bf(v.y); o.z = f2bf(v.z); o.w = f2bf(v.w);
        ((ushort4*)dst)[i] = o;
    }
}

// ---------------- all weights -> transposed bf16, one kernel ----------------
// dst rows: [0,512) WqT | [512,1024) WkT | [1024,2048) WvT | [2048,3072) WgT
//           [3072,3088) W1T | [3088,3328) zero | [3328,4352) WoT
__global__ __launch_bounds__(256) void weight_prep(const float* __restrict__ Wq,
                                                   const float* __restrict__ Wk,
                                                   const float* __restrict__ Wv,
                                                   const float* __restrict__ Wg,
                                                   const float* __restrict__ W1,
                                                   const float* __restrict__ Wo,
                                                   u16* __restrict__ dst) {
    __shared__ float tile[32][33];
    int n0 = blockIdx.x * 32, k0 = blockIdx.y * 32;
    int tx = threadIdx.x & 31, ty = threadIdx.x >> 5;
    int n = n0 + tx;
    const float* src; int sN, cc;
    if (n < 512)       { src = Wq; sN = 512;  cc = n; }
    else if (n < 1024) { src = Wk; sN = 512;  cc = n - 512; }
    else if (n < 2048) { src = Wv; sN = 1024; cc = n - 1024; }
    else if (n < 3072) { src = Wg; sN = 1024; cc = n - 2048; }
    else if (n < 3088) { src = W1; sN = 16;   cc = n - 3072; }
    else if (n < 3328) { src = nullptr; sN = 0; cc = 0; }
    else               { src = Wo; sN = 1024; cc = n - 3328; }
    for (int r = ty; r < 32; r += 8)
        tile[r][tx] = src ? src[(size_t)(k0 + r) * sN + cc] : 0.f;
    __syncthreads();
    for (int r = ty; r < 32; r += 8)
        dst[(size_t)(n0 + r) * 1024 + k0 + tx] = f2bf(tile[tx][r]);
}

// ======================= 6-phase 256x256 GEMM (T2+T3+T4+T5) =======================
// 512 thr / 8 waves (2M x 4N), BK=64, LDS 128KB dbuf. 6 phases per 2-K-tile iteration
// (merged the two read-free phases of the 8-phase form -> 12 barriers/iter).
// Counted vmcnt ring: VMW(8) end-P3, VMW(10) end-P5, VMW(6) end-P6; all stage->read
// leads >= 4 phases, all read->overwrite gaps >= 1 barrier (derivation in R8 notes).
#define BARM() do { asm volatile("" ::: "memory"); __builtin_amdgcn_s_barrier(); asm volatile("" ::: "memory"); } while (0)
#define VMW(n) asm volatile("s_waitcnt vmcnt(" #n ")" ::: "memory")

template<int OUTBF>
__global__ __launch_bounds__(512, 2) void gemm8(const u16* __restrict__ A,
                                                const u16* __restrict__ Bt,
                                                void* __restrict__ C,
                                                int M, int N, int K, int nbx) {
    __shared__ u16 SA[2][16384];
    __shared__ u16 SB[2][16384];
    int nwg = gridDim.x, bid = blockIdx.x, cpx = nwg >> 3;
    int wg = (bid & 7) * cpx + (bid >> 3);       // XCD-chunked, bijective (nwg%8==0)
    int bx = wg % nbx, by = wg / nbx;
    int brow = by << 8, bcol = bx << 8;
    int tid = threadIdx.x;
    int wv = tid >> 6, lane = tid & 63;
    int wm = wv >> 2, wn = wv & 3;               // wave -> 128x64 C block
    int l15 = lane & 15, hi = lane >> 4;
    int rxor = l15 & 7;

    int srw = tid >> 3;                          // 0..63 perm-row within instr
    int sg8 = ((tid & 7) ^ (srw & 7)) << 3;      // swizzled source granule (u16 units)
    const u16* aBase = A + (size_t)(brow + srw) * K + sg8;
    const u16* bBase = Bt + (size_t)(bcol + ((tid >> 8) << 6) + (srw & 31)) * K + sg8;

#define STAGE_A(b, h, tt) do { \
        const u16* s_ = aBase + (size_t)(tt) * 64 + (size_t)(h) * 64 * K; \
        gload16(s_,                    &SA[b][(h) * 8192 + tid * 8]); \
        gload16(s_ + (size_t)128 * K,  &SA[b][(h) * 8192 + 4096 + tid * 8]); \
    } while (0)
#define STAGE_B(b, h, tt) do { \
        const u16* s_ = bBase + (size_t)(tt) * 64 + (size_t)(h) * 32 * K; \
        gload16(s_,                    &SB[b][(h) * 8192 + tid * 8]); \
        gload16(s_ + (size_t)128 * K,  &SB[b][(h) * 8192 + 4096 + tid * 8]); \
    } while (0)

    int aRow = (wm * 64 + l15) * 64;
    int bRow = (wn * 32 + l15) * 64;
    int cg0 = (hi ^ rxor) << 3;
    int cg1 = ((4 + hi) ^ rxor) << 3;

#define READ_A(dst, mh, b) do { \
        _Pragma("unroll") \
        for (int mil_ = 0; mil_ < 4; ++mil_) { \
            dst[mil_ * 2 + 0] = *(const short8*)&SA[b][(mh) * 8192 + mil_ * 1024 + aRow + cg0]; \
            dst[mil_ * 2 + 1] = *(const short8*)&SA[b][(mh) * 8192 + mil_ * 1024 + aRow + cg1]; \
        } } while (0)
#define READ_B(dst, nh, b) do { \
        _Pragma("unroll") \
        for (int nil_ = 0; nil_ < 2; ++nil_) { \
            dst[nil_ * 2 + 0] = *(const short8*)&SB[b][(nh) * 8192 + nil_ * 1024 + bRow + cg0]; \
            dst[nil_ * 2 + 1] = *(const short8*)&SB[b][(nh) * 8192 + nil_ * 1024 + bRow + cg1]; \
        } } while (0)

    f32x4 acc[8][4];
    #pragma unroll
    for (int mi = 0; mi < 8; ++mi)
        #pragma unroll
        for (int ni = 0; ni < 4; ++ni)
            acc[mi][ni] = (f32x4){0.f, 0.f, 0.f, 0.f};

#define MM(mb, nb, AF, BF) do { \
        __builtin_amdgcn_s_setprio(1); \
        _Pragma("unroll") \
        for (int ks_ = 0; ks_ < 2; ++ks_) \
        _Pragma("unroll") \
        for (int mil_ = 0; mil_ < 4; ++mil_) \
        _Pragma("unroll") \
        for (int nil_ = 0; nil_ < 2; ++nil_) \
            acc[(mb) + mil_][(nb) + nil_] = __builtin_amdgcn_mfma_f32_16x16x32_bf16( \
                AF[mil_ * 2 + ks_], BF[nil_ * 2 + ks_], acc[(mb) + mil_][(nb) + nil_], 0, 0, 0); \
        __builtin_amdgcn_s_setprio(0); \
    } while (0)

    int NK = K >> 6, NI = NK >> 1;
    // prologue: buf0 <- t0 (4 regions), buf1 <- t1 (3 of 4; B1-hi staged at iter0 P1)
    STAGE_B(0, 0, 0); STAGE_A(0, 0, 0); STAGE_A(0, 1, 0); STAGE_B(0, 1, 0);
    STAGE_B(1, 0, 1); STAGE_A(1, 0, 1); STAGE_A(1, 1, 1);
    VMW(6);            // t0's 4 regions landed
    BARM();

    short8 alo[8], ahi[8], bb[4];
    for (int i = 0; i < NI; ++i) {
        int ta = 2 * i + 1; if (ta >= NK) ta = NK - 1;
        int tb = 2 * i + 2; if (tb >= NK) tb = NK - 1;
        int tc = 2 * i + 3; if (tc >= NK) tc = NK - 1;
        // ---- half 0: tile 2i from buf0 ----
        STAGE_B(1, 1, ta);                 // P1: B1-hi <- 2i+1 (read at P6)
        READ_A(alo, 0, 0); READ_B(bb, 0, 0);
        BARM(); MM(0, 0, alo, bb); BARM();
        STAGE_B(0, 0, tb);                 // P2: B0-lo <- 2i+2
        READ_A(ahi, 1, 0);
        BARM(); MM(4, 0, ahi, bb); BARM();
        STAGE_A(0, 0, tb); STAGE_A(0, 1, tb);   // P3: A0-lo, A0-hi <- 2i+2
        READ_B(bb, 1, 0);
        BARM(); MM(4, 2, ahi, bb); MM(0, 2, alo, bb);
        VMW(8);                            // prev-iter buf1 stages landed -> buf1 ready
        BARM();
        // ---- half 1: tile 2i+1 from buf1 ----
        STAGE_B(0, 1, tb);                 // P4: B0-hi <- 2i+2
        READ_A(alo, 0, 1); READ_B(bb, 0, 1);
        BARM(); MM(0, 0, alo, bb); BARM();
        STAGE_B(1, 0, tc);                 // P5: B1-lo <- 2i+3
        READ_A(ahi, 1, 1);
        BARM(); MM(4, 0, ahi, bb);
        VMW(10);                           // P1's B1-hi landed -> P6 read ready
        BARM();
        STAGE_A(1, 0, tc); STAGE_A(1, 1, tc);   // P6: A1-lo, A1-hi <- 2i+3
        READ_B(bb, 1, 1);
        BARM(); MM(4, 2, ahi, bb); MM(0, 2, alo, bb);
        VMW(6);                            // tb's 4 regions (P2,P3,P4) landed -> buf0 ready
        BARM();
    }

    int r0 = brow + wm * 128 + (hi << 2);
    int c0 = bcol + wn * 64 + l15;
    #pragma unroll
    for (int mi = 0; mi < 8; ++mi)
        #pragma unroll
        for (int ni = 0; ni < 4; ++ni)
            #pragma unroll
            for (int rr = 0; rr < 4; ++rr) {
                size_t idx = (size_t)(r0 + mi * 16 + rr) * N + (c0 + ni * 16);
                float val = acc[mi][ni][rr];
                if (OUTBF) ((u16*)C)[idx] = f2bf(val);
                else       ((float*)C)[idx] = val;
            }
#undef STAGE_A
#undef STAGE_B
#undef READ_A
#undef READ_B
#undef MM
}

// ---------------- 2-phase 128x128 GEMM (for the N=1024 out-proj: 512 blocks, 5/CU) ----
template<int OUTBF>
__global__ __launch_bounds__(256) void gemm_sb(const u16* __restrict__ A,
                                               const u16* __restrict__ Bt,
                                               void* __restrict__ C,
                                               int M, int N, int K, int nbx) {
    __shared__ u16 As[128 * 64];
    __shared__ u16 Bs[128 * 64];
    int nwg = gridDim.x;
    int bid = blockIdx.x;
    int cpx = nwg >> 3;
    int wg = (bid & 7) * cpx + (bid >> 3);   // XCD-chunked, bijective (nwg%8==0)
    int bx = wg % nbx, by = wg / nbx;
    int tid = threadIdx.x;
    int wave = tid >> 6, lane = tid & 63;
    int wr = wave >> 1, wc = wave & 1;       // 2x2 waves, each owns 64x64
    int brow = by * 128, bcol = bx * 128;
    int srow = tid >> 3;
    int sgrp = (tid & 7) ^ (srow & 7);
    const u16* aS = A + (size_t)(brow + srow) * K + sgrp * 8;
    const u16* bS = Bt + (size_t)(bcol + srow) * K + sgrp * 8;
    f32x4 acc[4][4];
    #pragma unroll
    for (int mi = 0; mi < 4; ++mi)
        #pragma unroll
        for (int ni = 0; ni < 4; ++ni)
            acc[mi][ni] = (f32x4){0.f, 0.f, 0.f, 0.f};
    int l15 = lane & 15, hi = lane >> 4;
    int rxor = l15 & 7;
    for (int kt = 0; kt < K; kt += 64) {
        __syncthreads();
        #pragma unroll
        for (int i_ = 0; i_ < 4; ++i_) {
            gload16(aS + (size_t)i_ * 32 * K + kt, As + tid * 8 + i_ * 2048);
            gload16(bS + (size_t)i_ * 32 * K + kt, Bs + tid * 8 + i_ * 2048);
        }
        __syncthreads();
        #pragma unroll
        for (int ks = 0; ks < 2; ++ks) {
            short8 af[4], bfr[4];
            int g = ks * 4 + hi;
            #pragma unroll
            for (int i = 0; i < 4; ++i)
                af[i] = *(const short8*)(As + (size_t)(wr * 64 + i * 16 + l15) * 64 + ((g ^ rxor) << 3));
            #pragma unroll
            for (int i = 0; i < 4; ++i)
                bfr[i] = *(const short8*)(Bs + (size_t)(wc * 64 + i * 16 + l15) * 64 + ((g ^ rxor) << 3));
            #pragma unroll
            for (int mi = 0; mi < 4; ++mi)
                #pragma unroll
                for (int ni = 0; ni < 4; ++ni)
                    acc[mi][ni] = __builtin_amdgcn_mfma_f32_16x16x32_bf16(af[mi], bfr[ni], acc[mi][ni], 0, 0, 0);
        }
    }
    int r0 = brow + wr * 64 + (hi << 2);
    int c0 = bcol + wc * 64 + l15;
    #pragma unroll
    for (int mi = 0; mi < 4; ++mi)
        #pragma unroll
        for (int ni = 0; ni < 4; ++ni)
            #pragma unroll
            for (int rr = 0; rr < 4; ++rr) {
                size_t idx = (size_t)(r0 + mi * 16 + rr) * N + (c0 + ni * 16);
                float val = acc[mi][ni][rr];
                if (OUTBF) ((u16*)C)[idx] = f2bf(val);
                else       ((float*)C)[idx] = val;
            }
}

// ---------------- gate slice: ls[j] = logsigmoid(xg1·W2[:,cc+j] + b2)/16, j=0..7 ----------------
__device__ __forceinline__ void gate_z8(const u16* __restrict__ xg,
                                        const float* __restrict__ W2,
                                        const float* __restrict__ b2,
                                        int cc, float* out8) {
    short8 x0 = *(const short8*)xg;
    short8 x1 = *(const short8*)(xg + 8);
    float z[8];
    float4 z0 = *(const float4*)(b2 + cc);
    float4 z1 = *(const float4*)(b2 + cc + 4);
    z[0]=z0.x; z[1]=z0.y; z[2]=z0.z; z[3]=z0.w;
    z[4]=z1.x; z[5]=z1.y; z[6]=z1.z; z[7]=z1.w;
    #pragma unroll
    for (int u = 0; u < 16; ++u) {
        float xu = bf2f((u16)(u < 8 ? x0[u] : x1[u - 8]));
        const float4 w0 = *(const float4*)(W2 + (size_t)u * 512 + cc);
        const float4 w1 = *(const float4*)(W2 + (size_t)u * 512 + cc + 4);
        z[0] += xu * w0.x; z[1] += xu * w0.y; z[2] += xu * w0.z; z[3] += xu * w0.w;
        z[4] += xu * w1.x; z[5] += xu * w1.y; z[6] += xu * w1.z; z[7] += xu * w1.w;
    }
    #pragma unroll
    for (int j = 0; j < 8; ++j) {
        float zz = z[j];
        out8[j] = (fminf(zz, 0.f) - log1pf(expf(-fabsf(zz)))) * 0.0625f;
    }
}

// ---------------- phase A (MFMA): gate+cumsum; M^T via mfma -> MT, D ----------------
__global__ __launch_bounds__(256) void phaseA(const u16* __restrict__ qkvg,
                                              const float* __restrict__ W2,
                                              const float* __restrict__ b2,
                                              float* __restrict__ MT_ws,
                                              float* __restrict__ D_ws) {
    int bh = blockIdx.x >> 6, c = blockIdx.x & 63;
    int b = bh >> 4, h = bh & 15;
    int t0 = b * TT + c * CHUNK;
    __shared__ float gkS[64][36];
    __shared__ u16 kdT_bf[32 * 72];
    __shared__ u16 VT_bf[64 * 72];
    __shared__ float Z[32];
    int tid = threadIdx.x;
    int s = tid >> 2, i0 = (tid & 3) << 3;
    {
        float ls[8];
        gate_z8(qkvg + (size_t)(t0 + s) * QSTR + 3072, W2, b2, h * DK + i0, ls);
        #pragma unroll
        for (int jj = 0; jj < 8; ++jj) gkS[s][i0 + jj] = ls[jj];
    }
    short8 kv = *(const short8*)(qkvg + (size_t)(t0 + s) * QSTR + 512 + h * DK + i0);
    {
        int j0 = (tid & 3) << 4;
        short8 v0 = *(const short8*)(qkvg + (size_t)(t0 + s) * QSTR + 1024 + h * DV + j0);
        short8 v1 = *(const short8*)(qkvg + (size_t)(t0 + s) * QSTR + 1024 + h * DV + j0 + 8);
        #pragma unroll
        for (int jj = 0; jj < 8; ++jj) {
            VT_bf[(j0 + jj) * 72 + s] = (u16)v0[jj];
            VT_bf[(j0 + 8 + jj) * 72 + s] = (u16)v1[jj];
        }
    }
    __syncthreads();
    if (tid < 32) {
        float run = 0.f;
        for (int t = 0; t < 64; ++t) { run += gkS[t][tid]; gkS[t][tid] = run; }
        Z[tid] = run;
    }
    __syncthreads();
    #pragma unroll
    for (int jj = 0; jj < 8; ++jj)
        kdT_bf[(i0 + jj) * 72 + s] = f2bf(expf(Z[i0 + jj] - gkS[s][i0 + jj]) * bf2f((u16)kv[jj]));
    __syncthreads();
    int wave = tid >> 6, lane = tid & 63, l15 = lane & 15, hi = lane >> 4;
    int it = wave & 1, jp = wave >> 1;
    size_t base = ((size_t)(bh * NCH + c)) * 2048;
    #pragma unroll
    for (int jj2 = 0; jj2 < 2; ++jj2) {
        int jt = jp * 2 + jj2;
        f32x4 mc = (f32x4){0.f, 0.f, 0.f, 0.f};
        #pragma unroll
        for (int kc = 0; kc < 2; ++kc) {
            short8 ak = *(const short8*)&kdT_bf[(it * 16 + l15) * 72 + kc * 32 + hi * 8];
            short8 bv = *(const short8*)&VT_bf[(jt * 16 + l15) * 72 + kc * 32 + hi * 8];
            mc = __builtin_amdgcn_mfma_f32_16x16x32_bf16(ak, bv, mc, 0, 0, 0);
        }
        #pragma unroll
        for (int rr = 0; rr < 4; ++rr)
            MT_ws[base + (size_t)(jt * 16 + l15) * 32 + it * 16 + hi * 4 + rr] = mc[rr];
    }
    if (tid < 32) D_ws[(size_t)(bh * NCH + c) * 32 + tid] = expf(Z[tid]);
}

// ---------------- phase B: chunk-state recurrence on transposed layout [j*32+i] ----------------
__global__ __launch_bounds__(256) void phaseB(const float* __restrict__ MT_ws,
                                              const float* __restrict__ D_ws,
                                              float* __restrict__ HT_ws) {
    int idx = blockIdx.x * 256 + threadIdx.x;
    int bh = idx >> 11;
    int ji = idx & 2047;
    int i = ji & 31;
    float h = 0.f;
    size_t base = (size_t)bh * NCH * 2048 + ji;
    const float* dp = D_ws + (size_t)bh * NCH * 32 + i;
    for (int c = 0; c < NCH; ++c) {
        HT_ws[base + (size_t)c * 2048] = h;
        h = h * dp[c * 32] + MT_ws[base + (size_t)c * 2048];
    }
}

// ---------------- phase C (MFMA): score->mask->P, O = P@V + qh@H, fused RMS/swish ----------------
__global__ __launch_bounds__(256) void phaseC(const u16* __restrict__ qkvg,
                                              const float* __restrict__ W2,
                                              const float* __restrict__ b2,
                                              const float* __restrict__ HT_ws,
                                              const float* __restrict__ gnw,
                                              u16* __restrict__ o_n) {
    int bh = blockIdx.x >> 6, c = blockIdx.x & 63;
    int b = bh >> 4, h = bh & 15;
    int t0 = b * TT + c * CHUNK;
    __shared__ float gkS[64][36];
    __shared__ u16 qh_bf[64 * 40];
    __shared__ u16 kt_bf[64 * 40];
    __shared__ u16 VT_bf[64 * 72];
    __shared__ u16 Ht_bf[64 * 40];
    u16* P_bf = (u16*)&gkS[0][0];
    int tid = threadIdx.x;
    int s = tid >> 2, i0 = (tid & 3) << 3;
    {
        float ls[8];
        gate_z8(qkvg + (size_t)(t0 + s) * QSTR + 3072, W2, b2, h * DK + i0, ls);
        #pragma unroll
        for (int jj = 0; jj < 8; ++jj) gkS[s][i0 + jj] = ls[jj];
    }
    short8 qv = *(const short8*)(qkvg + (size_t)(t0 + s) * QSTR + h * DK + i0);
    short8 kv = *(const short8*)(qkvg + (size_t)(t0 + s) * QSTR + 512 + h * DK + i0);
    {
        int j0 = (tid & 3) << 4;
        short8 v0 = *(const short8*)(qkvg + (size_t)(t0 + s) * QSTR + 1024 + h * DV + j0);
        short8 v1 = *(const short8*)(qkvg + (size_t)(t0 + s) * QSTR + 1024 + h * DV + j0 + 8);
        #pragma unroll
        for (int jj = 0; jj < 8; ++jj) {
            VT_bf[(j0 + jj) * 72 + s] = (u16)v0[jj];
            VT_bf[(j0 + 8 + jj) * 72 + s] = (u16)v1[jj];
        }
    }
    {
        const float* hp = HT_ws + ((size_t)(bh * NCH + c)) * 2048 + tid * 8;
        float4 h0 = *(const float4*)hp;
        float4 h1 = *(const float4*)(hp + 4);
        int j = tid >> 2, ii0 = (tid & 3) << 3;
        ushort4 o0, o1;
        o0.x = f2bf(h0.x); o0.y = f2bf(h0.y); o0.z = f2bf(h0.z); o0.w = f2bf(h0.w);
        o1.x = f2bf(h1.x); o1.y = f2bf(h1.y); o1.z = f2bf(h1.z); o1.w = f2bf(h1.w);
        *(ushort4*)&Ht_bf[j * 40 + ii0] = o0;
        *(ushort4*)&Ht_bf[j * 40 + ii0 + 4] = o1;
    }
    __syncthreads();
    if (tid < 32) {
        float run = 0.f;
        for (int t = 0; t < 64; ++t) { run += gkS[t][tid]; gkS[t][tid] = run; }
    }
    __syncthreads();
    #pragma unroll
    for (int jj = 0; jj < 8; ++jj) {
        float Sv = gkS[s][i0 + jj];
        qh_bf[s * 40 + i0 + jj] = f2bf(bf2f((u16)qv[jj]) * expf(Sv) * SCALE);
        kt_bf[s * 40 + i0 + jj] = f2bf(bf2f((u16)kv[jj]) * expf(fminf(-Sv, 80.f)));
    }
    __syncthreads();
    int wave = tid >> 6, lane = tid & 63, l15 = lane & 15, hi = lane >> 4;
    int w = wave;
    short8 aq = *(const short8*)&qh_bf[(w * 16 + l15) * 40 + hi * 8];
    #pragma unroll
    for (int sn = 0; sn < 4; ++sn) {
        f32x4 sc = (f32x4){0.f, 0.f, 0.f, 0.f};
        if (sn <= w) {
            short8 bk = *(const short8*)&kt_bf[(sn * 16 + l15) * 40 + hi * 8];
            sc = __builtin_amdgcn_mfma_f32_16x16x32_bf16(aq, bk, sc, 0, 0, 0);
        }
        #pragma unroll
        for (int rr = 0; rr < 4; ++rr) {
            float val = sc[rr];
            if (sn > w || (sn == w && l15 > hi * 4 + rr)) val = 0.f;
            P_bf[(w * 16 + hi * 4 + rr) * 72 + sn * 16 + l15] = f2bf(val);
        }
    }
    __syncthreads();
    f32x4 acc[4];
    #pragma unroll
    for (int jn = 0; jn < 4; ++jn) {
        f32x4 a = (f32x4){0.f, 0.f, 0.f, 0.f};
        short8 bhf = *(const short8*)&Ht_bf[(jn * 16 + l15) * 40 + hi * 8];
        acc[jn] = __builtin_amdgcn_mfma_f32_16x16x32_bf16(aq, bhf, a, 0, 0, 0);
    }
    int nkc = (w < 2) ? 1 : 2;
    for (int kc = 0; kc < nkc; ++kc) {
        short8 ap = *(const short8*)&P_bf[(w * 16 + l15) * 72 + kc * 32 + hi * 8];
        #pragma unroll
        for (int jn = 0; jn < 4; ++jn) {
            short8 bv = *(const short8*)&VT_bf[(jn * 16 + l15) * 72 + kc * 32 + hi * 8];
            acc[jn] = __builtin_amdgcn_mfma_f32_16x16x32_bf16(ap, bv, acc[jn], 0, 0, 0);
        }
    }
    #pragma unroll
    for (int rr = 0; rr < 4; ++rr) {
        float sum2 = 0.f;
        #pragma unroll
        for (int jn = 0; jn < 4; ++jn) sum2 += acc[jn][rr] * acc[jn][rr];
        sum2 += __shfl_xor(sum2, 1);
        sum2 += __shfl_xor(sum2, 2);
        sum2 += __shfl_xor(sum2, 4);
        sum2 += __shfl_xor(sum2, 8);
        float rms = rsqrtf(sum2 * (1.f / 64.f) + 1e-5f);
        int t = w * 16 + hi * 4 + rr;
        #pragma unroll
        for (int jn = 0; jn < 4; ++jn) {
            int j = jn * 16 + l15;
            float g = bf2f(qkvg[(size_t)(t0 + t) * QSTR + 2048 + h * DV + j]);
            float sw = g / (1.f + expf(-g));
            float o = acc[jn][rr] * rms * gnw[j] * sw;
            o_n[(size_t)(t0 + t) * 1024 + h * DV + j] = f2bf(o);
        }
    }
}

// ---------------- launch ----------------
extern "C" void kernel_launch(void* const* d_in, const int* in_sizes, int n_in,
                              void* d_out, int out_size, void* d_ws, size_t ws_size,
                              hipStream_t stream) {
    const float* x    = (const float*)d_in[0];
    const float* Wq   = (const float*)d_in[1];
    const float* Wk   = (const float*)d_in[2];
    const float* Wv   = (const float*)d_in[3];
    const float* Wgk1 = (const float*)d_in[4];
    const float* Wgk2 = (const float*)d_in[5];
    const float* bgk2 = (const float*)d_in[6];
    const float* Wg   = (const float*)d_in[7];
    const float* gnw  = (const float*)d_in[8];
    const float* Wo   = (const float*)d_in[9];

    char* ws = (char*)d_ws;
    size_t off = 0;
    u16* xb      = (u16*)(ws + off); off += (size_t)MROWS * 1024 * 2;          // 16.8 MB
    u16* Wall    = (u16*)(ws + off); off += (size_t)4352 * 1024 * 2;           // 8.9 MB (WcatT | WoT)
    u16* qkvg    = (u16*)(ws + off); off += (size_t)MROWS * QSTR * 2;          // 54.5 MB
    float* MT_ws = (float*)(ws + off); off += (size_t)NBH * NCH * 2048 * 4;    // 16.8 MB
    float* D_ws  = (float*)(ws + off); off += (size_t)NBH * NCH * 32 * 4;      // 0.26 MB
    float* HT_ws = (float*)(ws + off); off += (size_t)NBH * NCH * 2048 * 4;    // 16.8 MB
    u16* o_n     = (u16*)(ws + off); off += (size_t)MROWS * 1024 * 2;          // 16.8 MB
    u16* WcatT   = Wall;
    u16* WoT     = Wall + (size_t)3328 * 1024;

    f32_to_bf16_vec<<<MROWS, 256, 0, stream>>>(x, xb, MROWS * 1024 / 4);
    weight_prep<<<dim3(136, 32), 256, 0, stream>>>(Wq, Wk, Wv, Wg, Wgk1, Wo, Wall);
    gemm8<1><<<416, 512, 0, stream>>>(xb, WcatT, qkvg, MROWS, QSTR, 1024, 13);
    phaseA<<<NBH * NCH, 256, 0, stream>>>(qkvg, Wgk2, bgk2, MT_ws, D_ws);
    phaseB<<<256, 256, 0, stream>>>(MT_ws, D_ws, HT_ws);
    phaseC<<<NBH * NCH, 256, 0, stream>>>(qkvg, Wgk2, bgk2, HT_ws, gnw, o_n);
    gemm_sb<0><<<8 * 64, 256, 0, stream>>>(o_n, WoT, d_out, MROWS, 1024, 1024, 8);
}

// Round 9
// 173.504 us; speedup vs baseline: 3.0373x; 1.0029x over previous
//
#include <hip/hip_runtime.h>

typedef unsigned short u16;
typedef unsigned int u32;
typedef __attribute__((ext_vector_type(8))) short short8;
typedef __attribute__((ext_vector_type(4))) float f32x4;

#define KD 512
#define HEADS 16
#define DK 32
#define DV 64
#define TT 4096
#define MROWS 8192           // B*T
#define CHUNK 64
#define NCH 64               // T/CHUNK
#define NBH 32               // B*HEADS
#define QSTR 3328            // qkvg row stride (q 0 | k 512 | v 1024 | g 2048 | xg1 3072 | pad to 13*256)
#define SCALE 0.17677669529663687f  // 32^-0.5

__device__ __forceinline__ u16 f2bf(float f) {
    union { float f; unsigned int u; } x; x.f = f;
    unsigned int u = x.u;
    unsigned int r = (u + 0x7fffu + ((u >> 16) & 1u)) >> 16;
    return (u16)r;
}
__device__ __forceinline__ float bf2f(u16 s) {
    union { unsigned int u; float f; } x; x.u = ((unsigned int)s) << 16;
    return x.f;
}
__device__ __forceinline__ void gload16(const u16* g, u16* l) {
    __builtin_amdgcn_global_load_lds((const __attribute__((address_space(1))) u32*)g,
                                     (__attribute__((address_space(3))) u32*)l, 16, 0, 0);
}

// ---------------- fused prep: x f32->bf16 cast + all weights -> transposed bf16 ----------------
// blocks [0,8192): cast. blocks [8192, 8192+4352): weight transpose.
// Wall rows: [0,512) WqT | [512,1024) WkT | [1024,2048) WvT | [2048,3072) WgT
//            [3072,3088) W1T | [3088,3328) zero | [3328,4352) WoT
__global__ __launch_bounds__(256) void prep_fused(const float* __restrict__ x,
                                                  u16* __restrict__ xb,
                                                  const float* __restrict__ Wq,
                                                  const float* __restrict__ Wk,
                                                  const float* __restrict__ Wv,
                                                  const float* __restrict__ Wg,
                                                  const float* __restrict__ W1,
                                                  const float* __restrict__ Wo,
                                                  u16* __restrict__ dst) {
    __shared__ float tile[32][33];
    int bid = blockIdx.x;
    if (bid < 8192) {
        int i = bid * 256 + threadIdx.x;
        const float4 v = ((const float4*)x)[i];
        ushort4 o;
        o.x = f2bf(v.x); o.y = f2bf(v.y); o.z = f2bf(v.z); o.w = f2bf(v.w);
        ((ushort4*)xb)[i] = o;
        return;
    }
    int w = bid - 8192;
    int n0 = (w % 136) * 32, k0 = (w / 136) * 32;
    int tx = threadIdx.x & 31, ty = threadIdx.x >> 5;
    int n = n0 + tx;
    const float* src; int sN, cc;
    if (n < 512)       { src = Wq; sN = 512;  cc = n; }
    else if (n < 1024) { src = Wk; sN = 512;  cc = n - 512; }
    else if (n < 2048) { src = Wv; sN = 1024; cc = n - 1024; }
    else if (n < 3072) { src = Wg; sN = 1024; cc = n - 2048; }
    else if (n < 3088) { src = W1; sN = 16;   cc = n - 3072; }
    else if (n < 3328) { src = nullptr; sN = 0; cc = 0; }
    else               { src = Wo; sN = 1024; cc = n - 3328; }
    for (int r = ty; r < 32; r += 8)
        tile[r][tx] = src ? src[(size_t)(k0 + r) * sN + cc] : 0.f;
    __syncthreads();
    for (int r = ty; r < 32; r += 8)
        dst[(size_t)(n0 + r) * 1024 + k0 + tx] = f2bf(tile[tx][r]);
}

// ======================= 6-phase 256x256 GEMM (T2+T3+T4+T5) =======================
#define BARM() do { asm volatile("" ::: "memory"); __builtin_amdgcn_s_barrier(); asm volatile("" ::: "memory"); } while (0)
#define VMW(n) asm volatile("s_waitcnt vmcnt(" #n ")" ::: "memory")

template<int OUTBF>
__global__ __launch_bounds__(512, 2) void gemm8(const u16* __restrict__ A,
                                                const u16* __restrict__ Bt,
                                                void* __restrict__ C,
                                                int M, int N, int K, int nbx) {
    __shared__ u16 SA[2][16384];
    __shared__ u16 SB[2][16384];
    int nwg = gridDim.x, bid = blockIdx.x, cpx = nwg >> 3;
    int wg = (bid & 7) * cpx + (bid >> 3);       // XCD-chunked, bijective (nwg%8==0)
    int bx = wg % nbx, by = wg / nbx;
    int brow = by << 8, bcol = bx << 8;
    int tid = threadIdx.x;
    int wv = tid >> 6, lane = tid & 63;
    int wm = wv >> 2, wn = wv & 3;               // wave -> 128x64 C block
    int l15 = lane & 15, hi = lane >> 4;
    int rxor = l15 & 7;

    int srw = tid >> 3;
    int sg8 = ((tid & 7) ^ (srw & 7)) << 3;
    const u16* aBase = A + (size_t)(brow + srw) * K + sg8;
    const u16* bBase = Bt + (size_t)(bcol + ((tid >> 8) << 6) + (srw & 31)) * K + sg8;

#define STAGE_A(b, h, tt) do { \
        const u16* s_ = aBase + (size_t)(tt) * 64 + (size_t)(h) * 64 * K; \
        gload16(s_,                    &SA[b][(h) * 8192 + tid * 8]); \
        gload16(s_ + (size_t)128 * K,  &SA[b][(h) * 8192 + 4096 + tid * 8]); \
    } while (0)
#define STAGE_B(b, h, tt) do { \
        const u16* s_ = bBase + (size_t)(tt) * 64 + (size_t)(h) * 32 * K; \
        gload16(s_,                    &SB[b][(h) * 8192 + tid * 8]); \
        gload16(s_ + (size_t)128 * K,  &SB[b][(h) * 8192 + 4096 + tid * 8]); \
    } while (0)

    int aRow = (wm * 64 + l15) * 64;
    int bRow = (wn * 32 + l15) * 64;
    int cg0 = (hi ^ rxor) << 3;
    int cg1 = ((4 + hi) ^ rxor) << 3;

#define READ_A(dst, mh, b) do { \
        _Pragma("unroll") \
        for (int mil_ = 0; mil_ < 4; ++mil_) { \
            dst[mil_ * 2 + 0] = *(const short8*)&SA[b][(mh) * 8192 + mil_ * 1024 + aRow + cg0]; \
            dst[mil_ * 2 + 1] = *(const short8*)&SA[b][(mh) * 8192 + mil_ * 1024 + aRow + cg1]; \
        } } while (0)
#define READ_B(dst, nh, b) do { \
        _Pragma("unroll") \
        for (int nil_ = 0; nil_ < 2; ++nil_) { \
            dst[nil_ * 2 + 0] = *(const short8*)&SB[b][(nh) * 8192 + nil_ * 1024 + bRow + cg0]; \
            dst[nil_ * 2 + 1] = *(const short8*)&SB[b][(nh) * 8192 + nil_ * 1024 + bRow + cg1]; \
        } } while (0)

    f32x4 acc[8][4];
    #pragma unroll
    for (int mi = 0; mi < 8; ++mi)
        #pragma unroll
        for (int ni = 0; ni < 4; ++ni)
            acc[mi][ni] = (f32x4){0.f, 0.f, 0.f, 0.f};

#define MM(mb, nb, AF, BF) do { \
        __builtin_amdgcn_s_setprio(1); \
        _Pragma("unroll") \
        for (int ks_ = 0; ks_ < 2; ++ks_) \
        _Pragma("unroll") \
        for (int mil_ = 0; mil_ < 4; ++mil_) \
        _Pragma("unroll") \
        for (int nil_ = 0; nil_ < 2; ++nil_) \
            acc[(mb) + mil_][(nb) + nil_] = __builtin_amdgcn_mfma_f32_16x16x32_bf16( \
                AF[mil_ * 2 + ks_], BF[nil_ * 2 + ks_], acc[(mb) + mil_][(nb) + nil_], 0, 0, 0); \
        __builtin_amdgcn_s_setprio(0); \
    } while (0)

    int NK = K >> 6, NI = NK >> 1;
    STAGE_B(0, 0, 0); STAGE_A(0, 0, 0); STAGE_A(0, 1, 0); STAGE_B(0, 1, 0);
    STAGE_B(1, 0, 1); STAGE_A(1, 0, 1); STAGE_A(1, 1, 1);
    VMW(6);
    BARM();

    short8 alo[8], ahi[8], bb[4];
    for (int i = 0; i < NI; ++i) {
        int ta = 2 * i + 1; if (ta >= NK) ta = NK - 1;
        int tb = 2 * i + 2; if (tb >= NK) tb = NK - 1;
        int tc = 2 * i + 3; if (tc >= NK) tc = NK - 1;
        STAGE_B(1, 1, ta);
        READ_A(alo, 0, 0); READ_B(bb, 0, 0);
        BARM(); MM(0, 0, alo, bb); BARM();
        STAGE_B(0, 0, tb);
        READ_A(ahi, 1, 0);
        BARM(); MM(4, 0, ahi, bb); BARM();
        STAGE_A(0, 0, tb); STAGE_A(0, 1, tb);
        READ_B(bb, 1, 0);
        BARM(); MM(4, 2, ahi, bb); MM(0, 2, alo, bb);
        VMW(8);
        BARM();
        STAGE_B(0, 1, tb);
        READ_A(alo, 0, 1); READ_B(bb, 0, 1);
        BARM(); MM(0, 0, alo, bb); BARM();
        STAGE_B(1, 0, tc);
        READ_A(ahi, 1, 1);
        BARM(); MM(4, 0, ahi, bb);
        VMW(10);
        BARM();
        STAGE_A(1, 0, tc); STAGE_A(1, 1, tc);
        READ_B(bb, 1, 1);
        BARM(); MM(4, 2, ahi, bb); MM(0, 2, alo, bb);
        VMW(6);
        BARM();
    }

    int r0 = brow + wm * 128 + (hi << 2);
    int c0 = bcol + wn * 64 + l15;
    #pragma unroll
    for (int mi = 0; mi < 8; ++mi)
        #pragma unroll
        for (int ni = 0; ni < 4; ++ni)
            #pragma unroll
            for (int rr = 0; rr < 4; ++rr) {
                size_t idx = (size_t)(r0 + mi * 16 + rr) * N + (c0 + ni * 16);
                float val = acc[mi][ni][rr];
                if (OUTBF) ((u16*)C)[idx] = f2bf(val);
                else       ((float*)C)[idx] = val;
            }
#undef STAGE_A
#undef STAGE_B
#undef READ_A
#undef READ_B
#undef MM
}

// ---------------- 2-phase 128x128 GEMM (N=1024 out-proj: 512 blocks, 5/CU) ----------------
template<int OUTBF>
__global__ __launch_bounds__(256) void gemm_sb(const u16* __restrict__ A,
                                               const u16* __restrict__ Bt,
                                               void* __restrict__ C,
                                               int M, int N, int K, int nbx) {
    __shared__ u16 As[128 * 64];
    __shared__ u16 Bs[128 * 64];
    int nwg = gridDim.x;
    int bid = blockIdx.x;
    int cpx = nwg >> 3;
    int wg = (bid & 7) * cpx + (bid >> 3);
    int bx = wg % nbx, by = wg / nbx;
    int tid = threadIdx.x;
    int wave = tid >> 6, lane = tid & 63;
    int wr = wave >> 1, wc = wave & 1;
    int brow = by * 128, bcol = bx * 128;
    int srow = tid >> 3;
    int sgrp = (tid & 7) ^ (srow & 7);
    const u16* aS = A + (size_t)(brow + srow) * K + sgrp * 8;
    const u16* bS = Bt + (size_t)(bcol + srow) * K + sgrp * 8;
    f32x4 acc[4][4];
    #pragma unroll
    for (int mi = 0; mi < 4; ++mi)
        #pragma unroll
        for (int ni = 0; ni < 4; ++ni)
            acc[mi][ni] = (f32x4){0.f, 0.f, 0.f, 0.f};
    int l15 = lane & 15, hi = lane >> 4;
    int rxor = l15 & 7;
    for (int kt = 0; kt < K; kt += 64) {
        __syncthreads();
        #pragma unroll
        for (int i_ = 0; i_ < 4; ++i_) {
            gload16(aS + (size_t)i_ * 32 * K + kt, As + tid * 8 + i_ * 2048);
            gload16(bS + (size_t)i_ * 32 * K + kt, Bs + tid * 8 + i_ * 2048);
        }
        __syncthreads();
        #pragma unroll
        for (int ks = 0; ks < 2; ++ks) {
            short8 af[4], bfr[4];
            int g = ks * 4 + hi;
            #pragma unroll
            for (int i = 0; i < 4; ++i)
                af[i] = *(const short8*)(As + (size_t)(wr * 64 + i * 16 + l15) * 64 + ((g ^ rxor) << 3));
            #pragma unroll
            for (int i = 0; i < 4; ++i)
                bfr[i] = *(const short8*)(Bs + (size_t)(wc * 64 + i * 16 + l15) * 64 + ((g ^ rxor) << 3));
            #pragma unroll
            for (int mi = 0; mi < 4; ++mi)
                #pragma unroll
                for (int ni = 0; ni < 4; ++ni)
                    acc[mi][ni] = __builtin_amdgcn_mfma_f32_16x16x32_bf16(af[mi], bfr[ni], acc[mi][ni], 0, 0, 0);
        }
    }
    int r0 = brow + wr * 64 + (hi << 2);
    int c0 = bcol + wc * 64 + l15;
    #pragma unroll
    for (int mi = 0; mi < 4; ++mi)
        #pragma unroll
        for (int ni = 0; ni < 4; ++ni)
            #pragma unroll
            for (int rr = 0; rr < 4; ++rr) {
                size_t idx = (size_t)(r0 + mi * 16 + rr) * N + (c0 + ni * 16);
                float val = acc[mi][ni][rr];
                if (OUTBF) ((u16*)C)[idx] = f2bf(val);
                else       ((float*)C)[idx] = val;
            }
}

// ---------------- gate slice: ls[j] = logsigmoid(xg1·W2[:,cc+j] + b2)/16, j=0..7 ----------------
__device__ __forceinline__ void gate_z8(const u16* __restrict__ xg,
                                        const float* __restrict__ W2,
                                        const float* __restrict__ b2,
                                        int cc, float* out8) {
    short8 x0 = *(const short8*)xg;
    short8 x1 = *(const short8*)(xg + 8);
    float z[8];
    float4 z0 = *(const float4*)(b2 + cc);
    float4 z1 = *(const float4*)(b2 + cc + 4);
    z[0]=z0.x; z[1]=z0.y; z[2]=z0.z; z[3]=z0.w;
    z[4]=z1.x; z[5]=z1.y; z[6]=z1.z; z[7]=z1.w;
    #pragma unroll
    for (int u = 0; u < 16; ++u) {
        float xu = bf2f((u16)(u < 8 ? x0[u] : x1[u - 8]));
        const float4 w0 = *(const float4*)(W2 + (size_t)u * 512 + cc);
        const float4 w1 = *(const float4*)(W2 + (size_t)u * 512 + cc + 4);
        z[0] += xu * w0.x; z[1] += xu * w0.y; z[2] += xu * w0.z; z[3] += xu * w0.w;
        z[4] += xu * w1.x; z[5] += xu * w1.y; z[6] += xu * w1.z; z[7] += xu * w1.w;
    }
    #pragma unroll
    for (int j = 0; j < 8; ++j) {
        float zz = z[j];
        out8[j] = (fminf(zz, 0.f) - log1pf(expf(-fabsf(zz)))) * 0.0625f;
    }
}

// ---------------- parallel inclusive cumsum over t (64 rows) of gkS[64][36] ----------------
// wave w scans columns w*8..w*8+7; lane = t; 6-step shfl_up Hillis-Steele.
__device__ __forceinline__ void scan64(float (*gkS)[36], float* Ztot, int tid) {
    int wv2 = tid >> 6, ln = tid & 63;
    #pragma unroll
    for (int ii = 0; ii < 8; ++ii) {
        int i = wv2 * 8 + ii;
        float v = gkS[ln][i];
        #pragma unroll
        for (int d = 1; d < 64; d <<= 1) {
            float u = __shfl_up(v, d);
            if (ln >= d) v += u;
        }
        gkS[ln][i] = v;
        if (Ztot && ln == 63) Ztot[i] = v;
    }
}

// ---------------- phase A (MFMA): gate+cumsum; M^T (bf16) via mfma -> MT, D ----------------
__global__ __launch_bounds__(256) void phaseA(const u16* __restrict__ qkvg,
                                              const float* __restrict__ W2,
                                              const float* __restrict__ b2,
                                              u16* __restrict__ MT_ws,
                                              float* __restrict__ D_ws) {
    int bh = blockIdx.x >> 6, c = blockIdx.x & 63;
    int b = bh >> 4, h = bh & 15;
    int t0 = b * TT + c * CHUNK;
    __shared__ float gkS[64][36];
    __shared__ u16 kdT_bf[32 * 72];
    __shared__ u16 VT_bf[64 * 72];
    __shared__ float Z[32];
    int tid = threadIdx.x;
    int s = tid >> 2, i0 = (tid & 3) << 3;
    {
        float ls[8];
        gate_z8(qkvg + (size_t)(t0 + s) * QSTR + 3072, W2, b2, h * DK + i0, ls);
        #pragma unroll
        for (int jj = 0; jj < 8; ++jj) gkS[s][i0 + jj] = ls[jj];
    }
    short8 kv = *(const short8*)(qkvg + (size_t)(t0 + s) * QSTR + 512 + h * DK + i0);
    {
        int j0 = (tid & 3) << 4;
        short8 v0 = *(const short8*)(qkvg + (size_t)(t0 + s) * QSTR + 1024 + h * DV + j0);
        short8 v1 = *(const short8*)(qkvg + (size_t)(t0 + s) * QSTR + 1024 + h * DV + j0 + 8);
        #pragma unroll
        for (int jj = 0; jj < 8; ++jj) {
            VT_bf[(j0 + jj) * 72 + s] = (u16)v0[jj];
            VT_bf[(j0 + 8 + jj) * 72 + s] = (u16)v1[jj];
        }
    }
    __syncthreads();
    scan64(gkS, Z, tid);
    __syncthreads();
    #pragma unroll
    for (int jj = 0; jj < 8; ++jj)
        kdT_bf[(i0 + jj) * 72 + s] = f2bf(expf(Z[i0 + jj] - gkS[s][i0 + jj]) * bf2f((u16)kv[jj]));
    __syncthreads();
    int wave = tid >> 6, lane = tid & 63, l15 = lane & 15, hi = lane >> 4;
    int it = wave & 1, jp = wave >> 1;
    size_t base = ((size_t)(bh * NCH + c)) * 2048;
    #pragma unroll
    for (int jj2 = 0; jj2 < 2; ++jj2) {
        int jt = jp * 2 + jj2;
        f32x4 mc = (f32x4){0.f, 0.f, 0.f, 0.f};
        #pragma unroll
        for (int kc = 0; kc < 2; ++kc) {
            short8 ak = *(const short8*)&kdT_bf[(it * 16 + l15) * 72 + kc * 32 + hi * 8];
            short8 bv = *(const short8*)&VT_bf[(jt * 16 + l15) * 72 + kc * 32 + hi * 8];
            mc = __builtin_amdgcn_mfma_f32_16x16x32_bf16(ak, bv, mc, 0, 0, 0);
        }
        #pragma unroll
        for (int rr = 0; rr < 4; ++rr)
            MT_ws[base + (size_t)(jt * 16 + l15) * 32 + it * 16 + hi * 4 + rr] = f2bf(mc[rr]);
    }
    if (tid < 32) D_ws[(size_t)(bh * NCH + c) * 32 + tid] = expf(Z[tid]);
}

// ---------------- phase B: chunk-state recurrence, bf16 M in / bf16 H out ----------------
__global__ __launch_bounds__(256) void phaseB(const u16* __restrict__ MT_ws,
                                              const float* __restrict__ D_ws,
                                              u16* __restrict__ HT_ws) {
    int idx = blockIdx.x * 256 + threadIdx.x;
    int bh = idx >> 11;
    int ji = idx & 2047;
    int i = ji & 31;
    float h = 0.f;
    size_t base = (size_t)bh * NCH * 2048 + ji;
    const float* dp = D_ws + (size_t)bh * NCH * 32 + i;
    for (int c = 0; c < NCH; ++c) {
        HT_ws[base + (size_t)c * 2048] = f2bf(h);
        h = h * dp[c * 32] + bf2f(MT_ws[base + (size_t)c * 2048]);
    }
}

// ---------------- phase C (MFMA): score->mask->P, O = P@V + qh@H, fused RMS/swish ----------------
__global__ __launch_bounds__(256) void phaseC(const u16* __restrict__ qkvg,
                                              const float* __restrict__ W2,
                                              const float* __restrict__ b2,
                                              const u16* __restrict__ HT_ws,
                                              const float* __restrict__ gnw,
                                              u16* __restrict__ o_n) {
    int bh = blockIdx.x >> 6, c = blockIdx.x & 63;
    int b = bh >> 4, h = bh & 15;
    int t0 = b * TT + c * CHUNK;
    __shared__ float gkS[64][36];
    __shared__ u16 qh_bf[64 * 40];
    __shared__ u16 kt_bf[64 * 40];
    __shared__ u16 VT_bf[64 * 72];
    __shared__ u16 Ht_bf[64 * 40];
    u16* P_bf = (u16*)&gkS[0][0];
    int tid = threadIdx.x;
    int s = tid >> 2, i0 = (tid & 3) << 3;
    {
        float ls[8];
        gate_z8(qkvg + (size_t)(t0 + s) * QSTR + 3072, W2, b2, h * DK + i0, ls);
        #pragma unroll
        for (int jj = 0; jj < 8; ++jj) gkS[s][i0 + jj] = ls[jj];
    }
    short8 qv = *(const short8*)(qkvg + (size_t)(t0 + s) * QSTR + h * DK + i0);
    short8 kv = *(const short8*)(qkvg + (size_t)(t0 + s) * QSTR + 512 + h * DK + i0);
    {
        int j0 = (tid & 3) << 4;
        short8 v0 = *(const short8*)(qkvg + (size_t)(t0 + s) * QSTR + 1024 + h * DV + j0);
        short8 v1 = *(const short8*)(qkvg + (size_t)(t0 + s) * QSTR + 1024 + h * DV + j0 + 8);
        #pragma unroll
        for (int jj = 0; jj < 8; ++jj) {
            VT_bf[(j0 + jj) * 72 + s] = (u16)v0[jj];
            VT_bf[(j0 + 8 + jj) * 72 + s] = (u16)v1[jj];
        }
    }
    {
        // H^T chunk-initial state: raw bf16 copy
        const u16* hp = HT_ws + ((size_t)(bh * NCH + c)) * 2048 + tid * 8;
        short8 hv = *(const short8*)hp;
        int j = tid >> 2, ii0 = (tid & 3) << 3;
        *(short8*)&Ht_bf[j * 40 + ii0] = hv;
    }
    __syncthreads();
    scan64(gkS, nullptr, tid);
    __syncthreads();
    #pragma unroll
    for (int jj = 0; jj < 8; ++jj) {
        float Sv = gkS[s][i0 + jj];
        qh_bf[s * 40 + i0 + jj] = f2bf(bf2f((u16)qv[jj]) * expf(Sv) * SCALE);
        kt_bf[s * 40 + i0 + jj] = f2bf(bf2f((u16)kv[jj]) * expf(fminf(-Sv, 80.f)));
    }
    __syncthreads();
    int wave = tid >> 6, lane = tid & 63, l15 = lane & 15, hi = lane >> 4;
    int w = wave;
    short8 aq = *(const short8*)&qh_bf[(w * 16 + l15) * 40 + hi * 8];
    #pragma unroll
    for (int sn = 0; sn < 4; ++sn) {
        f32x4 sc = (f32x4){0.f, 0.f, 0.f, 0.f};
        if (sn <= w) {
            short8 bk = *(const short8*)&kt_bf[(sn * 16 + l15) * 40 + hi * 8];
            sc = __builtin_amdgcn_mfma_f32_16x16x32_bf16(aq, bk, sc, 0, 0, 0);
        }
        #pragma unroll
        for (int rr = 0; rr < 4; ++rr) {
            float val = sc[rr];
            if (sn > w || (sn == w && l15 > hi * 4 + rr)) val = 0.f;
            P_bf[(w * 16 + hi * 4 + rr) * 72 + sn * 16 + l15] = f2bf(val);
        }
    }
    __syncthreads();
    f32x4 acc[4];
    #pragma unroll
    for (int jn = 0; jn < 4; ++jn) {
        f32x4 a = (f32x4){0.f, 0.f, 0.f, 0.f};
        short8 bhf = *(const short8*)&Ht_bf[(jn * 16 + l15) * 40 + hi * 8];
        acc[jn] = __builtin_amdgcn_mfma_f32_16x16x32_bf16(aq, bhf, a, 0, 0, 0);
    }
    int nkc = (w < 2) ? 1 : 2;
    for (int kc = 0; kc < nkc; ++kc) {
        short8 ap = *(const short8*)&P_bf[(w * 16 + l15) * 72 + kc * 32 + hi * 8];
        #pragma unroll
        for (int jn = 0; jn < 4; ++jn) {
            short8 bv = *(const short8*)&VT_bf[(jn * 16 + l15) * 72 + kc * 32 + hi * 8];
            acc[jn] = __builtin_amdgcn_mfma_f32_16x16x32_bf16(ap, bv, acc[jn], 0, 0, 0);
        }
    }
    #pragma unroll
    for (int rr = 0; rr < 4; ++rr) {
        float sum2 = 0.f;
        #pragma unroll
        for (int jn = 0; jn < 4; ++jn) sum2 += acc[jn][rr] * acc[jn][rr];
        sum2 += __shfl_xor(sum2, 1);
        sum2 += __shfl_xor(sum2, 2);
        sum2 += __shfl_xor(sum2, 4);
        sum2 += __shfl_xor(sum2, 8);
        float rms = rsqrtf(sum2 * (1.f / 64.f) + 1e-5f);
        int t = w * 16 + hi * 4 + rr;
        #pragma unroll
        for (int jn = 0; jn < 4; ++jn) {
            int j = jn * 16 + l15;
            float g = bf2f(qkvg[(size_t)(t0 + t) * QSTR + 2048 + h * DV + j]);
            float sw = g / (1.f + expf(-g));
            float o = acc[jn][rr] * rms * gnw[j] * sw;
            o_n[(size_t)(t0 + t) * 1024 + h * DV + j] = f2bf(o);
        }
    }
}

// ---------------- launch ----------------
extern "C" void kernel_launch(void* const* d_in, const int* in_sizes, int n_in,
                              void* d_out, int out_size, void* d_ws, size_t ws_size,
                              hipStream_t stream) {
    const float* x    = (const float*)d_in[0];
    const float* Wq   = (const float*)d_in[1];
    const float* Wk   = (const float*)d_in[2];
    const float* Wv   = (const float*)d_in[3];
    const float* Wgk1 = (const float*)d_in[4];
    const float* Wgk2 = (const float*)d_in[5];
    const float* bgk2 = (const float*)d_in[6];
    const float* Wg   = (const float*)d_in[7];
    const float* gnw  = (const float*)d_in[8];
    const float* Wo   = (const float*)d_in[9];

    char* ws = (char*)d_ws;
    size_t off = 0;
    u16* xb      = (u16*)(ws + off); off += (size_t)MROWS * 1024 * 2;          // 16.8 MB
    u16* Wall    = (u16*)(ws + off); off += (size_t)4352 * 1024 * 2;           // 8.9 MB (WcatT | WoT)
    u16* qkvg    = (u16*)(ws + off); off += (size_t)MROWS * QSTR * 2;          // 54.5 MB
    u16* MT_ws   = (u16*)(ws + off); off += (size_t)NBH * NCH * 2048 * 2;      // 8.4 MB (bf16)
    float* D_ws  = (float*)(ws + off); off += (size_t)NBH * NCH * 32 * 4;      // 0.26 MB
    u16* HT_ws   = (u16*)(ws + off); off += (size_t)NBH * NCH * 2048 * 2;      // 8.4 MB (bf16)
    u16* o_n     = (u16*)(ws + off); off += (size_t)MROWS * 1024 * 2;          // 16.8 MB
    u16* WcatT   = Wall;
    u16* WoT     = Wall + (size_t)3328 * 1024;

    prep_fused<<<8192 + 136 * 32, 256, 0, stream>>>(x, xb, Wq, Wk, Wv, Wg, Wgk1, Wo, Wall);
    gemm8<1><<<416, 512, 0, stream>>>(xb, WcatT, qkvg, MROWS, QSTR, 1024, 13);
    phaseA<<<NBH * NCH, 256, 0, stream>>>(qkvg, Wgk2, bgk2, MT_ws, D_ws);
    phaseB<<<256, 256, 0, stream>>>(MT_ws, D_ws, HT_ws);
    phaseC<<<NBH * NCH, 256, 0, stream>>>(qkvg, Wgk2, bgk2, HT_ws, gnw, o_n);
    gemm_sb<0><<<8 * 64, 256, 0, stream>>>(o_n, WoT, d_out, MROWS, 1024, 1024, 8);
}